// Round 8
// baseline (1248.619 us; speedup 1.0000x reference)
//
#include <hip/hip_runtime.h>
#include <stdint.h>
#include <stddef.h>

#define FINF __builtin_inff()

// =================== Threefry-2x32 (JAX-compatible) ===================
__device__ inline void tf2x32(uint32_t k0, uint32_t k1, uint32_t x0, uint32_t x1,
                              uint32_t* o0, uint32_t* o1) {
  uint32_t ks2 = k0 ^ k1 ^ 0x1BD11BDAu;
  uint32_t v0 = x0 + k0, v1 = x1 + k1;
#define TFR(r) { v0 += v1; v1 = (v1 << (r)) | (v1 >> (32 - (r))); v1 ^= v0; }
  TFR(13) TFR(15) TFR(26) TFR(6)
  v0 += k1;  v1 += ks2 + 1u;
  TFR(17) TFR(29) TFR(16) TFR(24)
  v0 += ks2; v1 += k0 + 2u;
  TFR(13) TFR(15) TFR(26) TFR(6)
  v0 += k0;  v1 += k1 + 3u;
  TFR(17) TFR(29) TFR(16) TFR(24)
  v0 += k1;  v1 += ks2 + 4u;
  TFR(13) TFR(15) TFR(26) TFR(6)
  v0 += ks2; v1 += k0 + 5u;
#undef TFR
  *o0 = v0; *o1 = v1;
}

// subkey for round r of jax.random.permutation key chain:
// kst_0 = {0, seed}; subkey_r = tf(kst_r, (0,1)); kst_{r+1} = tf(kst_r, (0,0))
__device__ inline void perm_subkey(uint32_t seed, int round, uint32_t* s0, uint32_t* s1) {
  uint32_t k0 = 0u, k1 = seed;
  for (int r = 0; r < round; r++) {
    uint32_t a0, a1; tf2x32(k0, k1, 0u, 0u, &a0, &a1);
    k0 = a0; k1 = a1;
  }
  tf2x32(k0, k1, 0u, 1u, s0, s1);
}

// keys[i] = (bits << 32) | i   (stable sort key, identical to bitonic version)
__global__ __launch_bounds__(256) void perm_keys_kernel(uint32_t seed, int round, int n,
                                                        unsigned long long* __restrict__ keys) {
  uint32_t s0, s1; perm_subkey(seed, round, &s0, &s1);
  int i = blockIdx.x * 256 + threadIdx.x;
  if (i < n) {
    uint32_t y0, y1; tf2x32(s0, s1, 0u, (uint32_t)i, &y0, &y1);
    keys[i] = ((unsigned long long)(y0 ^ y1) << 32) | (unsigned)i;
  }
}

// out[rank(i)] = (vin ? vin[i] : i) for rank < m.  rank = #{j: key_j < key_i}
__global__ __launch_bounds__(256) void perm_rank_kernel(const unsigned long long* __restrict__ keys,
                                                        const int* __restrict__ vin,
                                                        int* __restrict__ vout, int n, int m) {
  __shared__ int part[256];
  int t = threadIdx.x;
  int r = blockIdx.x * 128 + (t & 127);
  int half = t >> 7;
  unsigned long long ki = keys[r];
  int cnt = 0;
  int j0 = half * (n >> 1), j1 = j0 + (n >> 1);
  for (int j = j0; j < j1; j++) cnt += (keys[j] < ki) ? 1 : 0;
  part[t] = cnt;
  __syncthreads();
  if (t < 128) {
    int rank = part[t] + part[t + 128];
    if (rank < m) vout[rank] = vin ? vin[r] : r;
  }
}

// ---- wave-wide argmin of per-lane heads (proven primitives) ----------------
__device__ inline void wave_argmin2(float head_d, int head_i, float* Mo, int* wio) {
  float M = head_d;
#pragma unroll
  for (int off = 1; off < 64; off <<= 1) M = fminf(M, __shfl_xor(M, off));
  int cand = (head_d == M) ? head_i : 0x7fffffff;
#pragma unroll
  for (int off = 1; off < 64; off <<= 1) cand = min(cand, __shfl_xor(cand, off));
  *Mo = M; *wio = cand;
}

// =================== KNN (N=4096): WAVES waves/row + rank merge ===============
template <int CNT, int WAVES>
__global__ __launch_bounds__(64 * WAVES) void knn_lex_kernel(const float* __restrict__ verts,
                                                             int N,
                                                             int* __restrict__ idx20,
                                                             int* __restrict__ idx4) {
  int row = blockIdx.x; int b = row / N, i = row - b * N;
  int t = threadIdx.x; int w = t >> 6; int lane = t & 63;
  const float* vb = verts + (size_t)b * N * 3;
  float xi = vb[i * 3], yi = vb[i * 3 + 1], zi = vb[i * 3 + 2];
  float sqi = (xi * xi + yi * yi) + zi * zi;

  int base = w * (N / WAVES) + lane;
  float qd[CNT]; int qi[CNT];
#pragma unroll
  for (int m = 0; m < CNT; m++) {
    int j = base + m * 64;
    float xj = vb[j * 3], yj = vb[j * 3 + 1], zj = vb[j * 3 + 2];
    float sqj = (xj * xj + yj * yj) + zj * zj;
    float dot = (xi * xj + yi * yj) + zi * zj;
    qd[m] = sqi + sqj - 2.f * dot;
    qi[m] = j;
  }
  // per-lane register bitonic sort ascending on dist
#pragma unroll
  for (int k = 2; k <= CNT; k <<= 1)
#pragma unroll
    for (int j = k >> 1; j > 0; j >>= 1)
#pragma unroll
      for (int m = 0; m < CNT; m++) {
        int l = m ^ j;
        if (l > m) {
          bool up = ((m & k) == 0);
          bool sw = up ? (qd[m] > qd[l]) : (qd[m] < qd[l]);
          float td = sw ? qd[l] : qd[m]; qd[l] = sw ? qd[m] : qd[l]; qd[m] = td;
          int ti = sw ? qi[l] : qi[m]; qi[l] = sw ? qi[m] : qi[l]; qi[m] = ti;
        }
      }

  __shared__ float wd[WAVES][21];
  __shared__ int wi[WAVES][21];
  for (int r = 0; r < 21; r++) {
    float M; int widx;
    wave_argmin2(qd[0], qi[0], &M, &widx);
    if (lane == 0) { wd[w][r] = M; wi[w][r] = widx; }
    bool win = (qi[0] == widx);
#pragma unroll
    for (int m = 0; m < CNT - 1; m++) {
      qd[m] = win ? qd[m + 1] : qd[m];
      qi[m] = win ? qi[m + 1] : qi[m];
    }
    if (win) { qd[CNT - 1] = FINF; qi[CNT - 1] = 0x7fffffff; }
  }
  __syncthreads();
  // rank merge of the WAVES sorted 21-lists
  if (lane < 21) {
    float d0 = wd[w][lane]; int i0 = wi[w][lane];
    int rank = lane;
#pragma unroll
    for (int w2 = 0; w2 < WAVES; w2++) {
      if (w2 == w) continue;
      for (int p = 0; p < 21; p++) {
        float ld = wd[w2][p]; int li = wi[w2][p];
        rank += (ld < d0 || (ld == d0 && li < i0)) ? 1 : 0;
      }
    }
    if (rank >= 1 && rank <= 20) idx20[(size_t)row * 20 + (rank - 1)] = i0;
    if (rank >= 1 && rank <= 4)  idx4[(size_t)row * 4 + (rank - 1)] = i0;
  }
}

// =================== KNN (N=1024): ONE wave/row, direct rank output ==========
template <int CNT>
__global__ __launch_bounds__(64) void knn_1w_lex_kernel(const float* __restrict__ verts, int N,
                                                        int* __restrict__ idx20,
                                                        int* __restrict__ idx4) {
  int row = blockIdx.x; int b = row / N, i = row - b * N;
  int lane = threadIdx.x;
  const float* vb = verts + (size_t)b * N * 3;
  float xi = vb[i * 3], yi = vb[i * 3 + 1], zi = vb[i * 3 + 2];
  float sqi = (xi * xi + yi * yi) + zi * zi;

  float qd[CNT]; int qi[CNT];
#pragma unroll
  for (int m = 0; m < CNT; m++) {
    int j = lane + m * 64;
    float xj = vb[j * 3], yj = vb[j * 3 + 1], zj = vb[j * 3 + 2];
    float sqj = (xj * xj + yj * yj) + zj * zj;
    float dot = (xi * xj + yi * yj) + zi * zj;
    qd[m] = sqi + sqj - 2.f * dot;
    qi[m] = j;
  }
#pragma unroll
  for (int k = 2; k <= CNT; k <<= 1)
#pragma unroll
    for (int j = k >> 1; j > 0; j >>= 1)
#pragma unroll
      for (int m = 0; m < CNT; m++) {
        int l = m ^ j;
        if (l > m) {
          bool up = ((m & k) == 0);
          bool sw = up ? (qd[m] > qd[l]) : (qd[m] < qd[l]);
          float td = sw ? qd[l] : qd[m]; qd[l] = sw ? qd[m] : qd[l]; qd[m] = td;
          int ti = sw ? qi[l] : qi[m]; qi[l] = sw ? qi[m] : qi[l]; qi[m] = ti;
        }
      }
  for (int r = 0; r < 21; r++) {
    float M; int widx;
    wave_argmin2(qd[0], qi[0], &M, &widx);
    if (lane == 0 && r >= 1) {
      idx20[(size_t)row * 20 + (r - 1)] = widx;
      if (r <= 4) idx4[(size_t)row * 4 + (r - 1)] = widx;
    }
    bool win = (qi[0] == widx);
#pragma unroll
    for (int m = 0; m < CNT - 1; m++) {
      qd[m] = win ? qd[m + 1] : qd[m];
      qi[m] = win ? qi[m + 1] : qi[m];
    }
    if (win) { qd[CNT - 1] = FINF; qi[CNT - 1] = 0x7fffffff; }
  }
}

// =================== conv_surface + LN + relu -> fm0 (C=32) ===================
__global__ void conv_surface_kernel(const float* __restrict__ verts,
                                    const int* __restrict__ idx20,
                                    const float* __restrict__ d0,
                                    const float* __restrict__ g, const float* __restrict__ be,
                                    float* __restrict__ out, int N) {
  int row = blockIdx.x; int b = row / N, i = row - b * N;
  int t = threadIdx.x;
  __shared__ float nd[20][3];
  const float* vb = verts + (size_t)b * N * 3;
  if (t < 20) {
    int j = idx20[(size_t)row * 20 + t];
    float dx = vb[j * 3] - vb[i * 3], dy = vb[j * 3 + 1] - vb[i * 3 + 1], dz = vb[j * 3 + 2] - vb[i * 3 + 2];
    float n2 = sqrtf(dx * dx + dy * dy + dz * dz); n2 = fmaxf(n2, 1e-12f);
    nd[t][0] = dx / n2; nd[t][1] = dy / n2; nd[t][2] = dz / n2;
  }
  __syncthreads();
  float x = 0.f;
  if (t < 32) {
    float a = d0[t], bb2 = d0[32 + t], c = d0[64 + t];
    float nrm = fmaxf(sqrtf(a * a + bb2 * bb2 + c * c), 1e-12f);
    a /= nrm; bb2 /= nrm; c /= nrm;
    float mx = -FINF;
    for (int kk = 0; kk < 20; kk++) {
      float th = fmaxf(nd[kk][0] * a + nd[kk][1] * bb2 + nd[kk][2] * c, 0.f);
      mx = fmaxf(mx, th);
    }
    x = mx;
  }
  float s = x;
  for (int off = 32; off; off >>= 1) s += __shfl_xor(s, off);
  float mean = s / 32.f;
  float dev = (t < 32) ? x - mean : 0.f;
  float s2 = dev * dev;
  for (int off = 32; off; off >>= 1) s2 += __shfl_xor(s2, off);
  float var = s2 / 32.f;
  if (t < 32) {
    float y = (x - mean) / sqrtf(var + 1e-6f) * g[t] + be[t];
    out[(size_t)row * 32 + t] = fmaxf(y, 0.f);
  }
}

// =================== GEMM: y = x(R,I) @ W(I,O) + bias (xs transposed) =========
__global__ void gemm_io_kernel(const float* __restrict__ x, const float* __restrict__ W,
                               const float* __restrict__ bias, float* __restrict__ y,
                               int R, int I, int O) {
  int rb = blockIdx.x * 8;
  int o = blockIdx.y * blockDim.x + threadIdx.x;
  __shared__ float xs[256][8];
  for (int u = 0; u < 8; u++)
    for (int i2 = threadIdx.x; i2 < I; i2 += blockDim.x) xs[i2][u] = x[(size_t)(rb + u) * I + i2];
  __syncthreads();
  float a[8] = {0, 0, 0, 0, 0, 0, 0, 0};
  for (int k2 = 0; k2 < I; k2++) {
    float wv = W[(size_t)k2 * O + o];
    float4 xa = *(const float4*)&xs[k2][0];
    float4 xb = *(const float4*)&xs[k2][4];
    a[0] += xa.x * wv; a[1] += xa.y * wv; a[2] += xa.z * wv; a[3] += xa.w * wv;
    a[4] += xb.x * wv; a[5] += xb.y * wv; a[6] += xb.z * wv; a[7] += xb.w * wv;
  }
  float bv = bias[o];
#pragma unroll
  for (int u = 0; u < 8; u++) y[(size_t)(rb + u) * O + o] = a[u] + bv;
}

// =================== conv_layer combine (k-loop hoisted) ===================
template <int CPT>
__global__ void combine_kernel(const float* __restrict__ verts, const int* __restrict__ idx20,
                               const float* __restrict__ fo, const float* __restrict__ dirs,
                               const float* __restrict__ g, const float* __restrict__ be,
                               float* __restrict__ out, int N, int C) {
  int row = blockIdx.x; int b = row / N, i = row - b * N;
  int t = threadIdx.x, bs = blockDim.x;
  __shared__ float nd[20][3];
  __shared__ int nidx[20];
  __shared__ float red[8];
  const float* vb = verts + (size_t)b * N * 3;
  if (t < 20) {
    int j = idx20[(size_t)row * 20 + t];
    nidx[t] = j;
    float dx = vb[j * 3] - vb[i * 3], dy = vb[j * 3 + 1] - vb[i * 3 + 1], dz = vb[j * 3 + 2] - vb[i * 3 + 2];
    float n2 = fmaxf(sqrtf(dx * dx + dy * dy + dz * dz), 1e-12f);
    nd[t][0] = dx / n2; nd[t][1] = dy / n2; nd[t][2] = dz / n2;
  }
  __syncthreads();
  const float* fob = fo + (size_t)b * N * 2 * C;
  const float* forow = fob + (size_t)i * 2 * C;
  float da[CPT], db[CPT], dc[CPT], mx[CPT];
#pragma unroll
  for (int u = 0; u < CPT; u++) {
    int c = t + u * bs;
    float a = dirs[c], bb = dirs[C + c], cc = dirs[2 * C + c];
    float nrm = fmaxf(sqrtf(a * a + bb * bb + cc * cc), 1e-12f);
    da[u] = a / nrm; db[u] = bb / nrm; dc[u] = cc / nrm;
    mx[u] = -FINF;
  }
  for (int kk = 0; kk < 20; kk++) {
    float n0 = nd[kk][0], n1 = nd[kk][1], n2v = nd[kk][2];
    const float* sup = fob + (size_t)nidx[kk] * 2 * C + C + t;
#pragma unroll
    for (int u = 0; u < CPT; u++) {
      float th = fmaxf(n0 * da[u] + n1 * db[u] + n2v * dc[u], 0.f);
      mx[u] = fmaxf(mx[u], th * sup[u * bs]);
    }
  }
  float xv[CPT];
  float ssum = 0.f;
#pragma unroll
  for (int u = 0; u < CPT; u++) {
    int c = t + u * bs;
    float val = forow[c] + mx[u];
    xv[u] = val; ssum += val;
  }
  int nw = bs >> 6;
  for (int off = 32; off; off >>= 1) ssum += __shfl_down(ssum, off);
  if ((t & 63) == 0) red[t >> 6] = ssum;
  __syncthreads();
  if (t == 0) { float s = red[0]; for (int w = 1; w < nw; w++) s += red[w]; red[0] = s; }
  __syncthreads();
  float mean = red[0] / (float)C;
  __syncthreads();
  float s2 = 0.f;
#pragma unroll
  for (int u = 0; u < CPT; u++) { float d2 = xv[u] - mean; s2 += d2 * d2; }
  for (int off = 32; off; off >>= 1) s2 += __shfl_down(s2, off);
  if ((t & 63) == 0) red[t >> 6] = s2;
  __syncthreads();
  if (t == 0) { float s = red[0]; for (int w = 1; w < nw; w++) s += red[w]; red[0] = s; }
  __syncthreads();
  float inv = 1.0f / sqrtf(red[0] / (float)C + 1e-6f);
#pragma unroll
  for (int u = 0; u < CPT; u++) {
    int c = t + u * bs;
    float yv = (xv[u] - mean) * inv * g[c] + be[c];
    out[(size_t)row * C + c] = fmaxf(yv, 0.f);
  }
}

// =================== pool (max over 4 NN) + row-select ===================
__global__ void pool_select_kernel(const float* __restrict__ fm, const int* __restrict__ idx4,
                                   const int* __restrict__ sel, const float* __restrict__ vin,
                                   float* __restrict__ vout, float* __restrict__ out,
                                   int N, int M, int C) {
  int row = blockIdx.x; int b = row / M, r = row - b * M;
  int s = sel[r];
  const int* id = idx4 + ((size_t)b * N + s) * 4;
  int i0 = id[0], i1 = id[1], i2 = id[2], i3 = id[3];
  const float* fb = fm + (size_t)b * N * C;
  for (int c = threadIdx.x; c < C; c += blockDim.x) {
    float m = fmaxf(fmaxf(fb[(size_t)i0 * C + c], fb[(size_t)i1 * C + c]),
                    fmaxf(fb[(size_t)i2 * C + c], fb[(size_t)i3 * C + c]));
    out[((size_t)b * M + r) * C + c] = m;
  }
  if (vout != nullptr && threadIdx.x < 3)
    vout[((size_t)b * M + r) * 3 + threadIdx.x] = vin[((size_t)b * N + s) * 3 + threadIdx.x];
}

// =================== token transpose ===================
__global__ void tok_kernel(const float* __restrict__ token, float* __restrict__ tok) {
  int id = blockIdx.x * 256 + threadIdx.x;
  int e = id & 63; int n = (id >> 6) & 1023;
  tok[id] = token[e * 1024 + n];
}

// =================== linear: y = x(R,I) @ W(O,I)^T + bias (+res) ===================
__global__ void linear_oi_kernel(const float* __restrict__ x, const float* __restrict__ W,
                                 const float* __restrict__ bias, const float* __restrict__ res,
                                 float* __restrict__ y, int R, int I, int O) {
  int rb = blockIdx.x * 8;
  int o = threadIdx.x;
  __shared__ float xs[8][256];
  for (int u = 0; u < 8; u++)
    for (int i2 = threadIdx.x; i2 < I; i2 += O) xs[u][i2] = x[(size_t)(rb + u) * I + i2];
  __syncthreads();
  float a[8] = {0, 0, 0, 0, 0, 0, 0, 0};
  const float* w = W + (size_t)o * I;
  for (int k2 = 0; k2 < I; k2++) {
    float wv = w[k2];
#pragma unroll
    for (int u = 0; u < 8; u++) a[u] += xs[u][k2] * wv;
  }
  float bv = bias[o];
#pragma unroll
  for (int u = 0; u < 8; u++) {
    float val = a[u] + bv;
    if (res) val += res[(size_t)(rb + u) * O + o];
    y[(size_t)(rb + u) * O + o] = val;
  }
}

// =================== tiled flash attention ===================
template <int HD, int QPT, int KS>
__global__ __launch_bounds__(256) void attn_tiled(
    const float* __restrict__ q, const float* __restrict__ kk,
    const float* __restrict__ vv, float* __restrict__ o,
    int Lq, int Lk, int H, float scale) {
  constexpr int TK = 64;
  constexpr int QG = 256 / (2 * KS);
  constexpr int QPB = QG * QPT;
  constexpr int V4 = HD / 4;
  constexpr int STR = V4 + 1;
  constexpr int HH = HD / 2;
  constexpr int V4H = HH / 4;

  __shared__ float4 Ks[TK * STR];
  __shared__ float4 Vs[TK * STR];

  int t = threadIdx.x;
  int dh = t & 1;
  int ki = (t >> 1) & (KS - 1);
  int qg = t / (2 * KS);
  int nqt = Lq / QPB;
  int qt = blockIdx.x % nqt, bh = blockIdx.x / nqt;
  int h = bh % H, b = bh / H;
  int E = H * HD;
  int q0 = qt * QPB + qg * QPT;

  const float* qbase = q + ((size_t)b * Lq + q0) * E + h * HD + dh * HH;
  const float* kbase = kk + (size_t)b * Lk * E + h * HD;
  const float* vbase = vv + (size_t)b * Lk * E + h * HD;

  float qr[QPT][HH], O[QPT][HH], m[QPT], l[QPT];
#pragma unroll
  for (int r = 0; r < QPT; r++) {
    m[r] = -FINF; l[r] = 0.f;
#pragma unroll
    for (int d = 0; d < HH; d++) { qr[r][d] = qbase[(size_t)r * E + d]; O[r][d] = 0.f; }
  }

  for (int k0 = 0; k0 < Lk; k0 += TK) {
    __syncthreads();
    for (int e = t; e < TK * V4; e += 256) {
      int rr = e / V4, cc = e - rr * V4;
      Ks[rr * STR + cc] = *(const float4*)(kbase + (size_t)(k0 + rr) * E + cc * 4);
      Vs[rr * STR + cc] = *(const float4*)(vbase + (size_t)(k0 + rr) * E + cc * 4);
    }
    __syncthreads();
#pragma unroll 1
    for (int g = 0; g < TK / KS; g += 4) {
      float sc[QPT][4];
#pragma unroll
      for (int jj = 0; jj < 4; jj++) {
        int kl = (g + jj) * KS + ki;
        float sh[QPT];
#pragma unroll
        for (int r = 0; r < QPT; r++) sh[r] = 0.f;
        const float4* kr = &Ks[kl * STR + dh * V4H];
#pragma unroll
        for (int c = 0; c < V4H; c++) {
          float4 kv = kr[c];
#pragma unroll
          for (int r = 0; r < QPT; r++)
            sh[r] += qr[r][4 * c] * kv.x + qr[r][4 * c + 1] * kv.y
                   + qr[r][4 * c + 2] * kv.z + qr[r][4 * c + 3] * kv.w;
        }
#pragma unroll
        for (int r = 0; r < QPT; r++)
          sc[r][jj] = (sh[r] + __shfl_xor(sh[r], 1)) * scale;
      }
#pragma unroll
      for (int r = 0; r < QPT; r++) {
        float tm = fmaxf(fmaxf(sc[r][0], sc[r][1]), fmaxf(sc[r][2], sc[r][3]));
        float nm = fmaxf(m[r], tm);
        float a = __expf(m[r] - nm);
        m[r] = nm;
        float ls = l[r] * a;
#pragma unroll
        for (int d = 0; d < HH; d++) O[r][d] *= a;
#pragma unroll
        for (int jj = 0; jj < 4; jj++) { sc[r][jj] = __expf(sc[r][jj] - nm); ls += sc[r][jj]; }
        l[r] = ls;
      }
#pragma unroll
      for (int jj = 0; jj < 4; jj++) {
        int kl = (g + jj) * KS + ki;
        const float4* vr = &Vs[kl * STR + dh * V4H];
#pragma unroll
        for (int c = 0; c < V4H; c++) {
          float4 v4 = vr[c];
#pragma unroll
          for (int r = 0; r < QPT; r++) {
            O[r][4 * c]     += sc[r][jj] * v4.x;
            O[r][4 * c + 1] += sc[r][jj] * v4.y;
            O[r][4 * c + 2] += sc[r][jj] * v4.z;
            O[r][4 * c + 3] += sc[r][jj] * v4.w;
          }
        }
      }
    }
  }
#pragma unroll
  for (int r = 0; r < QPT; r++) {
    float M = m[r];
#pragma unroll
    for (int mask = 2; mask < 2 * KS; mask <<= 1) M = fmaxf(M, __shfl_xor(M, mask));
    float w = __expf(m[r] - M);
    float ll = l[r] * w;
#pragma unroll
    for (int mask = 2; mask < 2 * KS; mask <<= 1) ll += __shfl_xor(ll, mask);
    float inv = 1.f / ll;
#pragma unroll
    for (int d = 0; d < HH; d++) {
      float x = O[r][d] * w;
#pragma unroll
      for (int mask = 2; mask < 2 * KS; mask <<= 1) x += __shfl_xor(x, mask);
      O[r][d] = x * inv;
    }
  }
  if (ki == 0) {
    float* obase = o + ((size_t)b * Lq + q0) * E + h * HD + dh * HH;
#pragma unroll
    for (int r = 0; r < QPT; r++)
#pragma unroll
      for (int d = 0; d < HH; d++) obase[(size_t)r * E + d] = O[r][d];
  }
}

// =================== BN (train-mode) stats & apply ===================
__global__ void bn_stats_kernel(const float* __restrict__ x, float* __restrict__ stats,
                                int R, int C) {
  int c = blockIdx.x; int t = threadIdx.x;
  __shared__ float red[8];
  float s = 0.f;
  for (int r = t; r < R; r += blockDim.x) s += x[(size_t)r * C + c];
  for (int off = 32; off; off >>= 1) s += __shfl_down(s, off);
  if ((t & 63) == 0) red[t >> 6] = s;
  __syncthreads();
  if (t == 0) { float a = red[0]; for (int w = 1; w < (int)(blockDim.x >> 6); w++) a += red[w]; red[0] = a; }
  __syncthreads();
  float mean = red[0] / (float)R;
  __syncthreads();
  float s2 = 0.f;
  for (int r = t; r < R; r += blockDim.x) { float d = x[(size_t)r * C + c] - mean; s2 += d * d; }
  for (int off = 32; off; off >>= 1) s2 += __shfl_down(s2, off);
  if ((t & 63) == 0) red[t >> 6] = s2;
  __syncthreads();
  if (t == 0) {
    float a = red[0]; for (int w = 1; w < (int)(blockDim.x >> 6); w++) a += red[w];
    stats[c] = mean; stats[C + c] = a / (float)R;
  }
}

__global__ void bn_apply_kernel(float* __restrict__ x, const float* __restrict__ stats,
                                const float* __restrict__ g, const float* __restrict__ b2,
                                int total, int C) {
  int id = blockIdx.x * blockDim.x + threadIdx.x;
  if (id >= total) return;
  int c = id % C;
  float y = (x[id] - stats[c]) / sqrtf(stats[C + c] + 1e-5f) * g[c] + b2[c];
  x[id] = fmaxf(y, 0.f);
}

// =================== final conv1x1 (xs transposed) ===================
__global__ void final_kernel(const float* __restrict__ fmf, const float* __restrict__ W,
                             const float* __restrict__ bias, float* __restrict__ out) {
  int nb = blockIdx.x * 8;
  int o = threadIdx.x;
  __shared__ float xs[1024][8];
  for (int u = 0; u < 8; u++)
    for (int c = threadIdx.x; c < 1024; c += 256) xs[c][u] = fmf[(size_t)(nb + u) * 1024 + c];
  __syncthreads();
  float acc[8] = {0, 0, 0, 0, 0, 0, 0, 0};
  const float* w = W + (size_t)o * 1024;
  for (int c = 0; c < 1024; c++) {
    float wv = w[c];
    float4 xa = *(const float4*)&xs[c][0];
    float4 xb = *(const float4*)&xs[c][4];
    acc[0] += xa.x * wv; acc[1] += xa.y * wv; acc[2] += xa.z * wv; acc[3] += xa.w * wv;
    acc[4] += xb.x * wv; acc[5] += xb.y * wv; acc[6] += xb.z * wv; acc[7] += xb.w * wv;
  }
  float bv = bias[o];
#pragma unroll
  for (int u = 0; u < 8; u++) {
    int r = nb + u; int b = r >> 10; int n = r & 1023;
    out[((size_t)(b * 256 + o) << 10) + n] = acc[u] + bv;
  }
}

// =================== launch ===================
extern "C" void kernel_launch(void* const* d_in, const int* in_sizes, int n_in,
                              void* d_out, int out_size, void* d_ws, size_t ws_size,
                              hipStream_t stream) {
  (void)in_sizes; (void)n_in; (void)out_size;
  const float* vertices = (const float*)d_in[0];
  const float* d0       = (const float*)d_in[1];
  const float* g0       = (const float*)d_in[2];
  const float* be0      = (const float*)d_in[3];
  const float* w1       = (const float*)d_in[4];
  const float* b1       = (const float*)d_in[5];
  const float* dir1     = (const float*)d_in[6];
  const float* g1       = (const float*)d_in[7];
  const float* be1      = (const float*)d_in[8];
  const float* w2       = (const float*)d_in[9];
  const float* b2       = (const float*)d_in[10];
  const float* dir2     = (const float*)d_in[11];
  const float* g2       = (const float*)d_in[12];
  const float* be2      = (const float*)d_in[13];
  const float* w3       = (const float*)d_in[14];
  const float* b3       = (const float*)d_in[15];
  const float* dir3     = (const float*)d_in[16];
  const float* g3       = (const float*)d_in[17];
  const float* be3      = (const float*)d_in[18];
  const float* token    = (const float*)d_in[19];
  const float* a1_in_w  = (const float*)d_in[20];
  const float* a1_in_b  = (const float*)d_in[21];
  const float* a1_out_w = (const float*)d_in[22];
  const float* a1_out_b = (const float*)d_in[23];
  const float* ffn1_w   = (const float*)d_in[24];
  const float* ffn1_b   = (const float*)d_in[25];
  const float* bg       = (const float*)d_in[26];
  const float* bbp      = (const float*)d_in[27];
  const float* ffn2_w   = (const float*)d_in[28];
  const float* ffn2_b   = (const float*)d_in[29];
  const float* a2_in_w  = (const float*)d_in[30];
  const float* a2_in_b  = (const float*)d_in[31];
  const float* a2_out_w = (const float*)d_in[32];
  const float* a2_out_b = (const float*)d_in[33];
  const float* w7       = (const float*)d_in[34];
  const float* b7       = (const float*)d_in[35];
  const float* dir7     = (const float*)d_in[36];
  const float* g4       = (const float*)d_in[37];
  const float* be4      = (const float*)d_in[38];
  const float* c8_w     = (const float*)d_in[39];
  const float* c8_b     = (const float*)d_in[40];
  float* out = (float*)d_out;
  float* ws = (float*)d_ws;

  if (ws_size < 78568448u) return;

  float* FO     = ws + 0;
  float* S1     = ws + 8388608;
  float* S2     = ws + 12582912;
  float* S3     = ws + 13631488;
  float* QUERY2 = ws + 14680064;
  float* CROSS  = ws + 15728640;
  float* FM1P   = ws + 16777216;
  float* FM3P   = FM1P + 262144;
  float* TOK    = FM3P + 262144;
  float* Q1     = TOK + 262144;
  float* K1     = Q1 + 262144;
  float* VA1    = K1 + 262144;
  float* ATT1   = VA1 + 262144;
  float* K2     = ATT1 + 262144;
  float* V2     = K2 + 262144;
  float* V1     = V2 + 262144;
  float* BNST   = V1 + 12288;
  int* IDX20_0  = (int*)(BNST + 512);
  int* IDX4_0   = IDX20_0 + 327680;
  int* IDX20_1  = IDX4_0 + 65536;
  int* IDX4_1   = IDX20_1 + 81920;
  int* SEL1     = IDX4_1 + 16384;
  int* SEL2     = SEL1 + 1024;
  // perm scratch: transient, overlaps IDX20_0 (knn16 writes that only later)
  unsigned long long* PK = (unsigned long long*)IDX20_0;  // 4096 u64 (8-aligned)
  int* PT1 = IDX20_0 + 8192;                              // 4096 ints

  // jax.random.permutation via rank-based stable sort (== bitonic result)
  perm_keys_kernel<<<16, 256, 0, stream>>>(1u, 0, 4096, PK);
  perm_rank_kernel<<<32, 256, 0, stream>>>(PK, nullptr, PT1, 4096, 4096);
  perm_keys_kernel<<<16, 256, 0, stream>>>(1u, 1, 4096, PK);
  perm_rank_kernel<<<32, 256, 0, stream>>>(PK, PT1, SEL1, 4096, 1024);
  perm_keys_kernel<<<4, 256, 0, stream>>>(2u, 0, 1024, PK);
  perm_rank_kernel<<<8, 256, 0, stream>>>(PK, nullptr, SEL2, 1024, 256);

  knn_lex_kernel<32, 2><<<4 * 4096, 128, 0, stream>>>(vertices, 4096, IDX20_0, IDX4_0);
  conv_surface_kernel<<<4 * 4096, 64, 0, stream>>>(vertices, IDX20_0, d0, g0, be0, S2, 4096);
  gemm_io_kernel<<<dim3(2048, 1), 128, 0, stream>>>(S2, w1, b1, FO, 16384, 32, 128);
  combine_kernel<1><<<16384, 64, 0, stream>>>(vertices, IDX20_0, FO, dir1, g1, be1, S1, 4096, 64);
  pool_select_kernel<<<4096, 64, 0, stream>>>(S1, IDX4_0, SEL1, vertices, V1, FM1P, 4096, 1024, 64);

  knn_1w_lex_kernel<16><<<4 * 1024, 64, 0, stream>>>(V1, 1024, IDX20_1, IDX4_1);
  gemm_io_kernel<<<dim3(512, 1), 256, 0, stream>>>(FM1P, w2, b2, FO, 4096, 64, 256);
  combine_kernel<1><<<4096, 128, 0, stream>>>(V1, IDX20_1, FO, dir2, g2, be2, S2, 1024, 128);
  gemm_io_kernel<<<dim3(512, 2), 256, 0, stream>>>(S2, w3, b3, FO, 4096, 128, 512);
  combine_kernel<1><<<4096, 256, 0, stream>>>(V1, IDX20_1, FO, dir3, g3, be3, S3, 1024, 256);
  pool_select_kernel<<<1024, 256, 0, stream>>>(S3, IDX4_1, SEL2, nullptr, nullptr, FM3P, 1024, 256, 256);

  // MHA1 (tok as Q, fm1p as KV) + residual
  tok_kernel<<<1024, 256, 0, stream>>>(token, TOK);
  linear_oi_kernel<<<512, 64, 0, stream>>>(TOK, a1_in_w, a1_in_b, nullptr, Q1, 4096, 64, 64);
  linear_oi_kernel<<<512, 64, 0, stream>>>(FM1P, a1_in_w + 64 * 64, a1_in_b + 64, nullptr, K1, 4096, 64, 64);
  linear_oi_kernel<<<512, 64, 0, stream>>>(FM1P, a1_in_w + 128 * 64, a1_in_b + 128, nullptr, VA1, 4096, 64, 64);
  attn_tiled<16, 4, 8><<<256, 256, 0, stream>>>(Q1, K1, VA1, ATT1, 1024, 1024, 4, 0.25f);
  linear_oi_kernel<<<512, 64, 0, stream>>>(ATT1, a1_out_w, a1_out_b, FM1P, S3, 4096, 64, 64);

  // FFN
  linear_oi_kernel<<<512, 256, 0, stream>>>(S3, ffn1_w, ffn1_b, nullptr, S2, 4096, 64, 256);
  bn_stats_kernel<<<256, 256, 0, stream>>>(S2, BNST, 4096, 256);
  bn_apply_kernel<<<4096, 256, 0, stream>>>(S2, BNST, bg, bbp, 4096 * 256, 256);
  linear_oi_kernel<<<512, 256, 0, stream>>>(S2, ffn2_w, ffn2_b, nullptr, QUERY2, 4096, 256, 256);

  // MHA2 (query2 as Q, fm3p as KV) + residual
  linear_oi_kernel<<<512, 256, 0, stream>>>(QUERY2, a2_in_w, a2_in_b, nullptr, S3, 4096, 256, 256);
  linear_oi_kernel<<<128, 256, 0, stream>>>(FM3P, a2_in_w + 256 * 256, a2_in_b + 256, nullptr, K2, 1024, 256, 256);
  linear_oi_kernel<<<128, 256, 0, stream>>>(FM3P, a2_in_w + 512 * 256, a2_in_b + 512, nullptr, V2, 1024, 256, 256);
  attn_tiled<64, 2, 8><<<512, 256, 0, stream>>>(S3, K2, V2, S1, 1024, 256, 4, 0.125f);
  linear_oi_kernel<<<512, 256, 0, stream>>>(S1, a2_out_w, a2_out_b, QUERY2, CROSS, 4096, 256, 256);

  // conv_layer7 + final conv1x1
  gemm_io_kernel<<<dim3(512, 8), 256, 0, stream>>>(CROSS, w7, b7, FO, 4096, 256, 2048);
  combine_kernel<4><<<4096, 256, 0, stream>>>(V1, IDX20_1, FO, dir7, g4, be4, S1, 1024, 1024);
  final_kernel<<<512, 256, 0, stream>>>(S1, c8_w, c8_b, out);
}

// Round 9
// 962.807 us; speedup vs baseline: 1.2969x; 1.2969x over previous
//
#include <hip/hip_runtime.h>
#include <stdint.h>
#include <stddef.h>

#define FINF __builtin_inff()

// =================== Threefry-2x32 (JAX-compatible) ===================
__device__ inline void tf2x32(uint32_t k0, uint32_t k1, uint32_t x0, uint32_t x1,
                              uint32_t* o0, uint32_t* o1) {
  uint32_t ks2 = k0 ^ k1 ^ 0x1BD11BDAu;
  uint32_t v0 = x0 + k0, v1 = x1 + k1;
#define TFR(r) { v0 += v1; v1 = (v1 << (r)) | (v1 >> (32 - (r))); v1 ^= v0; }
  TFR(13) TFR(15) TFR(26) TFR(6)
  v0 += k1;  v1 += ks2 + 1u;
  TFR(17) TFR(29) TFR(16) TFR(24)
  v0 += ks2; v1 += k0 + 2u;
  TFR(13) TFR(15) TFR(26) TFR(6)
  v0 += k0;  v1 += k1 + 3u;
  TFR(17) TFR(29) TFR(16) TFR(24)
  v0 += k1;  v1 += ks2 + 4u;
  TFR(13) TFR(15) TFR(26) TFR(6)
  v0 += ks2; v1 += k0 + 5u;
#undef TFR
  *o0 = v0; *o1 = v1;
}

// subkey for round r of jax.random.permutation key chain:
// kst_0 = {0, seed}; subkey_r = tf(kst_r, (0,1)); kst_{r+1} = tf(kst_r, (0,0))
__device__ inline void perm_subkey(uint32_t seed, int round, uint32_t* s0, uint32_t* s1) {
  uint32_t k0 = 0u, k1 = seed;
  for (int r = 0; r < round; r++) {
    uint32_t a0, a1; tf2x32(k0, k1, 0u, 0u, &a0, &a1);
    k0 = a0; k1 = a1;
  }
  tf2x32(k0, k1, 0u, 1u, s0, s1);
}

// One stable-sort pass of jax.random.permutation, rank-select formulation
// (HW-verified math in R8; now keygen is fused and the scan runs from LDS).
// Every block regenerates all n keys (deterministic) into LDS, then 4 threads
// per row count rank = #{j: key_j < key_i}; out[rank] = vin ? vin[i] : i.
__global__ __launch_bounds__(256) void perm_pass_kernel(uint32_t seed, int round, int n,
                                                        const int* __restrict__ vin,
                                                        int* __restrict__ vout, int m) {
  __shared__ unsigned long long lk[4096];
  __shared__ int part[256];
  uint32_t s0, s1; perm_subkey(seed, round, &s0, &s1);
  int t = threadIdx.x;
  for (int j = t; j < n; j += 256) {
    uint32_t y0, y1; tf2x32(s0, s1, 0u, (uint32_t)j, &y0, &y1);
    lk[j] = ((unsigned long long)(y0 ^ y1) << 32) | (unsigned)j;
  }
  __syncthreads();
  int r = blockIdx.x * 64 + (t & 63);
  int q = t >> 6;
  unsigned long long ki = lk[r];
  int cnt = 0;
  int j0 = q * (n >> 2), j1 = j0 + (n >> 2);
  for (int j = j0; j < j1; j++) cnt += (lk[j] < ki) ? 1 : 0;
  part[t] = cnt;
  __syncthreads();
  if (t < 64) {
    int rank = part[t] + part[t + 64] + part[t + 128] + part[t + 192];
    if (rank < m) vout[rank] = vin ? vin[r] : r;
  }
}

// ---- wave-wide argmin of per-lane heads (proven primitives) ----------------
__device__ inline void wave_argmin2(float head_d, int head_i, float* Mo, int* wio) {
  float M = head_d;
#pragma unroll
  for (int off = 1; off < 64; off <<= 1) M = fminf(M, __shfl_xor(M, off));
  int cand = (head_d == M) ? head_i : 0x7fffffff;
#pragma unroll
  for (int off = 1; off < 64; off <<= 1) cand = min(cand, __shfl_xor(cand, off));
  *Mo = M; *wio = cand;
}

// =================== KNN (N=4096): WAVES waves/row + rank merge ===============
// Pop-shift window: head at round r is the (wins<=r)-th sorted entry, so only
// entries 0..21 can ever reach head in 21 rounds -> shift min(CNT-1,21) pairs.
template <int CNT, int WAVES>
__global__ __launch_bounds__(64 * WAVES) void knn_lex_kernel(const float* __restrict__ verts,
                                                             int N,
                                                             int* __restrict__ idx20,
                                                             int* __restrict__ idx4) {
  constexpr int SH = (CNT - 1 < 21) ? (CNT - 1) : 21;
  int row = blockIdx.x; int b = row / N, i = row - b * N;
  int t = threadIdx.x; int w = t >> 6; int lane = t & 63;
  const float* vb = verts + (size_t)b * N * 3;
  float xi = vb[i * 3], yi = vb[i * 3 + 1], zi = vb[i * 3 + 2];
  float sqi = (xi * xi + yi * yi) + zi * zi;

  int base = w * (N / WAVES) + lane;
  float qd[CNT]; int qi[CNT];
#pragma unroll
  for (int m = 0; m < CNT; m++) {
    int j = base + m * 64;
    float xj = vb[j * 3], yj = vb[j * 3 + 1], zj = vb[j * 3 + 2];
    float sqj = (xj * xj + yj * yj) + zj * zj;
    float dot = (xi * xj + yi * yj) + zi * zj;
    qd[m] = sqi + sqj - 2.f * dot;
    qi[m] = j;
  }
  // per-lane register bitonic sort ascending on dist
#pragma unroll
  for (int k = 2; k <= CNT; k <<= 1)
#pragma unroll
    for (int j = k >> 1; j > 0; j >>= 1)
#pragma unroll
      for (int m = 0; m < CNT; m++) {
        int l = m ^ j;
        if (l > m) {
          bool up = ((m & k) == 0);
          bool sw = up ? (qd[m] > qd[l]) : (qd[m] < qd[l]);
          float td = sw ? qd[l] : qd[m]; qd[l] = sw ? qd[m] : qd[l]; qd[m] = td;
          int ti = sw ? qi[l] : qi[m]; qi[l] = sw ? qi[m] : qi[l]; qi[m] = ti;
        }
      }

  __shared__ float wd[WAVES][21];
  __shared__ int wi[WAVES][21];
  for (int r = 0; r < 21; r++) {
    float M; int widx;
    wave_argmin2(qd[0], qi[0], &M, &widx);
    if (lane == 0) { wd[w][r] = M; wi[w][r] = widx; }
    bool win = (qi[0] == widx);
#pragma unroll
    for (int m = 0; m < SH; m++) {
      qd[m] = win ? qd[m + 1] : qd[m];
      qi[m] = win ? qi[m + 1] : qi[m];
    }
    if (SH == CNT - 1) {  // lane can drain only when CNT < 22
      if (win) { qd[CNT - 1] = FINF; qi[CNT - 1] = 0x7fffffff; }
    }
  }
  __syncthreads();
  // rank merge of the WAVES sorted 21-lists
  if (lane < 21) {
    float d0 = wd[w][lane]; int i0 = wi[w][lane];
    int rank = lane;
#pragma unroll
    for (int w2 = 0; w2 < WAVES; w2++) {
      if (w2 == w) continue;
      for (int p = 0; p < 21; p++) {
        float ld = wd[w2][p]; int li = wi[w2][p];
        rank += (ld < d0 || (ld == d0 && li < i0)) ? 1 : 0;
      }
    }
    if (rank >= 1 && rank <= 20) idx20[(size_t)row * 20 + (rank - 1)] = i0;
    if (rank >= 1 && rank <= 4)  idx4[(size_t)row * 4 + (rank - 1)] = i0;
  }
}

// =================== KNN (N=1024): ONE wave/row, direct rank output ==========
template <int CNT>
__global__ __launch_bounds__(64) void knn_1w_lex_kernel(const float* __restrict__ verts, int N,
                                                        int* __restrict__ idx20,
                                                        int* __restrict__ idx4) {
  int row = blockIdx.x; int b = row / N, i = row - b * N;
  int lane = threadIdx.x;
  const float* vb = verts + (size_t)b * N * 3;
  float xi = vb[i * 3], yi = vb[i * 3 + 1], zi = vb[i * 3 + 2];
  float sqi = (xi * xi + yi * yi) + zi * zi;

  float qd[CNT]; int qi[CNT];
#pragma unroll
  for (int m = 0; m < CNT; m++) {
    int j = lane + m * 64;
    float xj = vb[j * 3], yj = vb[j * 3 + 1], zj = vb[j * 3 + 2];
    float sqj = (xj * xj + yj * yj) + zj * zj;
    float dot = (xi * xj + yi * yj) + zi * zj;
    qd[m] = sqi + sqj - 2.f * dot;
    qi[m] = j;
  }
#pragma unroll
  for (int k = 2; k <= CNT; k <<= 1)
#pragma unroll
    for (int j = k >> 1; j > 0; j >>= 1)
#pragma unroll
      for (int m = 0; m < CNT; m++) {
        int l = m ^ j;
        if (l > m) {
          bool up = ((m & k) == 0);
          bool sw = up ? (qd[m] > qd[l]) : (qd[m] < qd[l]);
          float td = sw ? qd[l] : qd[m]; qd[l] = sw ? qd[m] : qd[l]; qd[m] = td;
          int ti = sw ? qi[l] : qi[m]; qi[l] = sw ? qi[m] : qi[l]; qi[m] = ti;
        }
      }
  for (int r = 0; r < 21; r++) {
    float M; int widx;
    wave_argmin2(qd[0], qi[0], &M, &widx);
    if (lane == 0 && r >= 1) {
      idx20[(size_t)row * 20 + (r - 1)] = widx;
      if (r <= 4) idx4[(size_t)row * 4 + (r - 1)] = widx;
    }
    bool win = (qi[0] == widx);
#pragma unroll
    for (int m = 0; m < CNT - 1; m++) {
      qd[m] = win ? qd[m + 1] : qd[m];
      qi[m] = win ? qi[m + 1] : qi[m];
    }
    if (win) { qd[CNT - 1] = FINF; qi[CNT - 1] = 0x7fffffff; }
  }
}

// =================== conv_surface + LN + relu -> fm0 (C=32) ===================
__global__ void conv_surface_kernel(const float* __restrict__ verts,
                                    const int* __restrict__ idx20,
                                    const float* __restrict__ d0,
                                    const float* __restrict__ g, const float* __restrict__ be,
                                    float* __restrict__ out, int N) {
  int row = blockIdx.x; int b = row / N, i = row - b * N;
  int t = threadIdx.x;
  __shared__ float nd[20][3];
  const float* vb = verts + (size_t)b * N * 3;
  if (t < 20) {
    int j = idx20[(size_t)row * 20 + t];
    float dx = vb[j * 3] - vb[i * 3], dy = vb[j * 3 + 1] - vb[i * 3 + 1], dz = vb[j * 3 + 2] - vb[i * 3 + 2];
    float n2 = sqrtf(dx * dx + dy * dy + dz * dz); n2 = fmaxf(n2, 1e-12f);
    nd[t][0] = dx / n2; nd[t][1] = dy / n2; nd[t][2] = dz / n2;
  }
  __syncthreads();
  float x = 0.f;
  if (t < 32) {
    float a = d0[t], bb2 = d0[32 + t], c = d0[64 + t];
    float nrm = fmaxf(sqrtf(a * a + bb2 * bb2 + c * c), 1e-12f);
    a /= nrm; bb2 /= nrm; c /= nrm;
    float mx = -FINF;
    for (int kk = 0; kk < 20; kk++) {
      float th = fmaxf(nd[kk][0] * a + nd[kk][1] * bb2 + nd[kk][2] * c, 0.f);
      mx = fmaxf(mx, th);
    }
    x = mx;
  }
  float s = x;
  for (int off = 32; off; off >>= 1) s += __shfl_xor(s, off);
  float mean = s / 32.f;
  float dev = (t < 32) ? x - mean : 0.f;
  float s2 = dev * dev;
  for (int off = 32; off; off >>= 1) s2 += __shfl_xor(s2, off);
  float var = s2 / 32.f;
  if (t < 32) {
    float y = (x - mean) / sqrtf(var + 1e-6f) * g[t] + be[t];
    out[(size_t)row * 32 + t] = fmaxf(y, 0.f);
  }
}

// =================== GEMM: y = x(R,I) @ W(I,O) + bias (xs transposed) =========
__global__ void gemm_io_kernel(const float* __restrict__ x, const float* __restrict__ W,
                               const float* __restrict__ bias, float* __restrict__ y,
                               int R, int I, int O) {
  int rb = blockIdx.x * 8;
  int o = blockIdx.y * blockDim.x + threadIdx.x;
  __shared__ float xs[256][8];
  for (int u = 0; u < 8; u++)
    for (int i2 = threadIdx.x; i2 < I; i2 += blockDim.x) xs[i2][u] = x[(size_t)(rb + u) * I + i2];
  __syncthreads();
  float a[8] = {0, 0, 0, 0, 0, 0, 0, 0};
  for (int k2 = 0; k2 < I; k2++) {
    float wv = W[(size_t)k2 * O + o];
    float4 xa = *(const float4*)&xs[k2][0];
    float4 xb = *(const float4*)&xs[k2][4];
    a[0] += xa.x * wv; a[1] += xa.y * wv; a[2] += xa.z * wv; a[3] += xa.w * wv;
    a[4] += xb.x * wv; a[5] += xb.y * wv; a[6] += xb.z * wv; a[7] += xb.w * wv;
  }
  float bv = bias[o];
#pragma unroll
  for (int u = 0; u < 8; u++) y[(size_t)(rb + u) * O + o] = a[u] + bv;
}

// =================== conv_layer combine (k-loop hoisted) ===================
template <int CPT>
__global__ void combine_kernel(const float* __restrict__ verts, const int* __restrict__ idx20,
                               const float* __restrict__ fo, const float* __restrict__ dirs,
                               const float* __restrict__ g, const float* __restrict__ be,
                               float* __restrict__ out, int N, int C) {
  int row = blockIdx.x; int b = row / N, i = row - b * N;
  int t = threadIdx.x, bs = blockDim.x;
  __shared__ float nd[20][3];
  __shared__ int nidx[20];
  __shared__ float red[8];
  const float* vb = verts + (size_t)b * N * 3;
  if (t < 20) {
    int j = idx20[(size_t)row * 20 + t];
    nidx[t] = j;
    float dx = vb[j * 3] - vb[i * 3], dy = vb[j * 3 + 1] - vb[i * 3 + 1], dz = vb[j * 3 + 2] - vb[i * 3 + 2];
    float n2 = fmaxf(sqrtf(dx * dx + dy * dy + dz * dz), 1e-12f);
    nd[t][0] = dx / n2; nd[t][1] = dy / n2; nd[t][2] = dz / n2;
  }
  __syncthreads();
  const float* fob = fo + (size_t)b * N * 2 * C;
  const float* forow = fob + (size_t)i * 2 * C;
  float da[CPT], db[CPT], dc[CPT], mx[CPT];
#pragma unroll
  for (int u = 0; u < CPT; u++) {
    int c = t + u * bs;
    float a = dirs[c], bb = dirs[C + c], cc = dirs[2 * C + c];
    float nrm = fmaxf(sqrtf(a * a + bb * bb + cc * cc), 1e-12f);
    da[u] = a / nrm; db[u] = bb / nrm; dc[u] = cc / nrm;
    mx[u] = -FINF;
  }
  for (int kk = 0; kk < 20; kk++) {
    float n0 = nd[kk][0], n1 = nd[kk][1], n2v = nd[kk][2];
    const float* sup = fob + (size_t)nidx[kk] * 2 * C + C + t;
#pragma unroll
    for (int u = 0; u < CPT; u++) {
      float th = fmaxf(n0 * da[u] + n1 * db[u] + n2v * dc[u], 0.f);
      mx[u] = fmaxf(mx[u], th * sup[u * bs]);
    }
  }
  float xv[CPT];
  float ssum = 0.f;
#pragma unroll
  for (int u = 0; u < CPT; u++) {
    int c = t + u * bs;
    float val = forow[c] + mx[u];
    xv[u] = val; ssum += val;
  }
  int nw = bs >> 6;
  for (int off = 32; off; off >>= 1) ssum += __shfl_down(ssum, off);
  if ((t & 63) == 0) red[t >> 6] = ssum;
  __syncthreads();
  if (t == 0) { float s = red[0]; for (int w = 1; w < nw; w++) s += red[w]; red[0] = s; }
  __syncthreads();
  float mean = red[0] / (float)C;
  __syncthreads();
  float s2 = 0.f;
#pragma unroll
  for (int u = 0; u < CPT; u++) { float d2 = xv[u] - mean; s2 += d2 * d2; }
  for (int off = 32; off; off >>= 1) s2 += __shfl_down(s2, off);
  if ((t & 63) == 0) red[t >> 6] = s2;
  __syncthreads();
  if (t == 0) { float s = red[0]; for (int w = 1; w < nw; w++) s += red[w]; red[0] = s; }
  __syncthreads();
  float inv = 1.0f / sqrtf(red[0] / (float)C + 1e-6f);
#pragma unroll
  for (int u = 0; u < CPT; u++) {
    int c = t + u * bs;
    float yv = (xv[u] - mean) * inv * g[c] + be[c];
    out[(size_t)row * C + c] = fmaxf(yv, 0.f);
  }
}

// =================== pool (max over 4 NN) + row-select ===================
__global__ void pool_select_kernel(const float* __restrict__ fm, const int* __restrict__ idx4,
                                   const int* __restrict__ sel, const float* __restrict__ vin,
                                   float* __restrict__ vout, float* __restrict__ out,
                                   int N, int M, int C) {
  int row = blockIdx.x; int b = row / M, r = row - b * M;
  int s = sel[r];
  const int* id = idx4 + ((size_t)b * N + s) * 4;
  int i0 = id[0], i1 = id[1], i2 = id[2], i3 = id[3];
  const float* fb = fm + (size_t)b * N * C;
  for (int c = threadIdx.x; c < C; c += blockDim.x) {
    float m = fmaxf(fmaxf(fb[(size_t)i0 * C + c], fb[(size_t)i1 * C + c]),
                    fmaxf(fb[(size_t)i2 * C + c], fb[(size_t)i3 * C + c]));
    out[((size_t)b * M + r) * C + c] = m;
  }
  if (vout != nullptr && threadIdx.x < 3)
    vout[((size_t)b * M + r) * 3 + threadIdx.x] = vin[((size_t)b * N + s) * 3 + threadIdx.x];
}

// =================== token transpose ===================
__global__ void tok_kernel(const float* __restrict__ token, float* __restrict__ tok) {
  int id = blockIdx.x * 256 + threadIdx.x;
  int e = id & 63; int n = (id >> 6) & 1023;
  tok[id] = token[e * 1024 + n];
}

// =================== linear: y = x(R,I) @ W(O,I)^T + bias (+res) ===================
__global__ void linear_oi_kernel(const float* __restrict__ x, const float* __restrict__ W,
                                 const float* __restrict__ bias, const float* __restrict__ res,
                                 float* __restrict__ y, int R, int I, int O) {
  int rb = blockIdx.x * 8;
  int o = threadIdx.x;
  __shared__ float xs[8][256];
  for (int u = 0; u < 8; u++)
    for (int i2 = threadIdx.x; i2 < I; i2 += O) xs[u][i2] = x[(size_t)(rb + u) * I + i2];
  __syncthreads();
  float a[8] = {0, 0, 0, 0, 0, 0, 0, 0};
  const float* w = W + (size_t)o * I;
  for (int k2 = 0; k2 < I; k2++) {
    float wv = w[k2];
#pragma unroll
    for (int u = 0; u < 8; u++) a[u] += xs[u][k2] * wv;
  }
  float bv = bias[o];
#pragma unroll
  for (int u = 0; u < 8; u++) {
    float val = a[u] + bv;
    if (res) val += res[(size_t)(rb + u) * O + o];
    y[(size_t)(rb + u) * O + o] = val;
  }
}

// =================== tiled flash attention ===================
template <int HD, int QPT, int KS>
__global__ __launch_bounds__(256) void attn_tiled(
    const float* __restrict__ q, const float* __restrict__ kk,
    const float* __restrict__ vv, float* __restrict__ o,
    int Lq, int Lk, int H, float scale) {
  constexpr int TK = 64;
  constexpr int QG = 256 / (2 * KS);
  constexpr int QPB = QG * QPT;
  constexpr int V4 = HD / 4;
  constexpr int STR = V4 + 1;
  constexpr int HH = HD / 2;
  constexpr int V4H = HH / 4;

  __shared__ float4 Ks[TK * STR];
  __shared__ float4 Vs[TK * STR];

  int t = threadIdx.x;
  int dh = t & 1;
  int ki = (t >> 1) & (KS - 1);
  int qg = t / (2 * KS);
  int nqt = Lq / QPB;
  int qt = blockIdx.x % nqt, bh = blockIdx.x / nqt;
  int h = bh % H, b = bh / H;
  int E = H * HD;
  int q0 = qt * QPB + qg * QPT;

  const float* qbase = q + ((size_t)b * Lq + q0) * E + h * HD + dh * HH;
  const float* kbase = kk + (size_t)b * Lk * E + h * HD;
  const float* vbase = vv + (size_t)b * Lk * E + h * HD;

  float qr[QPT][HH], O[QPT][HH], m[QPT], l[QPT];
#pragma unroll
  for (int r = 0; r < QPT; r++) {
    m[r] = -FINF; l[r] = 0.f;
#pragma unroll
    for (int d = 0; d < HH; d++) { qr[r][d] = qbase[(size_t)r * E + d]; O[r][d] = 0.f; }
  }

  for (int k0 = 0; k0 < Lk; k0 += TK) {
    __syncthreads();
    for (int e = t; e < TK * V4; e += 256) {
      int rr = e / V4, cc = e - rr * V4;
      Ks[rr * STR + cc] = *(const float4*)(kbase + (size_t)(k0 + rr) * E + cc * 4);
      Vs[rr * STR + cc] = *(const float4*)(vbase + (size_t)(k0 + rr) * E + cc * 4);
    }
    __syncthreads();
#pragma unroll 1
    for (int g = 0; g < TK / KS; g += 4) {
      float sc[QPT][4];
#pragma unroll
      for (int jj = 0; jj < 4; jj++) {
        int kl = (g + jj) * KS + ki;
        float sh[QPT];
#pragma unroll
        for (int r = 0; r < QPT; r++) sh[r] = 0.f;
        const float4* kr = &Ks[kl * STR + dh * V4H];
#pragma unroll
        for (int c = 0; c < V4H; c++) {
          float4 kv = kr[c];
#pragma unroll
          for (int r = 0; r < QPT; r++)
            sh[r] += qr[r][4 * c] * kv.x + qr[r][4 * c + 1] * kv.y
                   + qr[r][4 * c + 2] * kv.z + qr[r][4 * c + 3] * kv.w;
        }
#pragma unroll
        for (int r = 0; r < QPT; r++)
          sc[r][jj] = (sh[r] + __shfl_xor(sh[r], 1)) * scale;
      }
#pragma unroll
      for (int r = 0; r < QPT; r++) {
        float tm = fmaxf(fmaxf(sc[r][0], sc[r][1]), fmaxf(sc[r][2], sc[r][3]));
        float nm = fmaxf(m[r], tm);
        float a = __expf(m[r] - nm);
        m[r] = nm;
        float ls = l[r] * a;
#pragma unroll
        for (int d = 0; d < HH; d++) O[r][d] *= a;
#pragma unroll
        for (int jj = 0; jj < 4; jj++) { sc[r][jj] = __expf(sc[r][jj] - nm); ls += sc[r][jj]; }
        l[r] = ls;
      }
#pragma unroll
      for (int jj = 0; jj < 4; jj++) {
        int kl = (g + jj) * KS + ki;
        const float4* vr = &Vs[kl * STR + dh * V4H];
#pragma unroll
        for (int c = 0; c < V4H; c++) {
          float4 v4 = vr[c];
#pragma unroll
          for (int r = 0; r < QPT; r++) {
            O[r][4 * c]     += sc[r][jj] * v4.x;
            O[r][4 * c + 1] += sc[r][jj] * v4.y;
            O[r][4 * c + 2] += sc[r][jj] * v4.z;
            O[r][4 * c + 3] += sc[r][jj] * v4.w;
          }
        }
      }
    }
  }
#pragma unroll
  for (int r = 0; r < QPT; r++) {
    float M = m[r];
#pragma unroll
    for (int mask = 2; mask < 2 * KS; mask <<= 1) M = fmaxf(M, __shfl_xor(M, mask));
    float w = __expf(m[r] - M);
    float ll = l[r] * w;
#pragma unroll
    for (int mask = 2; mask < 2 * KS; mask <<= 1) ll += __shfl_xor(ll, mask);
    float inv = 1.f / ll;
#pragma unroll
    for (int d = 0; d < HH; d++) {
      float x = O[r][d] * w;
#pragma unroll
      for (int mask = 2; mask < 2 * KS; mask <<= 1) x += __shfl_xor(x, mask);
      O[r][d] = x * inv;
    }
  }
  if (ki == 0) {
    float* obase = o + ((size_t)b * Lq + q0) * E + h * HD + dh * HH;
#pragma unroll
    for (int r = 0; r < QPT; r++)
#pragma unroll
      for (int d = 0; d < HH; d++) obase[(size_t)r * E + d] = O[r][d];
  }
}

// =================== BN (train-mode) stats & apply ===================
__global__ void bn_stats_kernel(const float* __restrict__ x, float* __restrict__ stats,
                                int R, int C) {
  int c = blockIdx.x; int t = threadIdx.x;
  __shared__ float red[8];
  float s = 0.f;
  for (int r = t; r < R; r += blockDim.x) s += x[(size_t)r * C + c];
  for (int off = 32; off; off >>= 1) s += __shfl_down(s, off);
  if ((t & 63) == 0) red[t >> 6] = s;
  __syncthreads();
  if (t == 0) { float a = red[0]; for (int w = 1; w < (int)(blockDim.x >> 6); w++) a += red[w]; red[0] = a; }
  __syncthreads();
  float mean = red[0] / (float)R;
  __syncthreads();
  float s2 = 0.f;
  for (int r = t; r < R; r += blockDim.x) { float d = x[(size_t)r * C + c] - mean; s2 += d * d; }
  for (int off = 32; off; off >>= 1) s2 += __shfl_down(s2, off);
  if ((t & 63) == 0) red[t >> 6] = s2;
  __syncthreads();
  if (t == 0) {
    float a = red[0]; for (int w = 1; w < (int)(blockDim.x >> 6); w++) a += red[w];
    stats[c] = mean; stats[C + c] = a / (float)R;
  }
}

__global__ void bn_apply_kernel(float* __restrict__ x, const float* __restrict__ stats,
                                const float* __restrict__ g, const float* __restrict__ b2,
                                int total, int C) {
  int id = blockIdx.x * blockDim.x + threadIdx.x;
  if (id >= total) return;
  int c = id % C;
  float y = (x[id] - stats[c]) / sqrtf(stats[C + c] + 1e-5f) * g[c] + b2[c];
  x[id] = fmaxf(y, 0.f);
}

// =================== final conv1x1 (xs transposed) ===================
__global__ void final_kernel(const float* __restrict__ fmf, const float* __restrict__ W,
                             const float* __restrict__ bias, float* __restrict__ out) {
  int nb = blockIdx.x * 8;
  int o = threadIdx.x;
  __shared__ float xs[1024][8];
  for (int u = 0; u < 8; u++)
    for (int c = threadIdx.x; c < 1024; c += 256) xs[c][u] = fmf[(size_t)(nb + u) * 1024 + c];
  __syncthreads();
  float acc[8] = {0, 0, 0, 0, 0, 0, 0, 0};
  const float* w = W + (size_t)o * 1024;
  for (int c = 0; c < 1024; c++) {
    float wv = w[c];
    float4 xa = *(const float4*)&xs[c][0];
    float4 xb = *(const float4*)&xs[c][4];
    acc[0] += xa.x * wv; acc[1] += xa.y * wv; acc[2] += xa.z * wv; acc[3] += xa.w * wv;
    acc[4] += xb.x * wv; acc[5] += xb.y * wv; acc[6] += xb.z * wv; acc[7] += xb.w * wv;
  }
  float bv = bias[o];
#pragma unroll
  for (int u = 0; u < 8; u++) {
    int r = nb + u; int b = r >> 10; int n = r & 1023;
    out[((size_t)(b * 256 + o) << 10) + n] = acc[u] + bv;
  }
}

// =================== launch ===================
extern "C" void kernel_launch(void* const* d_in, const int* in_sizes, int n_in,
                              void* d_out, int out_size, void* d_ws, size_t ws_size,
                              hipStream_t stream) {
  (void)in_sizes; (void)n_in; (void)out_size;
  const float* vertices = (const float*)d_in[0];
  const float* d0       = (const float*)d_in[1];
  const float* g0       = (const float*)d_in[2];
  const float* be0      = (const float*)d_in[3];
  const float* w1       = (const float*)d_in[4];
  const float* b1       = (const float*)d_in[5];
  const float* dir1     = (const float*)d_in[6];
  const float* g1       = (const float*)d_in[7];
  const float* be1      = (const float*)d_in[8];
  const float* w2       = (const float*)d_in[9];
  const float* b2       = (const float*)d_in[10];
  const float* dir2     = (const float*)d_in[11];
  const float* g2       = (const float*)d_in[12];
  const float* be2      = (const float*)d_in[13];
  const float* w3       = (const float*)d_in[14];
  const float* b3       = (const float*)d_in[15];
  const float* dir3     = (const float*)d_in[16];
  const float* g3       = (const float*)d_in[17];
  const float* be3      = (const float*)d_in[18];
  const float* token    = (const float*)d_in[19];
  const float* a1_in_w  = (const float*)d_in[20];
  const float* a1_in_b  = (const float*)d_in[21];
  const float* a1_out_w = (const float*)d_in[22];
  const float* a1_out_b = (const float*)d_in[23];
  const float* ffn1_w   = (const float*)d_in[24];
  const float* ffn1_b   = (const float*)d_in[25];
  const float* bg       = (const float*)d_in[26];
  const float* bbp      = (const float*)d_in[27];
  const float* ffn2_w   = (const float*)d_in[28];
  const float* ffn2_b   = (const float*)d_in[29];
  const float* a2_in_w  = (const float*)d_in[30];
  const float* a2_in_b  = (const float*)d_in[31];
  const float* a2_out_w = (const float*)d_in[32];
  const float* a2_out_b = (const float*)d_in[33];
  const float* w7       = (const float*)d_in[34];
  const float* b7       = (const float*)d_in[35];
  const float* dir7     = (const float*)d_in[36];
  const float* g4       = (const float*)d_in[37];
  const float* be4      = (const float*)d_in[38];
  const float* c8_w     = (const float*)d_in[39];
  const float* c8_b     = (const float*)d_in[40];
  float* out = (float*)d_out;
  float* ws = (float*)d_ws;

  if (ws_size < 78568448u) return;

  float* FO     = ws + 0;
  float* S1     = ws + 8388608;
  float* S2     = ws + 12582912;
  float* S3     = ws + 13631488;
  float* QUERY2 = ws + 14680064;
  float* CROSS  = ws + 15728640;
  float* FM1P   = ws + 16777216;
  float* FM3P   = FM1P + 262144;
  float* TOK    = FM3P + 262144;
  float* Q1     = TOK + 262144;
  float* K1     = Q1 + 262144;
  float* VA1    = K1 + 262144;
  float* ATT1   = VA1 + 262144;
  float* K2     = ATT1 + 262144;
  float* V2     = K2 + 262144;
  float* V1     = V2 + 262144;
  float* BNST   = V1 + 12288;
  int* IDX20_0  = (int*)(BNST + 512);
  int* IDX4_0   = IDX20_0 + 327680;
  int* IDX20_1  = IDX4_0 + 65536;
  int* IDX4_1   = IDX20_1 + 81920;
  int* SEL1     = IDX4_1 + 16384;
  int* SEL2     = SEL1 + 1024;
  // perm scratch: transient, overlaps IDX20_0 (knn16 writes that only later)
  int* PT1 = IDX20_0;  // 4096 ints

  // jax.random.permutation via rank-select stable sort (math HW-verified R8)
  perm_pass_kernel<<<64, 256, 0, stream>>>(1u, 0, 4096, nullptr, PT1, 4096);
  perm_pass_kernel<<<64, 256, 0, stream>>>(1u, 1, 4096, PT1, SEL1, 1024);
  perm_pass_kernel<<<16, 256, 0, stream>>>(2u, 0, 1024, nullptr, SEL2, 256);

  knn_lex_kernel<32, 2><<<4 * 4096, 128, 0, stream>>>(vertices, 4096, IDX20_0, IDX4_0);
  conv_surface_kernel<<<4 * 4096, 64, 0, stream>>>(vertices, IDX20_0, d0, g0, be0, S2, 4096);
  gemm_io_kernel<<<dim3(2048, 1), 128, 0, stream>>>(S2, w1, b1, FO, 16384, 32, 128);
  combine_kernel<1><<<16384, 64, 0, stream>>>(vertices, IDX20_0, FO, dir1, g1, be1, S1, 4096, 64);
  pool_select_kernel<<<4096, 64, 0, stream>>>(S1, IDX4_0, SEL1, vertices, V1, FM1P, 4096, 1024, 64);

  knn_1w_lex_kernel<16><<<4 * 1024, 64, 0, stream>>>(V1, 1024, IDX20_1, IDX4_1);
  gemm_io_kernel<<<dim3(512, 1), 256, 0, stream>>>(FM1P, w2, b2, FO, 4096, 64, 256);
  combine_kernel<1><<<4096, 128, 0, stream>>>(V1, IDX20_1, FO, dir2, g2, be2, S2, 1024, 128);
  gemm_io_kernel<<<dim3(512, 2), 256, 0, stream>>>(S2, w3, b3, FO, 4096, 128, 512);
  combine_kernel<1><<<4096, 256, 0, stream>>>(V1, IDX20_1, FO, dir3, g3, be3, S3, 1024, 256);
  pool_select_kernel<<<1024, 256, 0, stream>>>(S3, IDX4_1, SEL2, nullptr, nullptr, FM3P, 1024, 256, 256);

  // MHA1 (tok as Q, fm1p as KV) + residual
  tok_kernel<<<1024, 256, 0, stream>>>(token, TOK);
  linear_oi_kernel<<<512, 64, 0, stream>>>(TOK, a1_in_w, a1_in_b, nullptr, Q1, 4096, 64, 64);
  linear_oi_kernel<<<512, 64, 0, stream>>>(FM1P, a1_in_w + 64 * 64, a1_in_b + 64, nullptr, K1, 4096, 64, 64);
  linear_oi_kernel<<<512, 64, 0, stream>>>(FM1P, a1_in_w + 128 * 64, a1_in_b + 128, nullptr, VA1, 4096, 64, 64);
  attn_tiled<16, 4, 8><<<256, 256, 0, stream>>>(Q1, K1, VA1, ATT1, 1024, 1024, 4, 0.25f);
  linear_oi_kernel<<<512, 64, 0, stream>>>(ATT1, a1_out_w, a1_out_b, FM1P, S3, 4096, 64, 64);

  // FFN
  linear_oi_kernel<<<512, 256, 0, stream>>>(S3, ffn1_w, ffn1_b, nullptr, S2, 4096, 64, 256);
  bn_stats_kernel<<<256, 256, 0, stream>>>(S2, BNST, 4096, 256);
  bn_apply_kernel<<<4096, 256, 0, stream>>>(S2, BNST, bg, bbp, 4096 * 256, 256);
  linear_oi_kernel<<<512, 256, 0, stream>>>(S2, ffn2_w, ffn2_b, nullptr, QUERY2, 4096, 256, 256);

  // MHA2 (query2 as Q, fm3p as KV) + residual
  linear_oi_kernel<<<512, 256, 0, stream>>>(QUERY2, a2_in_w, a2_in_b, nullptr, S3, 4096, 256, 256);
  linear_oi_kernel<<<128, 256, 0, stream>>>(FM3P, a2_in_w + 256 * 256, a2_in_b + 256, nullptr, K2, 1024, 256, 256);
  linear_oi_kernel<<<128, 256, 0, stream>>>(FM3P, a2_in_w + 512 * 256, a2_in_b + 512, nullptr, V2, 1024, 256, 256);
  attn_tiled<64, 2, 8><<<512, 256, 0, stream>>>(S3, K2, V2, S1, 1024, 256, 4, 0.125f);
  linear_oi_kernel<<<512, 256, 0, stream>>>(S1, a2_out_w, a2_out_b, QUERY2, CROSS, 4096, 256, 256);

  // conv_layer7 + final conv1x1
  gemm_io_kernel<<<dim3(512, 8), 256, 0, stream>>>(CROSS, w7, b7, FO, 4096, 256, 2048);
  combine_kernel<4><<<4096, 256, 0, stream>>>(V1, IDX20_1, FO, dir7, g4, be4, S1, 1024, 1024);
  final_kernel<<<512, 256, 0, stream>>>(S1, c8_w, c8_b, out);
}

// Round 10
// 934.445 us; speedup vs baseline: 1.3362x; 1.0304x over previous
//
#include <hip/hip_runtime.h>
#include <stdint.h>
#include <stddef.h>

#define FINF __builtin_inff()

// =================== Threefry-2x32 (JAX-compatible) ===================
__device__ inline void tf2x32(uint32_t k0, uint32_t k1, uint32_t x0, uint32_t x1,
                              uint32_t* o0, uint32_t* o1) {
  uint32_t ks2 = k0 ^ k1 ^ 0x1BD11BDAu;
  uint32_t v0 = x0 + k0, v1 = x1 + k1;
#define TFR(r) { v0 += v1; v1 = (v1 << (r)) | (v1 >> (32 - (r))); v1 ^= v0; }
  TFR(13) TFR(15) TFR(26) TFR(6)
  v0 += k1;  v1 += ks2 + 1u;
  TFR(17) TFR(29) TFR(16) TFR(24)
  v0 += ks2; v1 += k0 + 2u;
  TFR(13) TFR(15) TFR(26) TFR(6)
  v0 += k0;  v1 += k1 + 3u;
  TFR(17) TFR(29) TFR(16) TFR(24)
  v0 += k1;  v1 += ks2 + 4u;
  TFR(13) TFR(15) TFR(26) TFR(6)
  v0 += ks2; v1 += k0 + 5u;
#undef TFR
  *o0 = v0; *o1 = v1;
}

__device__ inline void perm_subkey(uint32_t seed, int round, uint32_t* s0, uint32_t* s1) {
  uint32_t k0 = 0u, k1 = seed;
  for (int r = 0; r < round; r++) {
    uint32_t a0, a1; tf2x32(k0, k1, 0u, 0u, &a0, &a1);
    k0 = a0; k1 = a1;
  }
  tf2x32(k0, k1, 0u, 1u, s0, s1);
}

// Rank-select stable-sort pass (HW-verified R8/R9), LDS-resident keys.
__global__ __launch_bounds__(256) void perm_pass_kernel(uint32_t seed, int round, int n,
                                                        const int* __restrict__ vin,
                                                        int* __restrict__ vout, int m) {
  __shared__ unsigned long long lk[4096];
  __shared__ int part[256];
  uint32_t s0, s1; perm_subkey(seed, round, &s0, &s1);
  int t = threadIdx.x;
  for (int j = t; j < n; j += 256) {
    uint32_t y0, y1; tf2x32(s0, s1, 0u, (uint32_t)j, &y0, &y1);
    lk[j] = ((unsigned long long)(y0 ^ y1) << 32) | (unsigned)j;
  }
  __syncthreads();
  int r = blockIdx.x * 64 + (t & 63);
  int q = t >> 6;
  unsigned long long ki = lk[r];
  int cnt = 0;
  int j0 = q * (n >> 2), j1 = j0 + (n >> 2);
  for (int j = j0; j < j1; j++) cnt += (lk[j] < ki) ? 1 : 0;
  part[t] = cnt;
  __syncthreads();
  if (t < 64) {
    int rank = part[t] + part[t + 64] + part[t + 128] + part[t + 192];
    if (rank < m) vout[rank] = vin ? vin[r] : r;
  }
}

// Fused first passes: blocks 0..63 = seed1 round0 (n=4096 -> PT1),
// blocks 64..79 = seed2 round0 (n=1024, m=256 -> SEL2).  vin==identity both.
__global__ __launch_bounds__(256) void perm_passA_kernel(int* __restrict__ pt1,
                                                         int* __restrict__ sel2) {
  __shared__ unsigned long long lk[4096];
  __shared__ int part[256];
  bool big = (blockIdx.x < 64);
  uint32_t seed = big ? 1u : 2u;
  int n = big ? 4096 : 1024;
  int m = big ? 4096 : 256;
  int* vout = big ? pt1 : sel2;
  int blk = big ? blockIdx.x : (blockIdx.x - 64);
  uint32_t s0, s1; perm_subkey(seed, 0, &s0, &s1);
  int t = threadIdx.x;
  for (int j = t; j < n; j += 256) {
    uint32_t y0, y1; tf2x32(s0, s1, 0u, (uint32_t)j, &y0, &y1);
    lk[j] = ((unsigned long long)(y0 ^ y1) << 32) | (unsigned)j;
  }
  __syncthreads();
  int r = blk * 64 + (t & 63);
  int q = t >> 6;
  unsigned long long ki = lk[r];
  int cnt = 0;
  int j0 = q * (n >> 2), j1 = j0 + (n >> 2);
  for (int j = j0; j < j1; j++) cnt += (lk[j] < ki) ? 1 : 0;
  part[t] = cnt;
  __syncthreads();
  if (t < 64) {
    int rank = part[t] + part[t + 64] + part[t + 128] + part[t + 192];
    if (rank < m) vout[rank] = r;
  }
}

// ---- wave-wide argmin of per-lane heads (proven primitives) ----------------
__device__ inline void wave_argmin2(float head_d, int head_i, float* Mo, int* wio) {
  float M = head_d;
#pragma unroll
  for (int off = 1; off < 64; off <<= 1) M = fminf(M, __shfl_xor(M, off));
  int cand = (head_d == M) ? head_i : 0x7fffffff;
#pragma unroll
  for (int off = 1; off < 64; off <<= 1) cand = min(cand, __shfl_xor(cand, off));
  *Mo = M; *wio = cand;
}

// =================== KNN (N=4096): WAVES waves/row + rank merge ===============
// Candidates u64-packed (bits(d)<<32)|idx in REGISTERS: d>=0 on this data so
// u32 order == float order; sort compare = 1 u64 cmp (exact (d,idx) lex).
// Extraction keeps the proven float/idx shfl butterflies.
template <int CNT, int WAVES>
__global__ __launch_bounds__(64 * WAVES) void knn_lex_kernel(const float* __restrict__ verts,
                                                             int N,
                                                             int* __restrict__ idx20,
                                                             int* __restrict__ idx4) {
  constexpr int SH = (CNT - 1 < 21) ? (CNT - 1) : 21;
  int row = blockIdx.x; int b = row / N, i = row - b * N;
  int t = threadIdx.x; int w = t >> 6; int lane = t & 63;
  const float* vb = verts + (size_t)b * N * 3;
  float xi = vb[i * 3], yi = vb[i * 3 + 1], zi = vb[i * 3 + 2];
  float sqi = (xi * xi + yi * yi) + zi * zi;

  int base = w * (N / WAVES) + lane;
  unsigned long long qe[CNT];
#pragma unroll
  for (int m = 0; m < CNT; m++) {
    int j = base + m * 64;
    float xj = vb[j * 3], yj = vb[j * 3 + 1], zj = vb[j * 3 + 2];
    float sqj = (xj * xj + yj * yj) + zj * zj;
    float dot = (xi * xj + yi * yj) + zi * zj;
    float d = sqi + sqj - 2.f * dot;
    qe[m] = ((unsigned long long)__float_as_uint(d) << 32) | (unsigned)j;
  }
  // per-lane register bitonic sort ascending on u64 (lex (d, idx))
#pragma unroll
  for (int k = 2; k <= CNT; k <<= 1)
#pragma unroll
    for (int j = k >> 1; j > 0; j >>= 1)
#pragma unroll
      for (int m = 0; m < CNT; m++) {
        int l = m ^ j;
        if (l > m) {
          unsigned long long a = qe[m], c = qe[l];
          bool up = ((m & k) == 0);
          bool sw = up ? (a > c) : (a < c);
          qe[m] = sw ? c : a;
          qe[l] = sw ? a : c;
        }
      }

  __shared__ float wd[WAVES][21];
  __shared__ int wi[WAVES][21];
  for (int r = 0; r < 21; r++) {
    float hd = __uint_as_float((uint32_t)(qe[0] >> 32));
    int hi = (int)(qe[0] & 0xffffffffu);
    float M; int widx;
    wave_argmin2(hd, hi, &M, &widx);
    if (lane == 0) { wd[w][r] = M; wi[w][r] = widx; }
    bool win = (hi == widx);
#pragma unroll
    for (int m = 0; m < SH; m++) qe[m] = win ? qe[m + 1] : qe[m];
    if (SH == CNT - 1) {
      if (win) qe[CNT - 1] = 0x7F8000007FFFFFFFull;  // (+inf, idx max)
    }
  }
  __syncthreads();
  // rank merge of the WAVES sorted 21-lists
  if (lane < 21) {
    float d0 = wd[w][lane]; int i0 = wi[w][lane];
    int rank = lane;
#pragma unroll
    for (int w2 = 0; w2 < WAVES; w2++) {
      if (w2 == w) continue;
      for (int p = 0; p < 21; p++) {
        float ld = wd[w2][p]; int li = wi[w2][p];
        rank += (ld < d0 || (ld == d0 && li < i0)) ? 1 : 0;
      }
    }
    if (rank >= 1 && rank <= 20) idx20[(size_t)row * 20 + (rank - 1)] = i0;
    if (rank >= 1 && rank <= 4)  idx4[(size_t)row * 4 + (rank - 1)] = i0;
  }
}

// =================== KNN (N=1024): ONE wave/row, u64 register queue ===========
template <int CNT>
__global__ __launch_bounds__(64) void knn_1w_lex_kernel(const float* __restrict__ verts, int N,
                                                        int* __restrict__ idx20,
                                                        int* __restrict__ idx4) {
  int row = blockIdx.x; int b = row / N, i = row - b * N;
  int lane = threadIdx.x;
  const float* vb = verts + (size_t)b * N * 3;
  float xi = vb[i * 3], yi = vb[i * 3 + 1], zi = vb[i * 3 + 2];
  float sqi = (xi * xi + yi * yi) + zi * zi;

  unsigned long long qe[CNT];
#pragma unroll
  for (int m = 0; m < CNT; m++) {
    int j = lane + m * 64;
    float xj = vb[j * 3], yj = vb[j * 3 + 1], zj = vb[j * 3 + 2];
    float sqj = (xj * xj + yj * yj) + zj * zj;
    float dot = (xi * xj + yi * yj) + zi * zj;
    float d = sqi + sqj - 2.f * dot;
    qe[m] = ((unsigned long long)__float_as_uint(d) << 32) | (unsigned)j;
  }
#pragma unroll
  for (int k = 2; k <= CNT; k <<= 1)
#pragma unroll
    for (int j = k >> 1; j > 0; j >>= 1)
#pragma unroll
      for (int m = 0; m < CNT; m++) {
        int l = m ^ j;
        if (l > m) {
          unsigned long long a = qe[m], c = qe[l];
          bool up = ((m & k) == 0);
          bool sw = up ? (a > c) : (a < c);
          qe[m] = sw ? c : a;
          qe[l] = sw ? a : c;
        }
      }
  for (int r = 0; r < 21; r++) {
    float hd = __uint_as_float((uint32_t)(qe[0] >> 32));
    int hi = (int)(qe[0] & 0xffffffffu);
    float M; int widx;
    wave_argmin2(hd, hi, &M, &widx);
    if (lane == 0 && r >= 1) {
      idx20[(size_t)row * 20 + (r - 1)] = widx;
      if (r <= 4) idx4[(size_t)row * 4 + (r - 1)] = widx;
    }
    bool win = (hi == widx);
#pragma unroll
    for (int m = 0; m < CNT - 1; m++) qe[m] = win ? qe[m + 1] : qe[m];
    if (win) qe[CNT - 1] = 0x7F8000007FFFFFFFull;
  }
}

// =================== conv_surface + LN + relu -> fm0 (C=32) ===================
__global__ void conv_surface_kernel(const float* __restrict__ verts,
                                    const int* __restrict__ idx20,
                                    const float* __restrict__ d0,
                                    const float* __restrict__ g, const float* __restrict__ be,
                                    float* __restrict__ out, int N) {
  int row = blockIdx.x; int b = row / N, i = row - b * N;
  int t = threadIdx.x;
  __shared__ float nd[20][3];
  const float* vb = verts + (size_t)b * N * 3;
  if (t < 20) {
    int j = idx20[(size_t)row * 20 + t];
    float dx = vb[j * 3] - vb[i * 3], dy = vb[j * 3 + 1] - vb[i * 3 + 1], dz = vb[j * 3 + 2] - vb[i * 3 + 2];
    float n2 = sqrtf(dx * dx + dy * dy + dz * dz); n2 = fmaxf(n2, 1e-12f);
    nd[t][0] = dx / n2; nd[t][1] = dy / n2; nd[t][2] = dz / n2;
  }
  __syncthreads();
  float x = 0.f;
  if (t < 32) {
    float a = d0[t], bb2 = d0[32 + t], c = d0[64 + t];
    float nrm = fmaxf(sqrtf(a * a + bb2 * bb2 + c * c), 1e-12f);
    a /= nrm; bb2 /= nrm; c /= nrm;
    float mx = -FINF;
    for (int kk = 0; kk < 20; kk++) {
      float th = fmaxf(nd[kk][0] * a + nd[kk][1] * bb2 + nd[kk][2] * c, 0.f);
      mx = fmaxf(mx, th);
    }
    x = mx;
  }
  float s = x;
  for (int off = 32; off; off >>= 1) s += __shfl_xor(s, off);
  float mean = s / 32.f;
  float dev = (t < 32) ? x - mean : 0.f;
  float s2 = dev * dev;
  for (int off = 32; off; off >>= 1) s2 += __shfl_xor(s2, off);
  float var = s2 / 32.f;
  if (t < 32) {
    float y = (x - mean) / sqrtf(var + 1e-6f) * g[t] + be[t];
    out[(size_t)row * 32 + t] = fmaxf(y, 0.f);
  }
}

// =================== GEMM: y = x(R,I) @ W(I,O) + bias, 8 rows/block ===========
__global__ void gemm_io_kernel(const float* __restrict__ x, const float* __restrict__ W,
                               const float* __restrict__ bias, float* __restrict__ y,
                               int R, int I, int O) {
  int rb = blockIdx.x * 8;
  int o = blockIdx.y * blockDim.x + threadIdx.x;
  __shared__ float xs[256][8];
  for (int u = 0; u < 8; u++)
    for (int i2 = threadIdx.x; i2 < I; i2 += blockDim.x) xs[i2][u] = x[(size_t)(rb + u) * I + i2];
  __syncthreads();
  float a[8] = {0, 0, 0, 0, 0, 0, 0, 0};
  for (int k2 = 0; k2 < I; k2++) {
    float wv = W[(size_t)k2 * O + o];
    float4 xa = *(const float4*)&xs[k2][0];
    float4 xb = *(const float4*)&xs[k2][4];
    a[0] += xa.x * wv; a[1] += xa.y * wv; a[2] += xa.z * wv; a[3] += xa.w * wv;
    a[4] += xb.x * wv; a[5] += xb.y * wv; a[6] += xb.z * wv; a[7] += xb.w * wv;
  }
  float bv = bias[o];
#pragma unroll
  for (int u = 0; u < 8; u++) y[(size_t)(rb + u) * O + o] = a[u] + bv;
}

// =================== GEMM 16 rows/block (for w7: halves W re-reads) ===========
__global__ void gemm_io16_kernel(const float* __restrict__ x, const float* __restrict__ W,
                                 const float* __restrict__ bias, float* __restrict__ y,
                                 int R, int I, int O) {
  int rb = blockIdx.x * 16;
  int o = blockIdx.y * blockDim.x + threadIdx.x;
  __shared__ float xs[256][16];
  for (int u = 0; u < 16; u++)
    for (int i2 = threadIdx.x; i2 < I; i2 += blockDim.x) xs[i2][u] = x[(size_t)(rb + u) * I + i2];
  __syncthreads();
  float a[16];
#pragma unroll
  for (int u = 0; u < 16; u++) a[u] = 0.f;
  for (int k2 = 0; k2 < I; k2++) {
    float wv = W[(size_t)k2 * O + o];
    float4 x0 = *(const float4*)&xs[k2][0];
    float4 x1 = *(const float4*)&xs[k2][4];
    float4 x2 = *(const float4*)&xs[k2][8];
    float4 x3 = *(const float4*)&xs[k2][12];
    a[0] += x0.x * wv; a[1] += x0.y * wv; a[2] += x0.z * wv; a[3] += x0.w * wv;
    a[4] += x1.x * wv; a[5] += x1.y * wv; a[6] += x1.z * wv; a[7] += x1.w * wv;
    a[8] += x2.x * wv; a[9] += x2.y * wv; a[10] += x2.z * wv; a[11] += x2.w * wv;
    a[12] += x3.x * wv; a[13] += x3.y * wv; a[14] += x3.z * wv; a[15] += x3.w * wv;
  }
  float bv = bias[o];
#pragma unroll
  for (int u = 0; u < 16; u++) y[(size_t)(rb + u) * O + o] = a[u] + bv;
}

// =================== conv_layer combine (k-loop hoisted) ===================
template <int CPT>
__global__ void combine_kernel(const float* __restrict__ verts, const int* __restrict__ idx20,
                               const float* __restrict__ fo, const float* __restrict__ dirs,
                               const float* __restrict__ g, const float* __restrict__ be,
                               float* __restrict__ out, int N, int C) {
  int row = blockIdx.x; int b = row / N, i = row - b * N;
  int t = threadIdx.x, bs = blockDim.x;
  __shared__ float nd[20][3];
  __shared__ int nidx[20];
  __shared__ float red[8];
  const float* vb = verts + (size_t)b * N * 3;
  if (t < 20) {
    int j = idx20[(size_t)row * 20 + t];
    nidx[t] = j;
    float dx = vb[j * 3] - vb[i * 3], dy = vb[j * 3 + 1] - vb[i * 3 + 1], dz = vb[j * 3 + 2] - vb[i * 3 + 2];
    float n2 = fmaxf(sqrtf(dx * dx + dy * dy + dz * dz), 1e-12f);
    nd[t][0] = dx / n2; nd[t][1] = dy / n2; nd[t][2] = dz / n2;
  }
  __syncthreads();
  const float* fob = fo + (size_t)b * N * 2 * C;
  const float* forow = fob + (size_t)i * 2 * C;
  float da[CPT], db[CPT], dc[CPT], mx[CPT];
#pragma unroll
  for (int u = 0; u < CPT; u++) {
    int c = t + u * bs;
    float a = dirs[c], bb = dirs[C + c], cc = dirs[2 * C + c];
    float nrm = fmaxf(sqrtf(a * a + bb * bb + cc * cc), 1e-12f);
    da[u] = a / nrm; db[u] = bb / nrm; dc[u] = cc / nrm;
    mx[u] = -FINF;
  }
  for (int kk = 0; kk < 20; kk++) {
    float n0 = nd[kk][0], n1 = nd[kk][1], n2v = nd[kk][2];
    const float* sup = fob + (size_t)nidx[kk] * 2 * C + C + t;
#pragma unroll
    for (int u = 0; u < CPT; u++) {
      float th = fmaxf(n0 * da[u] + n1 * db[u] + n2v * dc[u], 0.f);
      mx[u] = fmaxf(mx[u], th * sup[u * bs]);
    }
  }
  float xv[CPT];
  float ssum = 0.f;
#pragma unroll
  for (int u = 0; u < CPT; u++) {
    int c = t + u * bs;
    float val = forow[c] + mx[u];
    xv[u] = val; ssum += val;
  }
  int nw = bs >> 6;
  for (int off = 32; off; off >>= 1) ssum += __shfl_down(ssum, off);
  if ((t & 63) == 0) red[t >> 6] = ssum;
  __syncthreads();
  if (t == 0) { float s = red[0]; for (int w = 1; w < nw; w++) s += red[w]; red[0] = s; }
  __syncthreads();
  float mean = red[0] / (float)C;
  __syncthreads();
  float s2 = 0.f;
#pragma unroll
  for (int u = 0; u < CPT; u++) { float d2 = xv[u] - mean; s2 += d2 * d2; }
  for (int off = 32; off; off >>= 1) s2 += __shfl_down(s2, off);
  if ((t & 63) == 0) red[t >> 6] = s2;
  __syncthreads();
  if (t == 0) { float s = red[0]; for (int w = 1; w < nw; w++) s += red[w]; red[0] = s; }
  __syncthreads();
  float inv = 1.0f / sqrtf(red[0] / (float)C + 1e-6f);
#pragma unroll
  for (int u = 0; u < CPT; u++) {
    int c = t + u * bs;
    float yv = (xv[u] - mean) * inv * g[c] + be[c];
    out[(size_t)row * C + c] = fmaxf(yv, 0.f);
  }
}

// =================== pool (max over 4 NN) + row-select ===================
__global__ void pool_select_kernel(const float* __restrict__ fm, const int* __restrict__ idx4,
                                   const int* __restrict__ sel, const float* __restrict__ vin,
                                   float* __restrict__ vout, float* __restrict__ out,
                                   int N, int M, int C) {
  int row = blockIdx.x; int b = row / M, r = row - b * M;
  int s = sel[r];
  const int* id = idx4 + ((size_t)b * N + s) * 4;
  int i0 = id[0], i1 = id[1], i2 = id[2], i3 = id[3];
  const float* fb = fm + (size_t)b * N * C;
  for (int c = threadIdx.x; c < C; c += blockDim.x) {
    float m = fmaxf(fmaxf(fb[(size_t)i0 * C + c], fb[(size_t)i1 * C + c]),
                    fmaxf(fb[(size_t)i2 * C + c], fb[(size_t)i3 * C + c]));
    out[((size_t)b * M + r) * C + c] = m;
  }
  if (vout != nullptr && threadIdx.x < 3)
    vout[((size_t)b * M + r) * 3 + threadIdx.x] = vin[((size_t)b * N + s) * 3 + threadIdx.x];
}

// =================== linear: y = x(R,I) @ W(O,I)^T + bias (+res) ===================
__global__ void linear_oi_kernel(const float* __restrict__ x, const float* __restrict__ W,
                                 const float* __restrict__ bias, const float* __restrict__ res,
                                 float* __restrict__ y, int R, int I, int O) {
  int rb = blockIdx.x * 8;
  int o = threadIdx.x;
  __shared__ float xs[8][256];
  for (int u = 0; u < 8; u++)
    for (int i2 = threadIdx.x; i2 < I; i2 += O) xs[u][i2] = x[(size_t)(rb + u) * I + i2];
  __syncthreads();
  float a[8] = {0, 0, 0, 0, 0, 0, 0, 0};
  const float* w = W + (size_t)o * I;
  for (int k2 = 0; k2 < I; k2++) {
    float wv = w[k2];
#pragma unroll
    for (int u = 0; u < 8; u++) a[u] += xs[u][k2] * wv;
  }
  float bv = bias[o];
#pragma unroll
  for (int u = 0; u < 8; u++) {
    float val = a[u] + bv;
    if (res) val += res[(size_t)(rb + u) * O + o];
    y[(size_t)(rb + u) * O + o] = val;
  }
}

// =================== fused QKV for MHA1 (token transpose folded into Q) =======
__global__ __launch_bounds__(64) void qkv1_kernel(const float* __restrict__ token,
                                                  const float* __restrict__ fm1p,
                                                  const float* __restrict__ Win,
                                                  const float* __restrict__ bin,
                                                  float* __restrict__ Q1,
                                                  float* __restrict__ K1,
                                                  float* __restrict__ V1) {
  int ybr = blockIdx.y;
  const float* W = Win + (size_t)ybr * 64 * 64;
  const float* bias = bin + ybr * 64;
  float* out = (ybr == 0) ? Q1 : (ybr == 1) ? K1 : V1;
  int rb = blockIdx.x * 8;
  int o = threadIdx.x;  // 64
  __shared__ float xs[8][64];
  if (ybr == 0) {
    for (int u = 0; u < 8; u++) {
      int n = (rb + u) & 1023;
      xs[u][o] = token[(size_t)o * 1024 + n];  // tok[r][e] = token[e*1024+n]
    }
  } else {
    for (int u = 0; u < 8; u++) xs[u][o] = fm1p[(size_t)(rb + u) * 64 + o];
  }
  __syncthreads();
  float a[8] = {0, 0, 0, 0, 0, 0, 0, 0};
  const float* w = W + (size_t)o * 64;
  for (int k2 = 0; k2 < 64; k2++) {
    float wv = w[k2];
#pragma unroll
    for (int u = 0; u < 8; u++) a[u] += xs[u][k2] * wv;
  }
  float bv = bias[o];
#pragma unroll
  for (int u = 0; u < 8; u++) out[(size_t)(rb + u) * 64 + o] = a[u] + bv;
}

// =================== fused K2/V2 for MHA2 ===================
__global__ __launch_bounds__(256) void kv2_kernel(const float* __restrict__ fm3p,
                                                  const float* __restrict__ Win,
                                                  const float* __restrict__ bin,
                                                  float* __restrict__ K2,
                                                  float* __restrict__ V2) {
  int ybr = blockIdx.y;
  const float* W = Win + (size_t)(1 + ybr) * 256 * 256;
  const float* bias = bin + (1 + ybr) * 256;
  float* out = ybr ? V2 : K2;
  int rb = blockIdx.x * 8;
  int o = threadIdx.x;  // 256
  __shared__ float xs[8][256];
  for (int u = 0; u < 8; u++) xs[u][o] = fm3p[(size_t)(rb + u) * 256 + o];
  __syncthreads();
  float a[8] = {0, 0, 0, 0, 0, 0, 0, 0};
  const float* w = W + (size_t)o * 256;
  for (int k2 = 0; k2 < 256; k2++) {
    float wv = w[k2];
#pragma unroll
    for (int u = 0; u < 8; u++) a[u] += xs[u][k2] * wv;
  }
  float bv = bias[o];
#pragma unroll
  for (int u = 0; u < 8; u++) out[(size_t)(rb + u) * 256 + o] = a[u] + bv;
}

// =================== tiled flash attention ===================
template <int HD, int QPT, int KS>
__global__ __launch_bounds__(256) void attn_tiled(
    const float* __restrict__ q, const float* __restrict__ kk,
    const float* __restrict__ vv, float* __restrict__ o,
    int Lq, int Lk, int H, float scale) {
  constexpr int TK = 64;
  constexpr int QG = 256 / (2 * KS);
  constexpr int QPB = QG * QPT;
  constexpr int V4 = HD / 4;
  constexpr int STR = V4 + 1;
  constexpr int HH = HD / 2;
  constexpr int V4H = HH / 4;

  __shared__ float4 Ks[TK * STR];
  __shared__ float4 Vs[TK * STR];

  int t = threadIdx.x;
  int dh = t & 1;
  int ki = (t >> 1) & (KS - 1);
  int qg = t / (2 * KS);
  int nqt = Lq / QPB;
  int qt = blockIdx.x % nqt, bh = blockIdx.x / nqt;
  int h = bh % H, b = bh / H;
  int E = H * HD;
  int q0 = qt * QPB + qg * QPT;

  const float* qbase = q + ((size_t)b * Lq + q0) * E + h * HD + dh * HH;
  const float* kbase = kk + (size_t)b * Lk * E + h * HD;
  const float* vbase = vv + (size_t)b * Lk * E + h * HD;

  float qr[QPT][HH], O[QPT][HH], m[QPT], l[QPT];
#pragma unroll
  for (int r = 0; r < QPT; r++) {
    m[r] = -FINF; l[r] = 0.f;
#pragma unroll
    for (int d = 0; d < HH; d++) { qr[r][d] = qbase[(size_t)r * E + d]; O[r][d] = 0.f; }
  }

  for (int k0 = 0; k0 < Lk; k0 += TK) {
    __syncthreads();
    for (int e = t; e < TK * V4; e += 256) {
      int rr = e / V4, cc = e - rr * V4;
      Ks[rr * STR + cc] = *(const float4*)(kbase + (size_t)(k0 + rr) * E + cc * 4);
      Vs[rr * STR + cc] = *(const float4*)(vbase + (size_t)(k0 + rr) * E + cc * 4);
    }
    __syncthreads();
#pragma unroll 1
    for (int g = 0; g < TK / KS; g += 4) {
      float sc[QPT][4];
#pragma unroll
      for (int jj = 0; jj < 4; jj++) {
        int kl = (g + jj) * KS + ki;
        float sh[QPT];
#pragma unroll
        for (int r = 0; r < QPT; r++) sh[r] = 0.f;
        const float4* kr = &Ks[kl * STR + dh * V4H];
#pragma unroll
        for (int c = 0; c < V4H; c++) {
          float4 kv = kr[c];
#pragma unroll
          for (int r = 0; r < QPT; r++)
            sh[r] += qr[r][4 * c] * kv.x + qr[r][4 * c + 1] * kv.y
                   + qr[r][4 * c + 2] * kv.z + qr[r][4 * c + 3] * kv.w;
        }
#pragma unroll
        for (int r = 0; r < QPT; r++)
          sc[r][jj] = (sh[r] + __shfl_xor(sh[r], 1)) * scale;
      }
#pragma unroll
      for (int r = 0; r < QPT; r++) {
        float tm = fmaxf(fmaxf(sc[r][0], sc[r][1]), fmaxf(sc[r][2], sc[r][3]));
        float nm = fmaxf(m[r], tm);
        float a = __expf(m[r] - nm);
        m[r] = nm;
        float ls = l[r] * a;
#pragma unroll
        for (int d = 0; d < HH; d++) O[r][d] *= a;
#pragma unroll
        for (int jj = 0; jj < 4; jj++) { sc[r][jj] = __expf(sc[r][jj] - nm); ls += sc[r][jj]; }
        l[r] = ls;
      }
#pragma unroll
      for (int jj = 0; jj < 4; jj++) {
        int kl = (g + jj) * KS + ki;
        const float4* vr = &Vs[kl * STR + dh * V4H];
#pragma unroll
        for (int c = 0; c < V4H; c++) {
          float4 v4 = vr[c];
#pragma unroll
          for (int r = 0; r < QPT; r++) {
            O[r][4 * c]     += sc[r][jj] * v4.x;
            O[r][4 * c + 1] += sc[r][jj] * v4.y;
            O[r][4 * c + 2] += sc[r][jj] * v4.z;
            O[r][4 * c + 3] += sc[r][jj] * v4.w;
          }
        }
      }
    }
  }
#pragma unroll
  for (int r = 0; r < QPT; r++) {
    float M = m[r];
#pragma unroll
    for (int mask = 2; mask < 2 * KS; mask <<= 1) M = fmaxf(M, __shfl_xor(M, mask));
    float w = __expf(m[r] - M);
    float ll = l[r] * w;
#pragma unroll
    for (int mask = 2; mask < 2 * KS; mask <<= 1) ll += __shfl_xor(ll, mask);
    float inv = 1.f / ll;
#pragma unroll
    for (int d = 0; d < HH; d++) {
      float x = O[r][d] * w;
#pragma unroll
      for (int mask = 2; mask < 2 * KS; mask <<= 1) x += __shfl_xor(x, mask);
      O[r][d] = x * inv;
    }
  }
  if (ki == 0) {
    float* obase = o + ((size_t)b * Lq + q0) * E + h * HD + dh * HH;
#pragma unroll
    for (int r = 0; r < QPT; r++)
#pragma unroll
      for (int d = 0; d < HH; d++) obase[(size_t)r * E + d] = O[r][d];
  }
}

// =================== BN (train-mode) stats & apply ===================
__global__ void bn_stats_kernel(const float* __restrict__ x, float* __restrict__ stats,
                                int R, int C) {
  int c = blockIdx.x; int t = threadIdx.x;
  __shared__ float red[8];
  float s = 0.f;
  for (int r = t; r < R; r += blockDim.x) s += x[(size_t)r * C + c];
  for (int off = 32; off; off >>= 1) s += __shfl_down(s, off);
  if ((t & 63) == 0) red[t >> 6] = s;
  __syncthreads();
  if (t == 0) { float a = red[0]; for (int w = 1; w < (int)(blockDim.x >> 6); w++) a += red[w]; red[0] = a; }
  __syncthreads();
  float mean = red[0] / (float)R;
  __syncthreads();
  float s2 = 0.f;
  for (int r = t; r < R; r += blockDim.x) { float d = x[(size_t)r * C + c] - mean; s2 += d * d; }
  for (int off = 32; off; off >>= 1) s2 += __shfl_down(s2, off);
  if ((t & 63) == 0) red[t >> 6] = s2;
  __syncthreads();
  if (t == 0) {
    float a = red[0]; for (int w = 1; w < (int)(blockDim.x >> 6); w++) a += red[w];
    stats[c] = mean; stats[C + c] = a / (float)R;
  }
}

__global__ void bn_apply_kernel(float* __restrict__ x, const float* __restrict__ stats,
                                const float* __restrict__ g, const float* __restrict__ b2,
                                int total, int C) {
  int id = blockIdx.x * blockDim.x + threadIdx.x;
  if (id >= total) return;
  int c = id % C;
  float y = (x[id] - stats[c]) / sqrtf(stats[C + c] + 1e-5f) * g[c] + b2[c];
  x[id] = fmaxf(y, 0.f);
}

// =================== final conv1x1 (xs transposed) ===================
__global__ void final_kernel(const float* __restrict__ fmf, const float* __restrict__ W,
                             const float* __restrict__ bias, float* __restrict__ out) {
  int nb = blockIdx.x * 8;
  int o = threadIdx.x;
  __shared__ float xs[1024][8];
  for (int u = 0; u < 8; u++)
    for (int c = threadIdx.x; c < 1024; c += 256) xs[c][u] = fmf[(size_t)(nb + u) * 1024 + c];
  __syncthreads();
  float acc[8] = {0, 0, 0, 0, 0, 0, 0, 0};
  const float* w = W + (size_t)o * 1024;
  for (int c = 0; c < 1024; c++) {
    float wv = w[c];
    float4 xa = *(const float4*)&xs[c][0];
    float4 xb = *(const float4*)&xs[c][4];
    acc[0] += xa.x * wv; acc[1] += xa.y * wv; acc[2] += xa.z * wv; acc[3] += xa.w * wv;
    acc[4] += xb.x * wv; acc[5] += xb.y * wv; acc[6] += xb.z * wv; acc[7] += xb.w * wv;
  }
  float bv = bias[o];
#pragma unroll
  for (int u = 0; u < 8; u++) {
    int r = nb + u; int b = r >> 10; int n = r & 1023;
    out[((size_t)(b * 256 + o) << 10) + n] = acc[u] + bv;
  }
}

// =================== launch ===================
extern "C" void kernel_launch(void* const* d_in, const int* in_sizes, int n_in,
                              void* d_out, int out_size, void* d_ws, size_t ws_size,
                              hipStream_t stream) {
  (void)in_sizes; (void)n_in; (void)out_size;
  const float* vertices = (const float*)d_in[0];
  const float* d0       = (const float*)d_in[1];
  const float* g0       = (const float*)d_in[2];
  const float* be0      = (const float*)d_in[3];
  const float* w1       = (const float*)d_in[4];
  const float* b1       = (const float*)d_in[5];
  const float* dir1     = (const float*)d_in[6];
  const float* g1       = (const float*)d_in[7];
  const float* be1      = (const float*)d_in[8];
  const float* w2       = (const float*)d_in[9];
  const float* b2       = (const float*)d_in[10];
  const float* dir2     = (const float*)d_in[11];
  const float* g2       = (const float*)d_in[12];
  const float* be2      = (const float*)d_in[13];
  const float* w3       = (const float*)d_in[14];
  const float* b3       = (const float*)d_in[15];
  const float* dir3     = (const float*)d_in[16];
  const float* g3       = (const float*)d_in[17];
  const float* be3      = (const float*)d_in[18];
  const float* token    = (const float*)d_in[19];
  const float* a1_in_w  = (const float*)d_in[20];
  const float* a1_in_b  = (const float*)d_in[21];
  const float* a1_out_w = (const float*)d_in[22];
  const float* a1_out_b = (const float*)d_in[23];
  const float* ffn1_w   = (const float*)d_in[24];
  const float* ffn1_b   = (const float*)d_in[25];
  const float* bg       = (const float*)d_in[26];
  const float* bbp      = (const float*)d_in[27];
  const float* ffn2_w   = (const float*)d_in[28];
  const float* ffn2_b   = (const float*)d_in[29];
  const float* a2_in_w  = (const float*)d_in[30];
  const float* a2_in_b  = (const float*)d_in[31];
  const float* a2_out_w = (const float*)d_in[32];
  const float* a2_out_b = (const float*)d_in[33];
  const float* w7       = (const float*)d_in[34];
  const float* b7       = (const float*)d_in[35];
  const float* dir7     = (const float*)d_in[36];
  const float* g4       = (const float*)d_in[37];
  const float* be4      = (const float*)d_in[38];
  const float* c8_w     = (const float*)d_in[39];
  const float* c8_b     = (const float*)d_in[40];
  float* out = (float*)d_out;
  float* ws = (float*)d_ws;

  if (ws_size < 78568448u) return;

  float* FO     = ws + 0;
  float* S1     = ws + 8388608;
  float* S2     = ws + 12582912;
  float* S3     = ws + 13631488;
  float* QUERY2 = ws + 14680064;
  float* CROSS  = ws + 15728640;
  float* FM1P   = ws + 16777216;
  float* FM3P   = FM1P + 262144;
  float* TOK    = FM3P + 262144;  // unused (kept for layout stability)
  float* Q1     = TOK + 262144;
  float* K1     = Q1 + 262144;
  float* VA1    = K1 + 262144;
  float* ATT1   = VA1 + 262144;
  float* K2     = ATT1 + 262144;
  float* V2     = K2 + 262144;
  float* V1     = V2 + 262144;
  float* BNST   = V1 + 12288;
  int* IDX20_0  = (int*)(BNST + 512);
  int* IDX4_0   = IDX20_0 + 327680;
  int* IDX20_1  = IDX4_0 + 65536;
  int* IDX4_1   = IDX20_1 + 81920;
  int* SEL1     = IDX4_1 + 16384;
  int* SEL2     = SEL1 + 1024;
  int* PT1 = IDX20_0;  // transient, overlaps IDX20_0 (written later by knn16)

  // jax.random.permutation via rank-select stable sort (HW-verified R8/R9)
  perm_passA_kernel<<<80, 256, 0, stream>>>(PT1, SEL2);
  perm_pass_kernel<<<64, 256, 0, stream>>>(1u, 1, 4096, PT1, SEL1, 1024);

  knn_lex_kernel<32, 2><<<4 * 4096, 128, 0, stream>>>(vertices, 4096, IDX20_0, IDX4_0);
  conv_surface_kernel<<<4 * 4096, 64, 0, stream>>>(vertices, IDX20_0, d0, g0, be0, S2, 4096);
  gemm_io_kernel<<<dim3(2048, 1), 128, 0, stream>>>(S2, w1, b1, FO, 16384, 32, 128);
  combine_kernel<1><<<16384, 64, 0, stream>>>(vertices, IDX20_0, FO, dir1, g1, be1, S1, 4096, 64);
  pool_select_kernel<<<4096, 64, 0, stream>>>(S1, IDX4_0, SEL1, vertices, V1, FM1P, 4096, 1024, 64);

  knn_1w_lex_kernel<16><<<4 * 1024, 64, 0, stream>>>(V1, 1024, IDX20_1, IDX4_1);
  gemm_io_kernel<<<dim3(512, 1), 256, 0, stream>>>(FM1P, w2, b2, FO, 4096, 64, 256);
  combine_kernel<1><<<4096, 128, 0, stream>>>(V1, IDX20_1, FO, dir2, g2, be2, S2, 1024, 128);
  gemm_io_kernel<<<dim3(512, 2), 256, 0, stream>>>(S2, w3, b3, FO, 4096, 128, 512);
  combine_kernel<1><<<4096, 256, 0, stream>>>(V1, IDX20_1, FO, dir3, g3, be3, S3, 1024, 256);
  pool_select_kernel<<<1024, 256, 0, stream>>>(S3, IDX4_1, SEL2, nullptr, nullptr, FM3P, 1024, 256, 256);

  // MHA1 (tok as Q, fm1p as KV) + residual  [QKV fused, token-fold]
  qkv1_kernel<<<dim3(512, 3), 64, 0, stream>>>(token, FM1P, a1_in_w, a1_in_b, Q1, K1, VA1);
  attn_tiled<16, 2, 8><<<512, 256, 0, stream>>>(Q1, K1, VA1, ATT1, 1024, 1024, 4, 0.25f);
  linear_oi_kernel<<<512, 64, 0, stream>>>(ATT1, a1_out_w, a1_out_b, FM1P, S3, 4096, 64, 64);

  // FFN
  linear_oi_kernel<<<512, 256, 0, stream>>>(S3, ffn1_w, ffn1_b, nullptr, S2, 4096, 64, 256);
  bn_stats_kernel<<<256, 256, 0, stream>>>(S2, BNST, 4096, 256);
  bn_apply_kernel<<<4096, 256, 0, stream>>>(S2, BNST, bg, bbp, 4096 * 256, 256);
  linear_oi_kernel<<<512, 256, 0, stream>>>(S2, ffn2_w, ffn2_b, nullptr, QUERY2, 4096, 256, 256);

  // MHA2 (query2 as Q, fm3p as KV) + residual  [K2/V2 fused]
  linear_oi_kernel<<<512, 256, 0, stream>>>(QUERY2, a2_in_w, a2_in_b, nullptr, S3, 4096, 256, 256);
  kv2_kernel<<<dim3(128, 2), 256, 0, stream>>>(FM3P, a2_in_w, a2_in_b, K2, V2);
  attn_tiled<64, 2, 8><<<512, 256, 0, stream>>>(S3, K2, V2, S1, 1024, 256, 4, 0.125f);
  linear_oi_kernel<<<512, 256, 0, stream>>>(S1, a2_out_w, a2_out_b, QUERY2, CROSS, 4096, 256, 256);

  // conv_layer7 + final conv1x1  [w7 via 16-row GEMM]
  gemm_io16_kernel<<<dim3(256, 8), 256, 0, stream>>>(CROSS, w7, b7, FO, 4096, 256, 2048);
  combine_kernel<4><<<4096, 256, 0, stream>>>(V1, IDX20_1, FO, dir7, g4, be4, S1, 1024, 1024);
  final_kernel<<<512, 256, 0, stream>>>(S1, c8_w, c8_b, out);
}

// Round 11
// 910.712 us; speedup vs baseline: 1.3710x; 1.0261x over previous
//
#include <hip/hip_runtime.h>
#include <stdint.h>
#include <stddef.h>

#define FINF __builtin_inff()

// =================== Threefry-2x32 (JAX-compatible) ===================
__device__ inline void tf2x32(uint32_t k0, uint32_t k1, uint32_t x0, uint32_t x1,
                              uint32_t* o0, uint32_t* o1) {
  uint32_t ks2 = k0 ^ k1 ^ 0x1BD11BDAu;
  uint32_t v0 = x0 + k0, v1 = x1 + k1;
#define TFR(r) { v0 += v1; v1 = (v1 << (r)) | (v1 >> (32 - (r))); v1 ^= v0; }
  TFR(13) TFR(15) TFR(26) TFR(6)
  v0 += k1;  v1 += ks2 + 1u;
  TFR(17) TFR(29) TFR(16) TFR(24)
  v0 += ks2; v1 += k0 + 2u;
  TFR(13) TFR(15) TFR(26) TFR(6)
  v0 += k0;  v1 += k1 + 3u;
  TFR(17) TFR(29) TFR(16) TFR(24)
  v0 += k1;  v1 += ks2 + 4u;
  TFR(13) TFR(15) TFR(26) TFR(6)
  v0 += ks2; v1 += k0 + 5u;
#undef TFR
  *o0 = v0; *o1 = v1;
}

__device__ inline void perm_subkey(uint32_t seed, int round, uint32_t* s0, uint32_t* s1) {
  uint32_t k0 = 0u, k1 = seed;
  for (int r = 0; r < round; r++) {
    uint32_t a0, a1; tf2x32(k0, k1, 0u, 0u, &a0, &a1);
    k0 = a0; k1 = a1;
  }
  tf2x32(k0, k1, 0u, 1u, s0, s1);
}

// Rank-select stable-sort pass (HW-verified R8/R9), LDS-resident keys.
__global__ __launch_bounds__(256) void perm_pass_kernel(uint32_t seed, int round, int n,
                                                        const int* __restrict__ vin,
                                                        int* __restrict__ vout, int m) {
  __shared__ unsigned long long lk[4096];
  __shared__ int part[256];
  uint32_t s0, s1; perm_subkey(seed, round, &s0, &s1);
  int t = threadIdx.x;
  for (int j = t; j < n; j += 256) {
    uint32_t y0, y1; tf2x32(s0, s1, 0u, (uint32_t)j, &y0, &y1);
    lk[j] = ((unsigned long long)(y0 ^ y1) << 32) | (unsigned)j;
  }
  __syncthreads();
  int r = blockIdx.x * 64 + (t & 63);
  int q = t >> 6;
  unsigned long long ki = lk[r];
  int cnt = 0;
  int j0 = q * (n >> 2), j1 = j0 + (n >> 2);
  for (int j = j0; j < j1; j++) cnt += (lk[j] < ki) ? 1 : 0;
  part[t] = cnt;
  __syncthreads();
  if (t < 64) {
    int rank = part[t] + part[t + 64] + part[t + 128] + part[t + 192];
    if (rank < m) vout[rank] = vin ? vin[r] : r;
  }
}

// Fused first passes (HW-verified R10).
__global__ __launch_bounds__(256) void perm_passA_kernel(int* __restrict__ pt1,
                                                         int* __restrict__ sel2) {
  __shared__ unsigned long long lk[4096];
  __shared__ int part[256];
  bool big = (blockIdx.x < 64);
  uint32_t seed = big ? 1u : 2u;
  int n = big ? 4096 : 1024;
  int m = big ? 4096 : 256;
  int* vout = big ? pt1 : sel2;
  int blk = big ? blockIdx.x : (blockIdx.x - 64);
  uint32_t s0, s1; perm_subkey(seed, 0, &s0, &s1);
  int t = threadIdx.x;
  for (int j = t; j < n; j += 256) {
    uint32_t y0, y1; tf2x32(s0, s1, 0u, (uint32_t)j, &y0, &y1);
    lk[j] = ((unsigned long long)(y0 ^ y1) << 32) | (unsigned)j;
  }
  __syncthreads();
  int r = blk * 64 + (t & 63);
  int q = t >> 6;
  unsigned long long ki = lk[r];
  int cnt = 0;
  int j0 = q * (n >> 2), j1 = j0 + (n >> 2);
  for (int j = j0; j < j1; j++) cnt += (lk[j] < ki) ? 1 : 0;
  part[t] = cnt;
  __syncthreads();
  if (t < 64) {
    int rank = part[t] + part[t + 64] + part[t + 128] + part[t + 192];
    if (rank < m) vout[rank] = r;
  }
}

// ---- wave-wide argmin of per-lane heads (proven primitives) ----------------
__device__ inline void wave_argmin2(float head_d, int head_i, float* Mo, int* wio) {
  float M = head_d;
#pragma unroll
  for (int off = 1; off < 64; off <<= 1) M = fminf(M, __shfl_xor(M, off));
  int cand = (head_d == M) ? head_i : 0x7fffffff;
#pragma unroll
  for (int off = 1; off < 64; off <<= 1) cand = min(cand, __shfl_xor(cand, off));
  *Mo = M; *wio = cand;
}

// =================== KNN (N=4096): WAVES waves/row + rank merge (R9-proven) ===
template <int CNT, int WAVES>
__global__ __launch_bounds__(64 * WAVES) void knn_lex_kernel(const float* __restrict__ verts,
                                                             int N,
                                                             int* __restrict__ idx20,
                                                             int* __restrict__ idx4) {
  constexpr int SH = (CNT - 1 < 21) ? (CNT - 1) : 21;
  int row = blockIdx.x; int b = row / N, i = row - b * N;
  int t = threadIdx.x; int w = t >> 6; int lane = t & 63;
  const float* vb = verts + (size_t)b * N * 3;
  float xi = vb[i * 3], yi = vb[i * 3 + 1], zi = vb[i * 3 + 2];
  float sqi = (xi * xi + yi * yi) + zi * zi;

  int base = w * (N / WAVES) + lane;
  float qd[CNT]; int qi[CNT];
#pragma unroll
  for (int m = 0; m < CNT; m++) {
    int j = base + m * 64;
    float xj = vb[j * 3], yj = vb[j * 3 + 1], zj = vb[j * 3 + 2];
    float sqj = (xj * xj + yj * yj) + zj * zj;
    float dot = (xi * xj + yi * yj) + zi * zj;
    qd[m] = sqi + sqj - 2.f * dot;
    qi[m] = j;
  }
#pragma unroll
  for (int k = 2; k <= CNT; k <<= 1)
#pragma unroll
    for (int j = k >> 1; j > 0; j >>= 1)
#pragma unroll
      for (int m = 0; m < CNT; m++) {
        int l = m ^ j;
        if (l > m) {
          bool up = ((m & k) == 0);
          bool sw = up ? (qd[m] > qd[l]) : (qd[m] < qd[l]);
          float td = sw ? qd[l] : qd[m]; qd[l] = sw ? qd[m] : qd[l]; qd[m] = td;
          int ti = sw ? qi[l] : qi[m]; qi[l] = sw ? qi[m] : qi[l]; qi[m] = ti;
        }
      }

  __shared__ float wd[WAVES][21];
  __shared__ int wi[WAVES][21];
  for (int r = 0; r < 21; r++) {
    float M; int widx;
    wave_argmin2(qd[0], qi[0], &M, &widx);
    if (lane == 0) { wd[w][r] = M; wi[w][r] = widx; }
    bool win = (qi[0] == widx);
#pragma unroll
    for (int m = 0; m < SH; m++) {
      qd[m] = win ? qd[m + 1] : qd[m];
      qi[m] = win ? qi[m + 1] : qi[m];
    }
    if (SH == CNT - 1) {
      if (win) { qd[CNT - 1] = FINF; qi[CNT - 1] = 0x7fffffff; }
    }
  }
  __syncthreads();
  if (lane < 21) {
    float d0 = wd[w][lane]; int i0 = wi[w][lane];
    int rank = lane;
#pragma unroll
    for (int w2 = 0; w2 < WAVES; w2++) {
      if (w2 == w) continue;
      for (int p = 0; p < 21; p++) {
        float ld = wd[w2][p]; int li = wi[w2][p];
        rank += (ld < d0 || (ld == d0 && li < i0)) ? 1 : 0;
      }
    }
    if (rank >= 1 && rank <= 20) idx20[(size_t)row * 20 + (rank - 1)] = i0;
    if (rank >= 1 && rank <= 4)  idx4[(size_t)row * 4 + (rank - 1)] = i0;
  }
}

// ====== FAT: knn(v1, N=1024) 4 waves/block [blocks 0..1023] + w2 GEMM [1024..1535]
__global__ __launch_bounds__(256) void knnv1_w2_kernel(const float* __restrict__ verts,
                                                       int* __restrict__ idx20,
                                                       int* __restrict__ idx4,
                                                       const float* __restrict__ x,
                                                       const float* __restrict__ W,
                                                       const float* __restrict__ bias,
                                                       float* __restrict__ y) {
  if (blockIdx.x < 1024) {
    constexpr int CNT = 16;
    const int N = 1024;
    int lane = threadIdx.x & 63;
    int row = blockIdx.x * 4 + (threadIdx.x >> 6);
    int b = row / N, i = row - b * N;
    const float* vb = verts + (size_t)b * N * 3;
    float xi = vb[i * 3], yi = vb[i * 3 + 1], zi = vb[i * 3 + 2];
    float sqi = (xi * xi + yi * yi) + zi * zi;
    float qd[CNT]; int qi[CNT];
#pragma unroll
    for (int m = 0; m < CNT; m++) {
      int j = lane + m * 64;
      float xj = vb[j * 3], yj = vb[j * 3 + 1], zj = vb[j * 3 + 2];
      float sqj = (xj * xj + yj * yj) + zj * zj;
      float dot = (xi * xj + yi * yj) + zi * zj;
      qd[m] = sqi + sqj - 2.f * dot;
      qi[m] = j;
    }
#pragma unroll
    for (int k = 2; k <= CNT; k <<= 1)
#pragma unroll
      for (int j = k >> 1; j > 0; j >>= 1)
#pragma unroll
        for (int m = 0; m < CNT; m++) {
          int l = m ^ j;
          if (l > m) {
            bool up = ((m & k) == 0);
            bool sw = up ? (qd[m] > qd[l]) : (qd[m] < qd[l]);
            float td = sw ? qd[l] : qd[m]; qd[l] = sw ? qd[m] : qd[l]; qd[m] = td;
            int ti = sw ? qi[l] : qi[m]; qi[l] = sw ? qi[m] : qi[l]; qi[m] = ti;
          }
        }
    for (int r = 0; r < 21; r++) {
      float M; int widx;
      wave_argmin2(qd[0], qi[0], &M, &widx);
      if (lane == 0 && r >= 1) {
        idx20[(size_t)row * 20 + (r - 1)] = widx;
        if (r <= 4) idx4[(size_t)row * 4 + (r - 1)] = widx;
      }
      bool win = (qi[0] == widx);
#pragma unroll
      for (int m = 0; m < CNT - 1; m++) {
        qd[m] = win ? qd[m + 1] : qd[m];
        qi[m] = win ? qi[m + 1] : qi[m];
      }
      if (win) { qd[CNT - 1] = FINF; qi[CNT - 1] = 0x7fffffff; }
    }
  } else {
    // w2 GEMM: x(4096,64) @ W(64,256) + bias  (identical math to gemm_io_kernel)
    const int I = 64, O = 256;
    int rb = (blockIdx.x - 1024) * 8;
    int o = threadIdx.x;
    __shared__ float xs[64][8];
    for (int u = 0; u < 8; u++)
      for (int i2 = threadIdx.x; i2 < I; i2 += 256) xs[i2][u] = x[(size_t)(rb + u) * I + i2];
    __syncthreads();
    float a[8] = {0, 0, 0, 0, 0, 0, 0, 0};
    for (int k2 = 0; k2 < I; k2++) {
      float wv = W[(size_t)k2 * O + o];
      float4 xa = *(const float4*)&xs[k2][0];
      float4 xb = *(const float4*)&xs[k2][4];
      a[0] += xa.x * wv; a[1] += xa.y * wv; a[2] += xa.z * wv; a[3] += xa.w * wv;
      a[4] += xb.x * wv; a[5] += xb.y * wv; a[6] += xb.z * wv; a[7] += xb.w * wv;
    }
    float bv = bias[o];
#pragma unroll
    for (int u = 0; u < 8; u++) y[(size_t)(rb + u) * O + o] = a[u] + bv;
  }
}

// =================== conv_surface, 4 rows/block (wave-local) ==================
__global__ __launch_bounds__(256) void conv_surface_kernel(const float* __restrict__ verts,
                                                           const int* __restrict__ idx20,
                                                           const float* __restrict__ d0,
                                                           const float* __restrict__ g,
                                                           const float* __restrict__ be,
                                                           float* __restrict__ out, int N) {
  int w = threadIdx.x >> 6; int t = threadIdx.x & 63;
  int row = blockIdx.x * 4 + w; int b = row / N, i = row - b * N;
  __shared__ float nd[4][20][3];
  const float* vb = verts + (size_t)b * N * 3;
  if (t < 20) {
    int j = idx20[(size_t)row * 20 + t];
    float dx = vb[j * 3] - vb[i * 3], dy = vb[j * 3 + 1] - vb[i * 3 + 1], dz = vb[j * 3 + 2] - vb[i * 3 + 2];
    float n2 = sqrtf(dx * dx + dy * dy + dz * dz); n2 = fmaxf(n2, 1e-12f);
    nd[w][t][0] = dx / n2; nd[w][t][1] = dy / n2; nd[w][t][2] = dz / n2;
  }
  // wave-synchronous LDS use (single wave writes+reads its own region)
  float x = 0.f;
  if (t < 32) {
    float a = d0[t], bb2 = d0[32 + t], c = d0[64 + t];
    float nrm = fmaxf(sqrtf(a * a + bb2 * bb2 + c * c), 1e-12f);
    a /= nrm; bb2 /= nrm; c /= nrm;
    float mx = -FINF;
    for (int kk = 0; kk < 20; kk++) {
      float th = fmaxf(nd[w][kk][0] * a + nd[w][kk][1] * bb2 + nd[w][kk][2] * c, 0.f);
      mx = fmaxf(mx, th);
    }
    x = mx;
  }
  float s = x;
  for (int off = 32; off; off >>= 1) s += __shfl_xor(s, off);
  float mean = s / 32.f;
  float dev = (t < 32) ? x - mean : 0.f;
  float s2 = dev * dev;
  for (int off = 32; off; off >>= 1) s2 += __shfl_xor(s2, off);
  float var = s2 / 32.f;
  if (t < 32) {
    float y = (x - mean) / sqrtf(var + 1e-6f) * g[t] + be[t];
    out[(size_t)row * 32 + t] = fmaxf(y, 0.f);
  }
}

// =================== GEMM: y = x(R,I) @ W(I,O) + bias, 8 rows/block ===========
__global__ void gemm_io_kernel(const float* __restrict__ x, const float* __restrict__ W,
                               const float* __restrict__ bias, float* __restrict__ y,
                               int R, int I, int O) {
  int rb = blockIdx.x * 8;
  int o = blockIdx.y * blockDim.x + threadIdx.x;
  __shared__ float xs[256][8];
  for (int u = 0; u < 8; u++)
    for (int i2 = threadIdx.x; i2 < I; i2 += blockDim.x) xs[i2][u] = x[(size_t)(rb + u) * I + i2];
  __syncthreads();
  float a[8] = {0, 0, 0, 0, 0, 0, 0, 0};
  for (int k2 = 0; k2 < I; k2++) {
    float wv = W[(size_t)k2 * O + o];
    float4 xa = *(const float4*)&xs[k2][0];
    float4 xb = *(const float4*)&xs[k2][4];
    a[0] += xa.x * wv; a[1] += xa.y * wv; a[2] += xa.z * wv; a[3] += xa.w * wv;
    a[4] += xb.x * wv; a[5] += xb.y * wv; a[6] += xb.z * wv; a[7] += xb.w * wv;
  }
  float bv = bias[o];
#pragma unroll
  for (int u = 0; u < 8; u++) y[(size_t)(rb + u) * O + o] = a[u] + bv;
}

// =================== GEMM 16 rows/block (for w7) ===================
__global__ void gemm_io16_kernel(const float* __restrict__ x, const float* __restrict__ W,
                                 const float* __restrict__ bias, float* __restrict__ y,
                                 int R, int I, int O) {
  int rb = blockIdx.x * 16;
  int o = blockIdx.y * blockDim.x + threadIdx.x;
  __shared__ float xs[256][16];
  for (int u = 0; u < 16; u++)
    for (int i2 = threadIdx.x; i2 < I; i2 += blockDim.x) xs[i2][u] = x[(size_t)(rb + u) * I + i2];
  __syncthreads();
  float a[16];
#pragma unroll
  for (int u = 0; u < 16; u++) a[u] = 0.f;
  for (int k2 = 0; k2 < I; k2++) {
    float wv = W[(size_t)k2 * O + o];
    float4 x0 = *(const float4*)&xs[k2][0];
    float4 x1 = *(const float4*)&xs[k2][4];
    float4 x2 = *(const float4*)&xs[k2][8];
    float4 x3 = *(const float4*)&xs[k2][12];
    a[0] += x0.x * wv; a[1] += x0.y * wv; a[2] += x0.z * wv; a[3] += x0.w * wv;
    a[4] += x1.x * wv; a[5] += x1.y * wv; a[6] += x1.z * wv; a[7] += x1.w * wv;
    a[8] += x2.x * wv; a[9] += x2.y * wv; a[10] += x2.z * wv; a[11] += x2.w * wv;
    a[12] += x3.x * wv; a[13] += x3.y * wv; a[14] += x3.z * wv; a[15] += x3.w * wv;
  }
  float bv = bias[o];
#pragma unroll
  for (int u = 0; u < 16; u++) y[(size_t)(rb + u) * O + o] = a[u] + bv;
}

// =================== conv_layer combine (k-loop hoisted) ===================
template <int CPT>
__global__ void combine_kernel(const float* __restrict__ verts, const int* __restrict__ idx20,
                               const float* __restrict__ fo, const float* __restrict__ dirs,
                               const float* __restrict__ g, const float* __restrict__ be,
                               float* __restrict__ out, int N, int C) {
  int row = blockIdx.x; int b = row / N, i = row - b * N;
  int t = threadIdx.x, bs = blockDim.x;
  __shared__ float nd[20][3];
  __shared__ int nidx[20];
  __shared__ float red[8];
  const float* vb = verts + (size_t)b * N * 3;
  if (t < 20) {
    int j = idx20[(size_t)row * 20 + t];
    nidx[t] = j;
    float dx = vb[j * 3] - vb[i * 3], dy = vb[j * 3 + 1] - vb[i * 3 + 1], dz = vb[j * 3 + 2] - vb[i * 3 + 2];
    float n2 = fmaxf(sqrtf(dx * dx + dy * dy + dz * dz), 1e-12f);
    nd[t][0] = dx / n2; nd[t][1] = dy / n2; nd[t][2] = dz / n2;
  }
  __syncthreads();
  const float* fob = fo + (size_t)b * N * 2 * C;
  const float* forow = fob + (size_t)i * 2 * C;
  float da[CPT], db[CPT], dc[CPT], mx[CPT];
#pragma unroll
  for (int u = 0; u < CPT; u++) {
    int c = t + u * bs;
    float a = dirs[c], bb = dirs[C + c], cc = dirs[2 * C + c];
    float nrm = fmaxf(sqrtf(a * a + bb * bb + cc * cc), 1e-12f);
    da[u] = a / nrm; db[u] = bb / nrm; dc[u] = cc / nrm;
    mx[u] = -FINF;
  }
  for (int kk = 0; kk < 20; kk++) {
    float n0 = nd[kk][0], n1 = nd[kk][1], n2v = nd[kk][2];
    const float* sup = fob + (size_t)nidx[kk] * 2 * C + C + t;
#pragma unroll
    for (int u = 0; u < CPT; u++) {
      float th = fmaxf(n0 * da[u] + n1 * db[u] + n2v * dc[u], 0.f);
      mx[u] = fmaxf(mx[u], th * sup[u * bs]);
    }
  }
  float xv[CPT];
  float ssum = 0.f;
#pragma unroll
  for (int u = 0; u < CPT; u++) {
    int c = t + u * bs;
    float val = forow[c] + mx[u];
    xv[u] = val; ssum += val;
  }
  int nw = bs >> 6;
  for (int off = 32; off; off >>= 1) ssum += __shfl_down(ssum, off);
  if ((t & 63) == 0) red[t >> 6] = ssum;
  __syncthreads();
  if (t == 0) { float s = red[0]; for (int w = 1; w < nw; w++) s += red[w]; red[0] = s; }
  __syncthreads();
  float mean = red[0] / (float)C;
  __syncthreads();
  float s2 = 0.f;
#pragma unroll
  for (int u = 0; u < CPT; u++) { float d2 = xv[u] - mean; s2 += d2 * d2; }
  for (int off = 32; off; off >>= 1) s2 += __shfl_down(s2, off);
  if ((t & 63) == 0) red[t >> 6] = s2;
  __syncthreads();
  if (t == 0) { float s = red[0]; for (int w = 1; w < nw; w++) s += red[w]; red[0] = s; }
  __syncthreads();
  float inv = 1.0f / sqrtf(red[0] / (float)C + 1e-6f);
#pragma unroll
  for (int u = 0; u < CPT; u++) {
    int c = t + u * bs;
    float yv = (xv[u] - mean) * inv * g[c] + be[c];
    out[(size_t)row * C + c] = fmaxf(yv, 0.f);
  }
}

// =================== pool (max over 4 NN) + row-select ===================
__global__ void pool_select_kernel(const float* __restrict__ fm, const int* __restrict__ idx4,
                                   const int* __restrict__ sel, const float* __restrict__ vin,
                                   float* __restrict__ vout, float* __restrict__ out,
                                   int N, int M, int C) {
  int row = blockIdx.x; int b = row / M, r = row - b * M;
  int s = sel[r];
  const int* id = idx4 + ((size_t)b * N + s) * 4;
  int i0 = id[0], i1 = id[1], i2 = id[2], i3 = id[3];
  const float* fb = fm + (size_t)b * N * C;
  for (int c = threadIdx.x; c < C; c += blockDim.x) {
    float m = fmaxf(fmaxf(fb[(size_t)i0 * C + c], fb[(size_t)i1 * C + c]),
                    fmaxf(fb[(size_t)i2 * C + c], fb[(size_t)i3 * C + c]));
    out[((size_t)b * M + r) * C + c] = m;
  }
  if (vout != nullptr && threadIdx.x < 3)
    vout[((size_t)b * M + r) * 3 + threadIdx.x] = vin[((size_t)b * N + s) * 3 + threadIdx.x];
}

// =================== linear: y = x(R,I) @ W(O,I)^T + bias (+res) ===================
__global__ void linear_oi_kernel(const float* __restrict__ x, const float* __restrict__ W,
                                 const float* __restrict__ bias, const float* __restrict__ res,
                                 float* __restrict__ y, int R, int I, int O) {
  int rb = blockIdx.x * 8;
  int o = threadIdx.x;
  __shared__ float xs[8][256];
  for (int u = 0; u < 8; u++)
    for (int i2 = threadIdx.x; i2 < I; i2 += O) xs[u][i2] = x[(size_t)(rb + u) * I + i2];
  __syncthreads();
  float a[8] = {0, 0, 0, 0, 0, 0, 0, 0};
  const float* w = W + (size_t)o * I;
  for (int k2 = 0; k2 < I; k2++) {
    float wv = w[k2];
#pragma unroll
    for (int u = 0; u < 8; u++) a[u] += xs[u][k2] * wv;
  }
  float bv = bias[o];
#pragma unroll
  for (int u = 0; u < 8; u++) {
    float val = a[u] + bv;
    if (res) val += res[(size_t)(rb + u) * O + o];
    y[(size_t)(rb + u) * O + o] = val;
  }
}

// === linear with BN(train)+relu applied to the INPUT on load (ffn2 fusion) ===
__global__ void linear_bn_kernel(const float* __restrict__ x, const float* __restrict__ W,
                                 const float* __restrict__ bias,
                                 const float* __restrict__ stats,
                                 const float* __restrict__ g, const float* __restrict__ b2,
                                 float* __restrict__ y, int R, int I, int O) {
  int rb = blockIdx.x * 8;
  int o = threadIdx.x;
  __shared__ float xs[8][256];
  for (int u = 0; u < 8; u++)
    for (int i2 = threadIdx.x; i2 < I; i2 += O) {
      float xr = x[(size_t)(rb + u) * I + i2];
      float yv = (xr - stats[i2]) / sqrtf(stats[I + i2] + 1e-5f) * g[i2] + b2[i2];
      xs[u][i2] = fmaxf(yv, 0.f);
    }
  __syncthreads();
  float a[8] = {0, 0, 0, 0, 0, 0, 0, 0};
  const float* w = W + (size_t)o * I;
  for (int k2 = 0; k2 < I; k2++) {
    float wv = w[k2];
#pragma unroll
    for (int u = 0; u < 8; u++) a[u] += xs[u][k2] * wv;
  }
  float bv = bias[o];
#pragma unroll
  for (int u = 0; u < 8; u++) y[(size_t)(rb + u) * O + o] = a[u] + bv;
}

// =================== fused QKV for MHA1 (token transpose folded into Q) =======
__global__ __launch_bounds__(64) void qkv1_kernel(const float* __restrict__ token,
                                                  const float* __restrict__ fm1p,
                                                  const float* __restrict__ Win,
                                                  const float* __restrict__ bin,
                                                  float* __restrict__ Q1,
                                                  float* __restrict__ K1,
                                                  float* __restrict__ V1) {
  int ybr = blockIdx.y;
  const float* W = Win + (size_t)ybr * 64 * 64;
  const float* bias = bin + ybr * 64;
  float* out = (ybr == 0) ? Q1 : (ybr == 1) ? K1 : V1;
  int rb = blockIdx.x * 8;
  int o = threadIdx.x;
  __shared__ float xs[8][64];
  if (ybr == 0) {
    for (int u = 0; u < 8; u++) {
      int n = (rb + u) & 1023;
      xs[u][o] = token[(size_t)o * 1024 + n];
    }
  } else {
    for (int u = 0; u < 8; u++) xs[u][o] = fm1p[(size_t)(rb + u) * 64 + o];
  }
  __syncthreads();
  float a[8] = {0, 0, 0, 0, 0, 0, 0, 0};
  const float* w = W + (size_t)o * 64;
  for (int k2 = 0; k2 < 64; k2++) {
    float wv = w[k2];
#pragma unroll
    for (int u = 0; u < 8; u++) a[u] += xs[u][k2] * wv;
  }
  float bv = bias[o];
#pragma unroll
  for (int u = 0; u < 8; u++) out[(size_t)(rb + u) * 64 + o] = a[u] + bv;
}

// =================== fused K2/V2 for MHA2 ===================
__global__ __launch_bounds__(256) void kv2_kernel(const float* __restrict__ fm3p,
                                                  const float* __restrict__ Win,
                                                  const float* __restrict__ bin,
                                                  float* __restrict__ K2,
                                                  float* __restrict__ V2) {
  int ybr = blockIdx.y;
  const float* W = Win + (size_t)(1 + ybr) * 256 * 256;
  const float* bias = bin + (1 + ybr) * 256;
  float* out = ybr ? V2 : K2;
  int rb = blockIdx.x * 8;
  int o = threadIdx.x;
  __shared__ float xs[8][256];
  for (int u = 0; u < 8; u++) xs[u][o] = fm3p[(size_t)(rb + u) * 256 + o];
  __syncthreads();
  float a[8] = {0, 0, 0, 0, 0, 0, 0, 0};
  const float* w = W + (size_t)o * 256;
  for (int k2 = 0; k2 < 256; k2++) {
    float wv = w[k2];
#pragma unroll
    for (int u = 0; u < 8; u++) a[u] += xs[u][k2] * wv;
  }
  float bv = bias[o];
#pragma unroll
  for (int u = 0; u < 8; u++) out[(size_t)(rb + u) * 256 + o] = a[u] + bv;
}

// =================== tiled flash attention ===================
template <int HD, int QPT, int KS>
__global__ __launch_bounds__(256) void attn_tiled(
    const float* __restrict__ q, const float* __restrict__ kk,
    const float* __restrict__ vv, float* __restrict__ o,
    int Lq, int Lk, int H, float scale) {
  constexpr int TK = 64;
  constexpr int QG = 256 / (2 * KS);
  constexpr int QPB = QG * QPT;
  constexpr int V4 = HD / 4;
  constexpr int STR = V4 + 1;
  constexpr int HH = HD / 2;
  constexpr int V4H = HH / 4;

  __shared__ float4 Ks[TK * STR];
  __shared__ float4 Vs[TK * STR];

  int t = threadIdx.x;
  int dh = t & 1;
  int ki = (t >> 1) & (KS - 1);
  int qg = t / (2 * KS);
  int nqt = Lq / QPB;
  int qt = blockIdx.x % nqt, bh = blockIdx.x / nqt;
  int h = bh % H, b = bh / H;
  int E = H * HD;
  int q0 = qt * QPB + qg * QPT;

  const float* qbase = q + ((size_t)b * Lq + q0) * E + h * HD + dh * HH;
  const float* kbase = kk + (size_t)b * Lk * E + h * HD;
  const float* vbase = vv + (size_t)b * Lk * E + h * HD;

  float qr[QPT][HH], O[QPT][HH], m[QPT], l[QPT];
#pragma unroll
  for (int r = 0; r < QPT; r++) {
    m[r] = -FINF; l[r] = 0.f;
#pragma unroll
    for (int d = 0; d < HH; d++) { qr[r][d] = qbase[(size_t)r * E + d]; O[r][d] = 0.f; }
  }

  for (int k0 = 0; k0 < Lk; k0 += TK) {
    __syncthreads();
    for (int e = t; e < TK * V4; e += 256) {
      int rr = e / V4, cc = e - rr * V4;
      Ks[rr * STR + cc] = *(const float4*)(kbase + (size_t)(k0 + rr) * E + cc * 4);
      Vs[rr * STR + cc] = *(const float4*)(vbase + (size_t)(k0 + rr) * E + cc * 4);
    }
    __syncthreads();
#pragma unroll 1
    for (int g = 0; g < TK / KS; g += 4) {
      float sc[QPT][4];
#pragma unroll
      for (int jj = 0; jj < 4; jj++) {
        int kl = (g + jj) * KS + ki;
        float sh[QPT];
#pragma unroll
        for (int r = 0; r < QPT; r++) sh[r] = 0.f;
        const float4* kr = &Ks[kl * STR + dh * V4H];
#pragma unroll
        for (int c = 0; c < V4H; c++) {
          float4 kv = kr[c];
#pragma unroll
          for (int r = 0; r < QPT; r++)
            sh[r] += qr[r][4 * c] * kv.x + qr[r][4 * c + 1] * kv.y
                   + qr[r][4 * c + 2] * kv.z + qr[r][4 * c + 3] * kv.w;
        }
#pragma unroll
        for (int r = 0; r < QPT; r++)
          sc[r][jj] = (sh[r] + __shfl_xor(sh[r], 1)) * scale;
      }
#pragma unroll
      for (int r = 0; r < QPT; r++) {
        float tm = fmaxf(fmaxf(sc[r][0], sc[r][1]), fmaxf(sc[r][2], sc[r][3]));
        float nm = fmaxf(m[r], tm);
        float a = __expf(m[r] - nm);
        m[r] = nm;
        float ls = l[r] * a;
#pragma unroll
        for (int d = 0; d < HH; d++) O[r][d] *= a;
#pragma unroll
        for (int jj = 0; jj < 4; jj++) { sc[r][jj] = __expf(sc[r][jj] - nm); ls += sc[r][jj]; }
        l[r] = ls;
      }
#pragma unroll
      for (int jj = 0; jj < 4; jj++) {
        int kl = (g + jj) * KS + ki;
        const float4* vr = &Vs[kl * STR + dh * V4H];
#pragma unroll
        for (int c = 0; c < V4H; c++) {
          float4 v4 = vr[c];
#pragma unroll
          for (int r = 0; r < QPT; r++) {
            O[r][4 * c]     += sc[r][jj] * v4.x;
            O[r][4 * c + 1] += sc[r][jj] * v4.y;
            O[r][4 * c + 2] += sc[r][jj] * v4.z;
            O[r][4 * c + 3] += sc[r][jj] * v4.w;
          }
        }
      }
    }
  }
#pragma unroll
  for (int r = 0; r < QPT; r++) {
    float M = m[r];
#pragma unroll
    for (int mask = 2; mask < 2 * KS; mask <<= 1) M = fmaxf(M, __shfl_xor(M, mask));
    float w = __expf(m[r] - M);
    float ll = l[r] * w;
#pragma unroll
    for (int mask = 2; mask < 2 * KS; mask <<= 1) ll += __shfl_xor(ll, mask);
    float inv = 1.f / ll;
#pragma unroll
    for (int d = 0; d < HH; d++) {
      float x = O[r][d] * w;
#pragma unroll
      for (int mask = 2; mask < 2 * KS; mask <<= 1) x += __shfl_xor(x, mask);
      O[r][d] = x * inv;
    }
  }
  if (ki == 0) {
    float* obase = o + ((size_t)b * Lq + q0) * E + h * HD + dh * HH;
#pragma unroll
    for (int r = 0; r < QPT; r++)
#pragma unroll
      for (int d = 0; d < HH; d++) obase[(size_t)r * E + d] = O[r][d];
  }
}

// =================== BN (train-mode) stats ===================
__global__ void bn_stats_kernel(const float* __restrict__ x, float* __restrict__ stats,
                                int R, int C) {
  int c = blockIdx.x; int t = threadIdx.x;
  __shared__ float red[8];
  float s = 0.f;
  for (int r = t; r < R; r += blockDim.x) s += x[(size_t)r * C + c];
  for (int off = 32; off; off >>= 1) s += __shfl_down(s, off);
  if ((t & 63) == 0) red[t >> 6] = s;
  __syncthreads();
  if (t == 0) { float a = red[0]; for (int w = 1; w < (int)(blockDim.x >> 6); w++) a += red[w]; red[0] = a; }
  __syncthreads();
  float mean = red[0] / (float)R;
  __syncthreads();
  float s2 = 0.f;
  for (int r = t; r < R; r += blockDim.x) { float d = x[(size_t)r * C + c] - mean; s2 += d * d; }
  for (int off = 32; off; off >>= 1) s2 += __shfl_down(s2, off);
  if ((t & 63) == 0) red[t >> 6] = s2;
  __syncthreads();
  if (t == 0) {
    float a = red[0]; for (int w = 1; w < (int)(blockDim.x >> 6); w++) a += red[w];
    stats[c] = mean; stats[C + c] = a / (float)R;
  }
}

// =================== final conv1x1 (xs transposed) ===================
__global__ void final_kernel(const float* __restrict__ fmf, const float* __restrict__ W,
                             const float* __restrict__ bias, float* __restrict__ out) {
  int nb = blockIdx.x * 8;
  int o = threadIdx.x;
  __shared__ float xs[1024][8];
  for (int u = 0; u < 8; u++)
    for (int c = threadIdx.x; c < 1024; c += 256) xs[c][u] = fmf[(size_t)(nb + u) * 1024 + c];
  __syncthreads();
  float acc[8] = {0, 0, 0, 0, 0, 0, 0, 0};
  const float* w = W + (size_t)o * 1024;
  for (int c = 0; c < 1024; c++) {
    float wv = w[c];
    float4 xa = *(const float4*)&xs[c][0];
    float4 xb = *(const float4*)&xs[c][4];
    acc[0] += xa.x * wv; acc[1] += xa.y * wv; acc[2] += xa.z * wv; acc[3] += xa.w * wv;
    acc[4] += xb.x * wv; acc[5] += xb.y * wv; acc[6] += xb.z * wv; acc[7] += xb.w * wv;
  }
  float bv = bias[o];
#pragma unroll
  for (int u = 0; u < 8; u++) {
    int r = nb + u; int b = r >> 10; int n = r & 1023;
    out[((size_t)(b * 256 + o) << 10) + n] = acc[u] + bv;
  }
}

// =================== launch ===================
extern "C" void kernel_launch(void* const* d_in, const int* in_sizes, int n_in,
                              void* d_out, int out_size, void* d_ws, size_t ws_size,
                              hipStream_t stream) {
  (void)in_sizes; (void)n_in; (void)out_size;
  const float* vertices = (const float*)d_in[0];
  const float* d0       = (const float*)d_in[1];
  const float* g0       = (const float*)d_in[2];
  const float* be0      = (const float*)d_in[3];
  const float* w1       = (const float*)d_in[4];
  const float* b1       = (const float*)d_in[5];
  const float* dir1     = (const float*)d_in[6];
  const float* g1       = (const float*)d_in[7];
  const float* be1      = (const float*)d_in[8];
  const float* w2       = (const float*)d_in[9];
  const float* b2       = (const float*)d_in[10];
  const float* dir2     = (const float*)d_in[11];
  const float* g2       = (const float*)d_in[12];
  const float* be2      = (const float*)d_in[13];
  const float* w3       = (const float*)d_in[14];
  const float* b3       = (const float*)d_in[15];
  const float* dir3     = (const float*)d_in[16];
  const float* g3       = (const float*)d_in[17];
  const float* be3      = (const float*)d_in[18];
  const float* token    = (const float*)d_in[19];
  const float* a1_in_w  = (const float*)d_in[20];
  const float* a1_in_b  = (const float*)d_in[21];
  const float* a1_out_w = (const float*)d_in[22];
  const float* a1_out_b = (const float*)d_in[23];
  const float* ffn1_w   = (const float*)d_in[24];
  const float* ffn1_b   = (const float*)d_in[25];
  const float* bg       = (const float*)d_in[26];
  const float* bbp      = (const float*)d_in[27];
  const float* ffn2_w   = (const float*)d_in[28];
  const float* ffn2_b   = (const float*)d_in[29];
  const float* a2_in_w  = (const float*)d_in[30];
  const float* a2_in_b  = (const float*)d_in[31];
  const float* a2_out_w = (const float*)d_in[32];
  const float* a2_out_b = (const float*)d_in[33];
  const float* w7       = (const float*)d_in[34];
  const float* b7       = (const float*)d_in[35];
  const float* dir7     = (const float*)d_in[36];
  const float* g4       = (const float*)d_in[37];
  const float* be4      = (const float*)d_in[38];
  const float* c8_w     = (const float*)d_in[39];
  const float* c8_b     = (const float*)d_in[40];
  float* out = (float*)d_out;
  float* ws = (float*)d_ws;

  if (ws_size < 78568448u) return;

  float* FO     = ws + 0;
  float* S1     = ws + 8388608;
  float* S2     = ws + 12582912;
  float* S3     = ws + 13631488;
  float* QUERY2 = ws + 14680064;
  float* CROSS  = ws + 15728640;
  float* FM1P   = ws + 16777216;
  float* FM3P   = FM1P + 262144;
  float* TOK    = FM3P + 262144;  // unused
  float* Q1     = TOK + 262144;
  float* K1     = Q1 + 262144;
  float* VA1    = K1 + 262144;
  float* ATT1   = VA1 + 262144;
  float* K2     = ATT1 + 262144;
  float* V2     = K2 + 262144;
  float* V1     = V2 + 262144;
  float* BNST   = V1 + 12288;
  int* IDX20_0  = (int*)(BNST + 512);
  int* IDX4_0   = IDX20_0 + 327680;
  int* IDX20_1  = IDX4_0 + 65536;
  int* IDX4_1   = IDX20_1 + 81920;
  int* SEL1     = IDX4_1 + 16384;
  int* SEL2     = SEL1 + 1024;
  int* PT1 = IDX20_0;  // transient

  perm_passA_kernel<<<80, 256, 0, stream>>>(PT1, SEL2);
  perm_pass_kernel<<<64, 256, 0, stream>>>(1u, 1, 4096, PT1, SEL1, 1024);

  knn_lex_kernel<32, 2><<<4 * 4096, 128, 0, stream>>>(vertices, 4096, IDX20_0, IDX4_0);
  conv_surface_kernel<<<4096, 256, 0, stream>>>(vertices, IDX20_0, d0, g0, be0, S2, 4096);
  gemm_io_kernel<<<dim3(2048, 1), 128, 0, stream>>>(S2, w1, b1, FO, 16384, 32, 128);
  combine_kernel<1><<<16384, 64, 0, stream>>>(vertices, IDX20_0, FO, dir1, g1, be1, S1, 4096, 64);
  pool_select_kernel<<<4096, 64, 0, stream>>>(S1, IDX4_0, SEL1, vertices, V1, FM1P, 4096, 1024, 64);

  // knn(v1) [4 waves/block] + w2 GEMM fat dispatch (independent after pool)
  knnv1_w2_kernel<<<1536, 256, 0, stream>>>(V1, IDX20_1, IDX4_1, FM1P, w2, b2, FO);
  combine_kernel<1><<<4096, 128, 0, stream>>>(V1, IDX20_1, FO, dir2, g2, be2, S2, 1024, 128);
  gemm_io_kernel<<<dim3(512, 2), 256, 0, stream>>>(S2, w3, b3, FO, 4096, 128, 512);
  combine_kernel<1><<<4096, 256, 0, stream>>>(V1, IDX20_1, FO, dir3, g3, be3, S3, 1024, 256);
  pool_select_kernel<<<1024, 256, 0, stream>>>(S3, IDX4_1, SEL2, nullptr, nullptr, FM3P, 1024, 256, 256);

  // MHA1 (tok as Q, fm1p as KV) + residual
  qkv1_kernel<<<dim3(512, 3), 64, 0, stream>>>(token, FM1P, a1_in_w, a1_in_b, Q1, K1, VA1);
  attn_tiled<16, 2, 8><<<512, 256, 0, stream>>>(Q1, K1, VA1, ATT1, 1024, 1024, 4, 0.25f);
  linear_oi_kernel<<<512, 64, 0, stream>>>(ATT1, a1_out_w, a1_out_b, FM1P, S3, 4096, 64, 64);

  // FFN (bn_apply fused into ffn2 input load)
  linear_oi_kernel<<<512, 256, 0, stream>>>(S3, ffn1_w, ffn1_b, nullptr, S2, 4096, 64, 256);
  bn_stats_kernel<<<256, 256, 0, stream>>>(S2, BNST, 4096, 256);
  linear_bn_kernel<<<512, 256, 0, stream>>>(S2, ffn2_w, ffn2_b, BNST, bg, bbp, QUERY2, 4096, 256, 256);

  // MHA2 (query2 as Q, fm3p as KV) + residual
  linear_oi_kernel<<<512, 256, 0, stream>>>(QUERY2, a2_in_w, a2_in_b, nullptr, S3, 4096, 256, 256);
  kv2_kernel<<<dim3(128, 2), 256, 0, stream>>>(FM3P, a2_in_w, a2_in_b, K2, V2);
  attn_tiled<64, 2, 8><<<512, 256, 0, stream>>>(S3, K2, V2, S1, 1024, 256, 4, 0.125f);
  linear_oi_kernel<<<512, 256, 0, stream>>>(S1, a2_out_w, a2_out_b, QUERY2, CROSS, 4096, 256, 256);

  // conv_layer7 + final conv1x1
  gemm_io16_kernel<<<dim3(256, 8), 256, 0, stream>>>(CROSS, w7, b7, FO, 4096, 256, 2048);
  combine_kernel<4><<<4096, 256, 0, stream>>>(V1, IDX20_1, FO, dir7, g4, be4, S1, 1024, 1024);
  final_kernel<<<512, 256, 0, stream>>>(S1, c8_w, c8_b, out);
}

// Round 12
// 886.863 us; speedup vs baseline: 1.4079x; 1.0269x over previous
//
#include <hip/hip_runtime.h>
#include <stdint.h>
#include <stddef.h>

#define FINF __builtin_inff()

// =================== Threefry-2x32 (JAX-compatible) ===================
__device__ inline void tf2x32(uint32_t k0, uint32_t k1, uint32_t x0, uint32_t x1,
                              uint32_t* o0, uint32_t* o1) {
  uint32_t ks2 = k0 ^ k1 ^ 0x1BD11BDAu;
  uint32_t v0 = x0 + k0, v1 = x1 + k1;
#define TFR(r) { v0 += v1; v1 = (v1 << (r)) | (v1 >> (32 - (r))); v1 ^= v0; }
  TFR(13) TFR(15) TFR(26) TFR(6)
  v0 += k1;  v1 += ks2 + 1u;
  TFR(17) TFR(29) TFR(16) TFR(24)
  v0 += ks2; v1 += k0 + 2u;
  TFR(13) TFR(15) TFR(26) TFR(6)
  v0 += k0;  v1 += k1 + 3u;
  TFR(17) TFR(29) TFR(16) TFR(24)
  v0 += k1;  v1 += ks2 + 4u;
  TFR(13) TFR(15) TFR(26) TFR(6)
  v0 += ks2; v1 += k0 + 5u;
#undef TFR
  *o0 = v0; *o1 = v1;
}

__device__ inline void perm_subkey(uint32_t seed, int round, uint32_t* s0, uint32_t* s1) {
  uint32_t k0 = 0u, k1 = seed;
  for (int r = 0; r < round; r++) {
    uint32_t a0, a1; tf2x32(k0, k1, 0u, 0u, &a0, &a1);
    k0 = a0; k1 = a1;
  }
  tf2x32(k0, k1, 0u, 1u, s0, s1);
}

// Rank-select stable-sort pass (HW-verified R8/R9), LDS-resident keys.
__global__ __launch_bounds__(256) void perm_pass_kernel(uint32_t seed, int round, int n,
                                                        const int* __restrict__ vin,
                                                        int* __restrict__ vout, int m) {
  __shared__ unsigned long long lk[4096];
  __shared__ int part[256];
  uint32_t s0, s1; perm_subkey(seed, round, &s0, &s1);
  int t = threadIdx.x;
  for (int j = t; j < n; j += 256) {
    uint32_t y0, y1; tf2x32(s0, s1, 0u, (uint32_t)j, &y0, &y1);
    lk[j] = ((unsigned long long)(y0 ^ y1) << 32) | (unsigned)j;
  }
  __syncthreads();
  int r = blockIdx.x * 64 + (t & 63);
  int q = t >> 6;
  unsigned long long ki = lk[r];
  int cnt = 0;
  int j0 = q * (n >> 2), j1 = j0 + (n >> 2);
  for (int j = j0; j < j1; j++) cnt += (lk[j] < ki) ? 1 : 0;
  part[t] = cnt;
  __syncthreads();
  if (t < 64) {
    int rank = part[t] + part[t + 64] + part[t + 128] + part[t + 192];
    if (rank < m) vout[rank] = vin ? vin[r] : r;
  }
}

// Fused first passes (HW-verified R10).
__global__ __launch_bounds__(256) void perm_passA_kernel(int* __restrict__ pt1,
                                                         int* __restrict__ sel2) {
  __shared__ unsigned long long lk[4096];
  __shared__ int part[256];
  bool big = (blockIdx.x < 64);
  uint32_t seed = big ? 1u : 2u;
  int n = big ? 4096 : 1024;
  int m = big ? 4096 : 256;
  int* vout = big ? pt1 : sel2;
  int blk = big ? blockIdx.x : (blockIdx.x - 64);
  uint32_t s0, s1; perm_subkey(seed, 0, &s0, &s1);
  int t = threadIdx.x;
  for (int j = t; j < n; j += 256) {
    uint32_t y0, y1; tf2x32(s0, s1, 0u, (uint32_t)j, &y0, &y1);
    lk[j] = ((unsigned long long)(y0 ^ y1) << 32) | (unsigned)j;
  }
  __syncthreads();
  int r = blk * 64 + (t & 63);
  int q = t >> 6;
  unsigned long long ki = lk[r];
  int cnt = 0;
  int j0 = q * (n >> 2), j1 = j0 + (n >> 2);
  for (int j = j0; j < j1; j++) cnt += (lk[j] < ki) ? 1 : 0;
  part[t] = cnt;
  __syncthreads();
  if (t < 64) {
    int rank = part[t] + part[t + 64] + part[t + 128] + part[t + 192];
    if (rank < m) vout[rank] = r;
  }
}

// ---- wave-wide argmin of per-lane heads (proven primitives) ----------------
__device__ inline void wave_argmin2(float head_d, int head_i, float* Mo, int* wio) {
  float M = head_d;
#pragma unroll
  for (int off = 1; off < 64; off <<= 1) M = fminf(M, __shfl_xor(M, off));
  int cand = (head_d == M) ? head_i : 0x7fffffff;
#pragma unroll
  for (int off = 1; off < 64; off <<= 1) cand = min(cand, __shfl_xor(cand, off));
  *Mo = M; *wio = cand;
}

// =================== KNN (N=4096): WAVES waves/row + rank merge (R9-proven) ===
template <int CNT, int WAVES>
__global__ __launch_bounds__(64 * WAVES) void knn_lex_kernel(const float* __restrict__ verts,
                                                             int N,
                                                             int* __restrict__ idx20,
                                                             int* __restrict__ idx4) {
  constexpr int SH = (CNT - 1 < 21) ? (CNT - 1) : 21;
  int row = blockIdx.x; int b = row / N, i = row - b * N;
  int t = threadIdx.x; int w = t >> 6; int lane = t & 63;
  const float* vb = verts + (size_t)b * N * 3;
  float xi = vb[i * 3], yi = vb[i * 3 + 1], zi = vb[i * 3 + 2];
  float sqi = (xi * xi + yi * yi) + zi * zi;

  int base = w * (N / WAVES) + lane;
  float qd[CNT]; int qi[CNT];
#pragma unroll
  for (int m = 0; m < CNT; m++) {
    int j = base + m * 64;
    float xj = vb[j * 3], yj = vb[j * 3 + 1], zj = vb[j * 3 + 2];
    float sqj = (xj * xj + yj * yj) + zj * zj;
    float dot = (xi * xj + yi * yj) + zi * zj;
    qd[m] = sqi + sqj - 2.f * dot;
    qi[m] = j;
  }
#pragma unroll
  for (int k = 2; k <= CNT; k <<= 1)
#pragma unroll
    for (int j = k >> 1; j > 0; j >>= 1)
#pragma unroll
      for (int m = 0; m < CNT; m++) {
        int l = m ^ j;
        if (l > m) {
          bool up = ((m & k) == 0);
          bool sw = up ? (qd[m] > qd[l]) : (qd[m] < qd[l]);
          float td = sw ? qd[l] : qd[m]; qd[l] = sw ? qd[m] : qd[l]; qd[m] = td;
          int ti = sw ? qi[l] : qi[m]; qi[l] = sw ? qi[m] : qi[l]; qi[m] = ti;
        }
      }

  __shared__ float wd[WAVES][21];
  __shared__ int wi[WAVES][21];
  for (int r = 0; r < 21; r++) {
    float M; int widx;
    wave_argmin2(qd[0], qi[0], &M, &widx);
    if (lane == 0) { wd[w][r] = M; wi[w][r] = widx; }
    bool win = (qi[0] == widx);
#pragma unroll
    for (int m = 0; m < SH; m++) {
      qd[m] = win ? qd[m + 1] : qd[m];
      qi[m] = win ? qi[m + 1] : qi[m];
    }
    if (SH == CNT - 1) {
      if (win) { qd[CNT - 1] = FINF; qi[CNT - 1] = 0x7fffffff; }
    }
  }
  __syncthreads();
  if (lane < 21) {
    float d0 = wd[w][lane]; int i0 = wi[w][lane];
    int rank = lane;
#pragma unroll
    for (int w2 = 0; w2 < WAVES; w2++) {
      if (w2 == w) continue;
      for (int p = 0; p < 21; p++) {
        float ld = wd[w2][p]; int li = wi[w2][p];
        rank += (ld < d0 || (ld == d0 && li < i0)) ? 1 : 0;
      }
    }
    if (rank >= 1 && rank <= 20) idx20[(size_t)row * 20 + (rank - 1)] = i0;
    if (rank >= 1 && rank <= 4)  idx4[(size_t)row * 4 + (rank - 1)] = i0;
  }
}

// ====== FAT: knn(v1, N=1024) 4 waves/block [blocks 0..1023] + w2 GEMM [1024..1535]
__global__ __launch_bounds__(256) void knnv1_w2_kernel(const float* __restrict__ verts,
                                                       int* __restrict__ idx20,
                                                       int* __restrict__ idx4,
                                                       const float* __restrict__ x,
                                                       const float* __restrict__ W,
                                                       const float* __restrict__ bias,
                                                       float* __restrict__ y) {
  if (blockIdx.x < 1024) {
    constexpr int CNT = 16;
    const int N = 1024;
    int lane = threadIdx.x & 63;
    int row = blockIdx.x * 4 + (threadIdx.x >> 6);
    int b = row / N, i = row - b * N;
    const float* vb = verts + (size_t)b * N * 3;
    float xi = vb[i * 3], yi = vb[i * 3 + 1], zi = vb[i * 3 + 2];
    float sqi = (xi * xi + yi * yi) + zi * zi;
    float qd[CNT]; int qi[CNT];
#pragma unroll
    for (int m = 0; m < CNT; m++) {
      int j = lane + m * 64;
      float xj = vb[j * 3], yj = vb[j * 3 + 1], zj = vb[j * 3 + 2];
      float sqj = (xj * xj + yj * yj) + zj * zj;
      float dot = (xi * xj + yi * yj) + zi * zj;
      qd[m] = sqi + sqj - 2.f * dot;
      qi[m] = j;
    }
#pragma unroll
    for (int k = 2; k <= CNT; k <<= 1)
#pragma unroll
      for (int j = k >> 1; j > 0; j >>= 1)
#pragma unroll
        for (int m = 0; m < CNT; m++) {
          int l = m ^ j;
          if (l > m) {
            bool up = ((m & k) == 0);
            bool sw = up ? (qd[m] > qd[l]) : (qd[m] < qd[l]);
            float td = sw ? qd[l] : qd[m]; qd[l] = sw ? qd[m] : qd[l]; qd[m] = td;
            int ti = sw ? qi[l] : qi[m]; qi[l] = sw ? qi[m] : qi[l]; qi[m] = ti;
          }
        }
    for (int r = 0; r < 21; r++) {
      float M; int widx;
      wave_argmin2(qd[0], qi[0], &M, &widx);
      if (lane == 0 && r >= 1) {
        idx20[(size_t)row * 20 + (r - 1)] = widx;
        if (r <= 4) idx4[(size_t)row * 4 + (r - 1)] = widx;
      }
      bool win = (qi[0] == widx);
#pragma unroll
      for (int m = 0; m < CNT - 1; m++) {
        qd[m] = win ? qd[m + 1] : qd[m];
        qi[m] = win ? qi[m + 1] : qi[m];
      }
      if (win) { qd[CNT - 1] = FINF; qi[CNT - 1] = 0x7fffffff; }
    }
  } else {
    const int I = 64, O = 256;
    int rb = (blockIdx.x - 1024) * 8;
    int o = threadIdx.x;
    __shared__ float xs[64][8];
    for (int u = 0; u < 8; u++)
      for (int i2 = threadIdx.x; i2 < I; i2 += 256) xs[i2][u] = x[(size_t)(rb + u) * I + i2];
    __syncthreads();
    float a[8] = {0, 0, 0, 0, 0, 0, 0, 0};
    for (int k2 = 0; k2 < I; k2++) {
      float wv = W[(size_t)k2 * O + o];
      float4 xa = *(const float4*)&xs[k2][0];
      float4 xb = *(const float4*)&xs[k2][4];
      a[0] += xa.x * wv; a[1] += xa.y * wv; a[2] += xa.z * wv; a[3] += xa.w * wv;
      a[4] += xb.x * wv; a[5] += xb.y * wv; a[6] += xb.z * wv; a[7] += xb.w * wv;
    }
    float bv = bias[o];
#pragma unroll
    for (int u = 0; u < 8; u++) y[(size_t)(rb + u) * O + o] = a[u] + bv;
  }
}

// =================== conv_surface, 4 rows/block (wave-local) ==================
__global__ __launch_bounds__(256) void conv_surface_kernel(const float* __restrict__ verts,
                                                           const int* __restrict__ idx20,
                                                           const float* __restrict__ d0,
                                                           const float* __restrict__ g,
                                                           const float* __restrict__ be,
                                                           float* __restrict__ out, int N) {
  int w = threadIdx.x >> 6; int t = threadIdx.x & 63;
  int row = blockIdx.x * 4 + w; int b = row / N, i = row - b * N;
  __shared__ float nd[4][20][3];
  const float* vb = verts + (size_t)b * N * 3;
  if (t < 20) {
    int j = idx20[(size_t)row * 20 + t];
    float dx = vb[j * 3] - vb[i * 3], dy = vb[j * 3 + 1] - vb[i * 3 + 1], dz = vb[j * 3 + 2] - vb[i * 3 + 2];
    float n2 = sqrtf(dx * dx + dy * dy + dz * dz); n2 = fmaxf(n2, 1e-12f);
    nd[w][t][0] = dx / n2; nd[w][t][1] = dy / n2; nd[w][t][2] = dz / n2;
  }
  float x = 0.f;
  if (t < 32) {
    float a = d0[t], bb2 = d0[32 + t], c = d0[64 + t];
    float nrm = fmaxf(sqrtf(a * a + bb2 * bb2 + c * c), 1e-12f);
    a /= nrm; bb2 /= nrm; c /= nrm;
    float mx = -FINF;
    for (int kk = 0; kk < 20; kk++) {
      float th = fmaxf(nd[w][kk][0] * a + nd[w][kk][1] * bb2 + nd[w][kk][2] * c, 0.f);
      mx = fmaxf(mx, th);
    }
    x = mx;
  }
  float s = x;
  for (int off = 32; off; off >>= 1) s += __shfl_xor(s, off);
  float mean = s / 32.f;
  float dev = (t < 32) ? x - mean : 0.f;
  float s2 = dev * dev;
  for (int off = 32; off; off >>= 1) s2 += __shfl_xor(s2, off);
  float var = s2 / 32.f;
  if (t < 32) {
    float y = (x - mean) / sqrtf(var + 1e-6f) * g[t] + be[t];
    out[(size_t)row * 32 + t] = fmaxf(y, 0.f);
  }
}

// =================== GEMM: y = x(R,I) @ W(I,O) + bias, 8 rows/block ===========
__global__ void gemm_io_kernel(const float* __restrict__ x, const float* __restrict__ W,
                               const float* __restrict__ bias, float* __restrict__ y,
                               int R, int I, int O) {
  int rb = blockIdx.x * 8;
  int o = blockIdx.y * blockDim.x + threadIdx.x;
  __shared__ float xs[256][8];
  for (int u = 0; u < 8; u++)
    for (int i2 = threadIdx.x; i2 < I; i2 += blockDim.x) xs[i2][u] = x[(size_t)(rb + u) * I + i2];
  __syncthreads();
  float a[8] = {0, 0, 0, 0, 0, 0, 0, 0};
  for (int k2 = 0; k2 < I; k2++) {
    float wv = W[(size_t)k2 * O + o];
    float4 xa = *(const float4*)&xs[k2][0];
    float4 xb = *(const float4*)&xs[k2][4];
    a[0] += xa.x * wv; a[1] += xa.y * wv; a[2] += xa.z * wv; a[3] += xa.w * wv;
    a[4] += xb.x * wv; a[5] += xb.y * wv; a[6] += xb.z * wv; a[7] += xb.w * wv;
  }
  float bv = bias[o];
#pragma unroll
  for (int u = 0; u < 8; u++) y[(size_t)(rb + u) * O + o] = a[u] + bv;
}

// ======== GEMM 8 rows x 2 cols/thread (w3: O=512, 256 thr -> o, o+256) ========
__global__ __launch_bounds__(256) void gemm_mc2_kernel(const float* __restrict__ x,
                                                       const float* __restrict__ W,
                                                       const float* __restrict__ bias,
                                                       float* __restrict__ y,
                                                       int R, int I, int O) {
  int rb = blockIdx.x * 8;
  int o = threadIdx.x;
  __shared__ float xs[256][8];
  for (int u = 0; u < 8; u++)
    for (int i2 = threadIdx.x; i2 < I; i2 += 256) xs[i2][u] = x[(size_t)(rb + u) * I + i2];
  __syncthreads();
  float a0[8] = {0, 0, 0, 0, 0, 0, 0, 0};
  float a1[8] = {0, 0, 0, 0, 0, 0, 0, 0};
  for (int k2 = 0; k2 < I; k2++) {
    float wv0 = W[(size_t)k2 * O + o];
    float wv1 = W[(size_t)k2 * O + o + 256];
    float4 xa = *(const float4*)&xs[k2][0];
    float4 xb = *(const float4*)&xs[k2][4];
    a0[0] += xa.x * wv0; a0[1] += xa.y * wv0; a0[2] += xa.z * wv0; a0[3] += xa.w * wv0;
    a0[4] += xb.x * wv0; a0[5] += xb.y * wv0; a0[6] += xb.z * wv0; a0[7] += xb.w * wv0;
    a1[0] += xa.x * wv1; a1[1] += xa.y * wv1; a1[2] += xa.z * wv1; a1[3] += xa.w * wv1;
    a1[4] += xb.x * wv1; a1[5] += xb.y * wv1; a1[6] += xb.z * wv1; a1[7] += xb.w * wv1;
  }
  float bv0 = bias[o], bv1 = bias[o + 256];
#pragma unroll
  for (int u = 0; u < 8; u++) {
    y[(size_t)(rb + u) * O + o] = a0[u] + bv0;
    y[(size_t)(rb + u) * O + o + 256] = a1[u] + bv1;
  }
}

// ======== GEMM 8 rows x 4 cols/thread (w7: O=2048, grid.y*1024 + t + m*256) ===
__global__ __launch_bounds__(256) void gemm_mc4_kernel(const float* __restrict__ x,
                                                       const float* __restrict__ W,
                                                       const float* __restrict__ bias,
                                                       float* __restrict__ y,
                                                       int R, int I, int O) {
  int rb = blockIdx.x * 8;
  int o = blockIdx.y * 1024 + threadIdx.x;
  __shared__ float xs[256][8];
  for (int u = 0; u < 8; u++)
    for (int i2 = threadIdx.x; i2 < I; i2 += 256) xs[i2][u] = x[(size_t)(rb + u) * I + i2];
  __syncthreads();
  float a[4][8];
#pragma unroll
  for (int m = 0; m < 4; m++)
#pragma unroll
    for (int u = 0; u < 8; u++) a[m][u] = 0.f;
  for (int k2 = 0; k2 < I; k2++) {
    float4 xa = *(const float4*)&xs[k2][0];
    float4 xb = *(const float4*)&xs[k2][4];
#pragma unroll
    for (int m = 0; m < 4; m++) {
      float wv = W[(size_t)k2 * O + o + m * 256];
      a[m][0] += xa.x * wv; a[m][1] += xa.y * wv; a[m][2] += xa.z * wv; a[m][3] += xa.w * wv;
      a[m][4] += xb.x * wv; a[m][5] += xb.y * wv; a[m][6] += xb.z * wv; a[m][7] += xb.w * wv;
    }
  }
#pragma unroll
  for (int m = 0; m < 4; m++) {
    float bv = bias[o + m * 256];
#pragma unroll
    for (int u = 0; u < 8; u++) y[(size_t)(rb + u) * O + o + m * 256] = a[m][u] + bv;
  }
}

// =================== conv_layer combine (k-loop hoisted) ===================
template <int CPT>
__global__ void combine_kernel(const float* __restrict__ verts, const int* __restrict__ idx20,
                               const float* __restrict__ fo, const float* __restrict__ dirs,
                               const float* __restrict__ g, const float* __restrict__ be,
                               float* __restrict__ out, int N, int C) {
  int row = blockIdx.x; int b = row / N, i = row - b * N;
  int t = threadIdx.x, bs = blockDim.x;
  __shared__ float nd[20][3];
  __shared__ int nidx[20];
  __shared__ float red[8];
  const float* vb = verts + (size_t)b * N * 3;
  if (t < 20) {
    int j = idx20[(size_t)row * 20 + t];
    nidx[t] = j;
    float dx = vb[j * 3] - vb[i * 3], dy = vb[j * 3 + 1] - vb[i * 3 + 1], dz = vb[j * 3 + 2] - vb[i * 3 + 2];
    float n2 = fmaxf(sqrtf(dx * dx + dy * dy + dz * dz), 1e-12f);
    nd[t][0] = dx / n2; nd[t][1] = dy / n2; nd[t][2] = dz / n2;
  }
  __syncthreads();
  const float* fob = fo + (size_t)b * N * 2 * C;
  const float* forow = fob + (size_t)i * 2 * C;
  float da[CPT], db[CPT], dc[CPT], mx[CPT];
#pragma unroll
  for (int u = 0; u < CPT; u++) {
    int c = t + u * bs;
    float a = dirs[c], bb = dirs[C + c], cc = dirs[2 * C + c];
    float nrm = fmaxf(sqrtf(a * a + bb * bb + cc * cc), 1e-12f);
    da[u] = a / nrm; db[u] = bb / nrm; dc[u] = cc / nrm;
    mx[u] = -FINF;
  }
  for (int kk = 0; kk < 20; kk++) {
    float n0 = nd[kk][0], n1 = nd[kk][1], n2v = nd[kk][2];
    const float* sup = fob + (size_t)nidx[kk] * 2 * C + C + t;
#pragma unroll
    for (int u = 0; u < CPT; u++) {
      float th = fmaxf(n0 * da[u] + n1 * db[u] + n2v * dc[u], 0.f);
      mx[u] = fmaxf(mx[u], th * sup[u * bs]);
    }
  }
  float xv[CPT];
  float ssum = 0.f;
#pragma unroll
  for (int u = 0; u < CPT; u++) {
    int c = t + u * bs;
    float val = forow[c] + mx[u];
    xv[u] = val; ssum += val;
  }
  int nw = bs >> 6;
  for (int off = 32; off; off >>= 1) ssum += __shfl_down(ssum, off);
  if ((t & 63) == 0) red[t >> 6] = ssum;
  __syncthreads();
  if (t == 0) { float s = red[0]; for (int w = 1; w < nw; w++) s += red[w]; red[0] = s; }
  __syncthreads();
  float mean = red[0] / (float)C;
  __syncthreads();
  float s2 = 0.f;
#pragma unroll
  for (int u = 0; u < CPT; u++) { float d2 = xv[u] - mean; s2 += d2 * d2; }
  for (int off = 32; off; off >>= 1) s2 += __shfl_down(s2, off);
  if ((t & 63) == 0) red[t >> 6] = s2;
  __syncthreads();
  if (t == 0) { float s = red[0]; for (int w = 1; w < nw; w++) s += red[w]; red[0] = s; }
  __syncthreads();
  float inv = 1.0f / sqrtf(red[0] / (float)C + 1e-6f);
#pragma unroll
  for (int u = 0; u < CPT; u++) {
    int c = t + u * bs;
    float yv = (xv[u] - mean) * inv * g[c] + be[c];
    out[(size_t)row * C + c] = fmaxf(yv, 0.f);
  }
}

// =================== pool (max over 4 NN) + row-select ===================
__global__ void pool_select_kernel(const float* __restrict__ fm, const int* __restrict__ idx4,
                                   const int* __restrict__ sel, const float* __restrict__ vin,
                                   float* __restrict__ vout, float* __restrict__ out,
                                   int N, int M, int C) {
  int row = blockIdx.x; int b = row / M, r = row - b * M;
  int s = sel[r];
  const int* id = idx4 + ((size_t)b * N + s) * 4;
  int i0 = id[0], i1 = id[1], i2 = id[2], i3 = id[3];
  const float* fb = fm + (size_t)b * N * C;
  for (int c = threadIdx.x; c < C; c += blockDim.x) {
    float m = fmaxf(fmaxf(fb[(size_t)i0 * C + c], fb[(size_t)i1 * C + c]),
                    fmaxf(fb[(size_t)i2 * C + c], fb[(size_t)i3 * C + c]));
    out[((size_t)b * M + r) * C + c] = m;
  }
  if (vout != nullptr && threadIdx.x < 3)
    vout[((size_t)b * M + r) * 3 + threadIdx.x] = vin[((size_t)b * N + s) * 3 + threadIdx.x];
}

// =================== linear: y = x(R,I) @ W(O,I)^T + bias (+res) ===================
__global__ void linear_oi_kernel(const float* __restrict__ x, const float* __restrict__ W,
                                 const float* __restrict__ bias, const float* __restrict__ res,
                                 float* __restrict__ y, int R, int I, int O) {
  int rb = blockIdx.x * 8;
  int o = threadIdx.x;
  __shared__ float xs[8][256];
  for (int u = 0; u < 8; u++)
    for (int i2 = threadIdx.x; i2 < I; i2 += O) xs[u][i2] = x[(size_t)(rb + u) * I + i2];
  __syncthreads();
  float a[8] = {0, 0, 0, 0, 0, 0, 0, 0};
  const float* w = W + (size_t)o * I;
  for (int k2 = 0; k2 < I; k2++) {
    float wv = w[k2];
#pragma unroll
    for (int u = 0; u < 8; u++) a[u] += xs[u][k2] * wv;
  }
  float bv = bias[o];
#pragma unroll
  for (int u = 0; u < 8; u++) {
    float val = a[u] + bv;
    if (res) val += res[(size_t)(rb + u) * O + o];
    y[(size_t)(rb + u) * O + o] = val;
  }
}

// ===== fused a1_out linear (+residual) -> ffn1 linear (row-local chain) =======
__global__ __launch_bounds__(256) void a1out_ffn1_kernel(const float* __restrict__ att,
                                                         const float* __restrict__ Wo,
                                                         const float* __restrict__ bo,
                                                         const float* __restrict__ res,
                                                         const float* __restrict__ W1,
                                                         const float* __restrict__ b1_,
                                                         float* __restrict__ x1out) {
  int rb = blockIdx.x * 8;
  int t = threadIdx.x;
  __shared__ float xs[8][64];
  __shared__ float qs[64][8];  // query tile transposed [k][u]
  for (int e = t; e < 512; e += 256) {
    int u = e >> 6, c = e & 63;
    xs[u][c] = att[(size_t)(rb + u) * 64 + c];
  }
  __syncthreads();
  // phase 1: query = att @ Wo^T + bo + res (2 outputs/thread), same k order
  for (int e = t; e < 512; e += 256) {
    int u = e >> 6, o = e & 63;
    const float* w = Wo + (size_t)o * 64;
    float acc = 0.f;
    for (int k = 0; k < 64; k++) acc += xs[u][k] * w[k];
    float val = acc + bo[o];
    val += res[(size_t)(rb + u) * 64 + o];
    qs[o][u] = val;
  }
  __syncthreads();
  // phase 2: x1 = query @ W1^T + b1
  float a[8] = {0, 0, 0, 0, 0, 0, 0, 0};
  const float* w = W1 + (size_t)t * 64;
  for (int k = 0; k < 64; k++) {
    float wv = w[k];
    float4 xa = *(const float4*)&qs[k][0];
    float4 xb = *(const float4*)&qs[k][4];
    a[0] += xa.x * wv; a[1] += xa.y * wv; a[2] += xa.z * wv; a[3] += xa.w * wv;
    a[4] += xb.x * wv; a[5] += xb.y * wv; a[6] += xb.z * wv; a[7] += xb.w * wv;
  }
  float bv = b1_[t];
#pragma unroll
  for (int u = 0; u < 8; u++) x1out[(size_t)(rb + u) * 256 + t] = a[u] + bv;
}

// ===== fused BN-apply -> ffn2 linear -> q2 linear (row-local chain) ===========
__global__ __launch_bounds__(256) void ffn2_q2_kernel(const float* __restrict__ x,
                                                      const float* __restrict__ W2,
                                                      const float* __restrict__ b2_,
                                                      const float* __restrict__ stats,
                                                      const float* __restrict__ g,
                                                      const float* __restrict__ bb,
                                                      const float* __restrict__ Wq,
                                                      const float* __restrict__ bq,
                                                      float* __restrict__ query2,
                                                      float* __restrict__ q2out) {
  int rb = blockIdx.x * 8;
  int o = threadIdx.x;  // 256
  __shared__ float xs[256][8];  // bn-relu'd input, transposed [k][u]
  __shared__ float qs[256][8];  // query2 tile transposed
  float mo = stats[o], vo = stats[256 + o], go = g[o], bo = bb[o];
  for (int u = 0; u < 8; u++) {
    float xr = x[(size_t)(rb + u) * 256 + o];
    float yv = (xr - mo) / sqrtf(vo + 1e-5f) * go + bo;
    xs[o][u] = fmaxf(yv, 0.f);
  }
  __syncthreads();
  float a[8] = {0, 0, 0, 0, 0, 0, 0, 0};
  const float* w = W2 + (size_t)o * 256;
  for (int k = 0; k < 256; k++) {
    float wv = w[k];
    float4 xa = *(const float4*)&xs[k][0];
    float4 xb = *(const float4*)&xs[k][4];
    a[0] += xa.x * wv; a[1] += xa.y * wv; a[2] += xa.z * wv; a[3] += xa.w * wv;
    a[4] += xb.x * wv; a[5] += xb.y * wv; a[6] += xb.z * wv; a[7] += xb.w * wv;
  }
  float bv = b2_[o];
#pragma unroll
  for (int u = 0; u < 8; u++) {
    float val = a[u] + bv;
    qs[o][u] = val;
    query2[(size_t)(rb + u) * 256 + o] = val;
  }
  __syncthreads();
  float c[8] = {0, 0, 0, 0, 0, 0, 0, 0};
  const float* wq = Wq + (size_t)o * 256;
  for (int k = 0; k < 256; k++) {
    float wv = wq[k];
    float4 xa = *(const float4*)&qs[k][0];
    float4 xb = *(const float4*)&qs[k][4];
    c[0] += xa.x * wv; c[1] += xa.y * wv; c[2] += xa.z * wv; c[3] += xa.w * wv;
    c[4] += xb.x * wv; c[5] += xb.y * wv; c[6] += xb.z * wv; c[7] += xb.w * wv;
  }
  float bqv = bq[o];
#pragma unroll
  for (int u = 0; u < 8; u++) q2out[(size_t)(rb + u) * 256 + o] = c[u] + bqv;
}

// =================== fused QKV for MHA1 (token transpose folded into Q) =======
__global__ __launch_bounds__(64) void qkv1_kernel(const float* __restrict__ token,
                                                  const float* __restrict__ fm1p,
                                                  const float* __restrict__ Win,
                                                  const float* __restrict__ bin,
                                                  float* __restrict__ Q1,
                                                  float* __restrict__ K1,
                                                  float* __restrict__ V1) {
  int ybr = blockIdx.y;
  const float* W = Win + (size_t)ybr * 64 * 64;
  const float* bias = bin + ybr * 64;
  float* out = (ybr == 0) ? Q1 : (ybr == 1) ? K1 : V1;
  int rb = blockIdx.x * 8;
  int o = threadIdx.x;
  __shared__ float xs[8][64];
  if (ybr == 0) {
    for (int u = 0; u < 8; u++) {
      int n = (rb + u) & 1023;
      xs[u][o] = token[(size_t)o * 1024 + n];
    }
  } else {
    for (int u = 0; u < 8; u++) xs[u][o] = fm1p[(size_t)(rb + u) * 64 + o];
  }
  __syncthreads();
  float a[8] = {0, 0, 0, 0, 0, 0, 0, 0};
  const float* w = W + (size_t)o * 64;
  for (int k2 = 0; k2 < 64; k2++) {
    float wv = w[k2];
#pragma unroll
    for (int u = 0; u < 8; u++) a[u] += xs[u][k2] * wv;
  }
  float bv = bias[o];
#pragma unroll
  for (int u = 0; u < 8; u++) out[(size_t)(rb + u) * 64 + o] = a[u] + bv;
}

// =================== fused K2/V2 for MHA2 ===================
__global__ __launch_bounds__(256) void kv2_kernel(const float* __restrict__ fm3p,
                                                  const float* __restrict__ Win,
                                                  const float* __restrict__ bin,
                                                  float* __restrict__ K2,
                                                  float* __restrict__ V2) {
  int ybr = blockIdx.y;
  const float* W = Win + (size_t)(1 + ybr) * 256 * 256;
  const float* bias = bin + (1 + ybr) * 256;
  float* out = ybr ? V2 : K2;
  int rb = blockIdx.x * 8;
  int o = threadIdx.x;
  __shared__ float xs[8][256];
  for (int u = 0; u < 8; u++) xs[u][o] = fm3p[(size_t)(rb + u) * 256 + o];
  __syncthreads();
  float a[8] = {0, 0, 0, 0, 0, 0, 0, 0};
  const float* w = W + (size_t)o * 256;
  for (int k2 = 0; k2 < 256; k2++) {
    float wv = w[k2];
#pragma unroll
    for (int u = 0; u < 8; u++) a[u] += xs[u][k2] * wv;
  }
  float bv = bias[o];
#pragma unroll
  for (int u = 0; u < 8; u++) out[(size_t)(rb + u) * 256 + o] = a[u] + bv;
}

// =================== tiled flash attention ===================
template <int HD, int QPT, int KS>
__global__ __launch_bounds__(256) void attn_tiled(
    const float* __restrict__ q, const float* __restrict__ kk,
    const float* __restrict__ vv, float* __restrict__ o,
    int Lq, int Lk, int H, float scale) {
  constexpr int TK = 64;
  constexpr int QG = 256 / (2 * KS);
  constexpr int QPB = QG * QPT;
  constexpr int V4 = HD / 4;
  constexpr int STR = V4 + 1;
  constexpr int HH = HD / 2;
  constexpr int V4H = HH / 4;

  __shared__ float4 Ks[TK * STR];
  __shared__ float4 Vs[TK * STR];

  int t = threadIdx.x;
  int dh = t & 1;
  int ki = (t >> 1) & (KS - 1);
  int qg = t / (2 * KS);
  int nqt = Lq / QPB;
  int qt = blockIdx.x % nqt, bh = blockIdx.x / nqt;
  int h = bh % H, b = bh / H;
  int E = H * HD;
  int q0 = qt * QPB + qg * QPT;

  const float* qbase = q + ((size_t)b * Lq + q0) * E + h * HD + dh * HH;
  const float* kbase = kk + (size_t)b * Lk * E + h * HD;
  const float* vbase = vv + (size_t)b * Lk * E + h * HD;

  float qr[QPT][HH], O[QPT][HH], m[QPT], l[QPT];
#pragma unroll
  for (int r = 0; r < QPT; r++) {
    m[r] = -FINF; l[r] = 0.f;
#pragma unroll
    for (int d = 0; d < HH; d++) { qr[r][d] = qbase[(size_t)r * E + d]; O[r][d] = 0.f; }
  }

  for (int k0 = 0; k0 < Lk; k0 += TK) {
    __syncthreads();
    for (int e = t; e < TK * V4; e += 256) {
      int rr = e / V4, cc = e - rr * V4;
      Ks[rr * STR + cc] = *(const float4*)(kbase + (size_t)(k0 + rr) * E + cc * 4);
      Vs[rr * STR + cc] = *(const float4*)(vbase + (size_t)(k0 + rr) * E + cc * 4);
    }
    __syncthreads();
#pragma unroll 1
    for (int g = 0; g < TK / KS; g += 4) {
      float sc[QPT][4];
#pragma unroll
      for (int jj = 0; jj < 4; jj++) {
        int kl = (g + jj) * KS + ki;
        float sh[QPT];
#pragma unroll
        for (int r = 0; r < QPT; r++) sh[r] = 0.f;
        const float4* kr = &Ks[kl * STR + dh * V4H];
#pragma unroll
        for (int c = 0; c < V4H; c++) {
          float4 kv = kr[c];
#pragma unroll
          for (int r = 0; r < QPT; r++)
            sh[r] += qr[r][4 * c] * kv.x + qr[r][4 * c + 1] * kv.y
                   + qr[r][4 * c + 2] * kv.z + qr[r][4 * c + 3] * kv.w;
        }
#pragma unroll
        for (int r = 0; r < QPT; r++)
          sc[r][jj] = (sh[r] + __shfl_xor(sh[r], 1)) * scale;
      }
#pragma unroll
      for (int r = 0; r < QPT; r++) {
        float tm = fmaxf(fmaxf(sc[r][0], sc[r][1]), fmaxf(sc[r][2], sc[r][3]));
        float nm = fmaxf(m[r], tm);
        float a = __expf(m[r] - nm);
        m[r] = nm;
        float ls = l[r] * a;
#pragma unroll
        for (int d = 0; d < HH; d++) O[r][d] *= a;
#pragma unroll
        for (int jj = 0; jj < 4; jj++) { sc[r][jj] = __expf(sc[r][jj] - nm); ls += sc[r][jj]; }
        l[r] = ls;
      }
#pragma unroll
      for (int jj = 0; jj < 4; jj++) {
        int kl = (g + jj) * KS + ki;
        const float4* vr = &Vs[kl * STR + dh * V4H];
#pragma unroll
        for (int c = 0; c < V4H; c++) {
          float4 v4 = vr[c];
#pragma unroll
          for (int r = 0; r < QPT; r++) {
            O[r][4 * c]     += sc[r][jj] * v4.x;
            O[r][4 * c + 1] += sc[r][jj] * v4.y;
            O[r][4 * c + 2] += sc[r][jj] * v4.z;
            O[r][4 * c + 3] += sc[r][jj] * v4.w;
          }
        }
      }
    }
  }
#pragma unroll
  for (int r = 0; r < QPT; r++) {
    float M = m[r];
#pragma unroll
    for (int mask = 2; mask < 2 * KS; mask <<= 1) M = fmaxf(M, __shfl_xor(M, mask));
    float w = __expf(m[r] - M);
    float ll = l[r] * w;
#pragma unroll
    for (int mask = 2; mask < 2 * KS; mask <<= 1) ll += __shfl_xor(ll, mask);
    float inv = 1.f / ll;
#pragma unroll
    for (int d = 0; d < HH; d++) {
      float x = O[r][d] * w;
#pragma unroll
      for (int mask = 2; mask < 2 * KS; mask <<= 1) x += __shfl_xor(x, mask);
      O[r][d] = x * inv;
    }
  }
  if (ki == 0) {
    float* obase = o + ((size_t)b * Lq + q0) * E + h * HD + dh * HH;
#pragma unroll
    for (int r = 0; r < QPT; r++)
#pragma unroll
      for (int d = 0; d < HH; d++) obase[(size_t)r * E + d] = O[r][d];
  }
}

// =================== BN stats, 4 cols/block via float4 (same reduce order) ====
__global__ __launch_bounds__(256) void bn_stats4_kernel(const float* __restrict__ x,
                                                        float* __restrict__ stats,
                                                        int R, int C) {
  int c4 = blockIdx.x * 4;
  int t = threadIdx.x;
  __shared__ float red[4][4];
  __shared__ float mean4[4];
  float4 s = make_float4(0.f, 0.f, 0.f, 0.f);
  for (int r = t; r < R; r += 256) {
    float4 v = *(const float4*)&x[(size_t)r * C + c4];
    s.x += v.x; s.y += v.y; s.z += v.z; s.w += v.w;
  }
  for (int off = 32; off; off >>= 1) {
    s.x += __shfl_down(s.x, off); s.y += __shfl_down(s.y, off);
    s.z += __shfl_down(s.z, off); s.w += __shfl_down(s.w, off);
  }
  if ((t & 63) == 0) { int w = t >> 6; red[w][0] = s.x; red[w][1] = s.y; red[w][2] = s.z; red[w][3] = s.w; }
  __syncthreads();
  if (t < 4) {
    float a = red[0][t]; a += red[1][t]; a += red[2][t]; a += red[3][t];
    mean4[t] = a / (float)R;
  }
  __syncthreads();
  float m0 = mean4[0], m1 = mean4[1], m2 = mean4[2], m3 = mean4[3];
  float4 s2 = make_float4(0.f, 0.f, 0.f, 0.f);
  for (int r = t; r < R; r += 256) {
    float4 v = *(const float4*)&x[(size_t)r * C + c4];
    float d;
    d = v.x - m0; s2.x += d * d;
    d = v.y - m1; s2.y += d * d;
    d = v.z - m2; s2.z += d * d;
    d = v.w - m3; s2.w += d * d;
  }
  for (int off = 32; off; off >>= 1) {
    s2.x += __shfl_down(s2.x, off); s2.y += __shfl_down(s2.y, off);
    s2.z += __shfl_down(s2.z, off); s2.w += __shfl_down(s2.w, off);
  }
  if ((t & 63) == 0) { int w = t >> 6; red[w][0] = s2.x; red[w][1] = s2.y; red[w][2] = s2.z; red[w][3] = s2.w; }
  __syncthreads();
  if (t < 4) {
    float a = red[0][t]; a += red[1][t]; a += red[2][t]; a += red[3][t];
    stats[c4 + t] = mean4[t];
    stats[C + c4 + t] = a / (float)R;
  }
}

// =================== final conv1x1, 8 rows x 2 cols/thread ===================
__global__ __launch_bounds__(128) void final_kernel(const float* __restrict__ fmf,
                                                    const float* __restrict__ W,
                                                    const float* __restrict__ bias,
                                                    float* __restrict__ out) {
  int nb = blockIdx.x * 8;
  int o = threadIdx.x;  // cols o, o+128
  __shared__ float xs[1024][8];
  for (int u = 0; u < 8; u++)
    for (int c = threadIdx.x; c < 1024; c += 128) xs[c][u] = fmf[(size_t)(nb + u) * 1024 + c];
  __syncthreads();
  float a0[8] = {0, 0, 0, 0, 0, 0, 0, 0};
  float a1[8] = {0, 0, 0, 0, 0, 0, 0, 0};
  const float* w0 = W + (size_t)o * 1024;
  const float* w1 = W + (size_t)(o + 128) * 1024;
  for (int c = 0; c < 1024; c++) {
    float wv0 = w0[c], wv1 = w1[c];
    float4 xa = *(const float4*)&xs[c][0];
    float4 xb = *(const float4*)&xs[c][4];
    a0[0] += xa.x * wv0; a0[1] += xa.y * wv0; a0[2] += xa.z * wv0; a0[3] += xa.w * wv0;
    a0[4] += xb.x * wv0; a0[5] += xb.y * wv0; a0[6] += xb.z * wv0; a0[7] += xb.w * wv0;
    a1[0] += xa.x * wv1; a1[1] += xa.y * wv1; a1[2] += xa.z * wv1; a1[3] += xa.w * wv1;
    a1[4] += xb.x * wv1; a1[5] += xb.y * wv1; a1[6] += xb.z * wv1; a1[7] += xb.w * wv1;
  }
  float bv0 = bias[o], bv1 = bias[o + 128];
#pragma unroll
  for (int u = 0; u < 8; u++) {
    int r = nb + u; int b = r >> 10; int n = r & 1023;
    out[((size_t)(b * 256 + o) << 10) + n] = a0[u] + bv0;
    out[((size_t)(b * 256 + o + 128) << 10) + n] = a1[u] + bv1;
  }
}

// =================== launch ===================
extern "C" void kernel_launch(void* const* d_in, const int* in_sizes, int n_in,
                              void* d_out, int out_size, void* d_ws, size_t ws_size,
                              hipStream_t stream) {
  (void)in_sizes; (void)n_in; (void)out_size;
  const float* vertices = (const float*)d_in[0];
  const float* d0       = (const float*)d_in[1];
  const float* g0       = (const float*)d_in[2];
  const float* be0      = (const float*)d_in[3];
  const float* w1       = (const float*)d_in[4];
  const float* b1       = (const float*)d_in[5];
  const float* dir1     = (const float*)d_in[6];
  const float* g1       = (const float*)d_in[7];
  const float* be1      = (const float*)d_in[8];
  const float* w2       = (const float*)d_in[9];
  const float* b2       = (const float*)d_in[10];
  const float* dir2     = (const float*)d_in[11];
  const float* g2       = (const float*)d_in[12];
  const float* be2      = (const float*)d_in[13];
  const float* w3       = (const float*)d_in[14];
  const float* b3       = (const float*)d_in[15];
  const float* dir3     = (const float*)d_in[16];
  const float* g3       = (const float*)d_in[17];
  const float* be3      = (const float*)d_in[18];
  const float* token    = (const float*)d_in[19];
  const float* a1_in_w  = (const float*)d_in[20];
  const float* a1_in_b  = (const float*)d_in[21];
  const float* a1_out_w = (const float*)d_in[22];
  const float* a1_out_b = (const float*)d_in[23];
  const float* ffn1_w   = (const float*)d_in[24];
  const float* ffn1_b   = (const float*)d_in[25];
  const float* bg       = (const float*)d_in[26];
  const float* bbp      = (const float*)d_in[27];
  const float* ffn2_w   = (const float*)d_in[28];
  const float* ffn2_b   = (const float*)d_in[29];
  const float* a2_in_w  = (const float*)d_in[30];
  const float* a2_in_b  = (const float*)d_in[31];
  const float* a2_out_w = (const float*)d_in[32];
  const float* a2_out_b = (const float*)d_in[33];
  const float* w7       = (const float*)d_in[34];
  const float* b7       = (const float*)d_in[35];
  const float* dir7     = (const float*)d_in[36];
  const float* g4       = (const float*)d_in[37];
  const float* be4      = (const float*)d_in[38];
  const float* c8_w     = (const float*)d_in[39];
  const float* c8_b     = (const float*)d_in[40];
  float* out = (float*)d_out;
  float* ws = (float*)d_ws;

  if (ws_size < 78568448u) return;

  float* FO     = ws + 0;
  float* S1     = ws + 8388608;
  float* S2     = ws + 12582912;
  float* S3     = ws + 13631488;
  float* QUERY2 = ws + 14680064;
  float* CROSS  = ws + 15728640;
  float* FM1P   = ws + 16777216;
  float* FM3P   = FM1P + 262144;
  float* TOK    = FM3P + 262144;  // unused
  float* Q1     = TOK + 262144;
  float* K1     = Q1 + 262144;
  float* VA1    = K1 + 262144;
  float* ATT1   = VA1 + 262144;
  float* K2     = ATT1 + 262144;
  float* V2     = K2 + 262144;
  float* V1     = V2 + 262144;
  float* BNST   = V1 + 12288;
  int* IDX20_0  = (int*)(BNST + 512);
  int* IDX4_0   = IDX20_0 + 327680;
  int* IDX20_1  = IDX4_0 + 65536;
  int* IDX4_1   = IDX20_1 + 81920;
  int* SEL1     = IDX4_1 + 16384;
  int* SEL2     = SEL1 + 1024;
  int* PT1 = IDX20_0;  // transient

  perm_passA_kernel<<<80, 256, 0, stream>>>(PT1, SEL2);
  perm_pass_kernel<<<64, 256, 0, stream>>>(1u, 1, 4096, PT1, SEL1, 1024);

  knn_lex_kernel<32, 2><<<4 * 4096, 128, 0, stream>>>(vertices, 4096, IDX20_0, IDX4_0);
  conv_surface_kernel<<<4096, 256, 0, stream>>>(vertices, IDX20_0, d0, g0, be0, S2, 4096);
  gemm_io_kernel<<<dim3(2048, 1), 128, 0, stream>>>(S2, w1, b1, FO, 16384, 32, 128);
  combine_kernel<1><<<16384, 64, 0, stream>>>(vertices, IDX20_0, FO, dir1, g1, be1, S1, 4096, 64);
  pool_select_kernel<<<4096, 64, 0, stream>>>(S1, IDX4_0, SEL1, vertices, V1, FM1P, 4096, 1024, 64);

  // knn(v1) + w2 GEMM fat dispatch
  knnv1_w2_kernel<<<1536, 256, 0, stream>>>(V1, IDX20_1, IDX4_1, FM1P, w2, b2, FO);
  combine_kernel<1><<<4096, 128, 0, stream>>>(V1, IDX20_1, FO, dir2, g2, be2, S2, 1024, 128);
  gemm_mc2_kernel<<<512, 256, 0, stream>>>(S2, w3, b3, FO, 4096, 128, 512);
  combine_kernel<1><<<4096, 256, 0, stream>>>(V1, IDX20_1, FO, dir3, g3, be3, S3, 1024, 256);
  pool_select_kernel<<<1024, 256, 0, stream>>>(S3, IDX4_1, SEL2, nullptr, nullptr, FM3P, 1024, 256, 256);

  // MHA1 + residual + ffn1 (fused)
  qkv1_kernel<<<dim3(512, 3), 64, 0, stream>>>(token, FM1P, a1_in_w, a1_in_b, Q1, K1, VA1);
  attn_tiled<16, 2, 8><<<512, 256, 0, stream>>>(Q1, K1, VA1, ATT1, 1024, 1024, 4, 0.25f);
  a1out_ffn1_kernel<<<512, 256, 0, stream>>>(ATT1, a1_out_w, a1_out_b, FM1P, ffn1_w, ffn1_b, S2);

  // BN stats, then fused BN-apply + ffn2 + q2
  bn_stats4_kernel<<<64, 256, 0, stream>>>(S2, BNST, 4096, 256);
  ffn2_q2_kernel<<<512, 256, 0, stream>>>(S2, ffn2_w, ffn2_b, BNST, bg, bbp,
                                          a2_in_w, a2_in_b, QUERY2, S3);

  // MHA2 (query2 as Q, fm3p as KV) + residual
  kv2_kernel<<<dim3(128, 2), 256, 0, stream>>>(FM3P, a2_in_w, a2_in_b, K2, V2);
  attn_tiled<64, 2, 8><<<512, 256, 0, stream>>>(S3, K2, V2, S1, 1024, 256, 4, 0.125f);
  linear_oi_kernel<<<512, 256, 0, stream>>>(S1, a2_out_w, a2_out_b, QUERY2, CROSS, 4096, 256, 256);

  // conv_layer7 + final conv1x1
  gemm_mc4_kernel<<<dim3(512, 2), 256, 0, stream>>>(CROSS, w7, b7, FO, 4096, 256, 2048);
  combine_kernel<4><<<4096, 256, 0, stream>>>(V1, IDX20_1, FO, dir7, g4, be4, S1, 1024, 1024);
  final_kernel<<<512, 128, 0, stream>>>(S1, c8_w, c8_b, out);
}